// Round 7
// baseline (1845.218 us; speedup 1.0000x reference)
//
#include <hip/hip_runtime.h>
#include <hip/hip_bf16.h>

#define SQ2F 0.70710678f
#define BNS 0.9999950000374997f   /* 1/sqrt(1+1e-5) */
#define L_ 1024

__device__ __forceinline__ float silu_f(float v) { return v / (1.f + __expf(-v)); }

// ---------------- sentinel: only if even 1-batch chunk doesn't fit ----------------
__global__ __launch_bounds__(256) void sentinel_s7(float* out, int n) {
    int i = blockIdx.x * 256 + threadIdx.x;
    if (i < n) out[i] = 1.0e6f;
}

// ---------------- wavelet (chunk of nb batches starting at b0) ----------------
__global__ __launch_bounds__(256) void wavelet_s7(const float* x, float* low, float* high, int b0) {
    int idx = blockIdx.x * 256 + threadIdx.x;      // nb*131072
    int fq = idx & 31, i = (idx >> 5) & 63, c = (idx >> 11) & 63, bl = idx >> 17;
    size_t base = ((size_t)((b0 + bl) * 64 + c) * 128 + 2 * i) * 32 + fq;
    float xe = x[base];
    float xo = x[base + 32];
    int m = (bl * 64 + i) * 16 + (fq >> 1);        // chunk-local row
    int k = c * 2 + (fq & 1);
    low[(size_t)m * 128 + k]  = (xe + xo) * SQ2F;
    high[(size_t)m * 128 + k] = (xo - xe) * SQ2F;
}

// ---------------- rec_w transpose: (c,o,k,l) -> (n=(o,k,l), c) ----------------
__global__ __launch_bounds__(256) void recwT_s7(const float* rec_w, float* recwT) {
    int idx = blockIdx.x * 256 + threadIdx.x;
    if (idx >= 49152) return;
    int c = idx % 192, n = idx / 192;
    int o = n >> 2, k = (n >> 1) & 1, l2 = n & 1;
    recwT[(size_t)n * 192 + c] = rec_w[((size_t)(c * 64 + o) * 2 + k) * 2 + l2];
}

// ---------------- naive GEMM, one block per local row m, thread per col n ----------------
// epi: 0 plain(cflip), 1 patch(+bias,BN,ReLU -> channel-major), 2 vim(+bias+x_seq),
//      3 fus(+bias,BN,+x_in), 4 rec(+bias,BN,ReLU,+x -> scatter, global batch b0g+bb)
__global__ __launch_bounds__(256) void gemm_s7(
    const float* A, const float* A2, const float* W, float* C,
    int N, int K, int lda, int ldw, int ldc,
    int aflip, int cflip, int epi, int b0g,
    const float* bias, const float* gg, const float* bet,
    const float* xm, const float* xa, const float* xres, float* outf) {
    __shared__ float As[256];
    int m = blockIdx.x;
    int ma = aflip ? (m ^ 1023) : m;
    for (int k = threadIdx.x; k < K; k += 256) {
        float v = A[(size_t)ma * lda + k];
        if (A2) v += A2[(size_t)ma * lda + k];
        As[k] = v;
    }
    __syncthreads();
    int n = blockIdx.y * 256 + threadIdx.x;
    if (n >= N) return;
    const float* Wr = W + (size_t)n * ldw;
    float acc = 0.f;
    for (int k = 0; k < K; ++k) acc = fmaf(As[k], Wr[k], acc);

    int bb = m >> 10, l = m & 1023;
    if (epi == 0) {
        int mm = cflip ? (m ^ 1023) : m;
        C[(size_t)mm * ldc + n] = acc;
    } else if (epi == 1) {
        float v = acc + bias[n];
        v = v * (gg[n] * BNS) + bet[n];
        C[((size_t)(bb * N + n) << 10) + l] = fmaxf(v, 0.f);
    } else if (epi == 2) {
        C[(size_t)m * ldc + n] = acc + bias[n] + xm[((size_t)(bb * 128 + n) << 10) + l];
    } else if (epi == 3) {
        float xin = (n < 128) ? xm[((size_t)(bb * 128 + n) << 10) + l]
                              : xa[((size_t)(bb * 64 + (n - 128)) << 10) + l];
        C[(size_t)m * ldc + n] = xin + (acc + bias[n]) * (gg[n] * BNS) + bet[n];
    } else {
        int o = n >> 2, kq = (n >> 1) & 1, l2 = n & 1;
        int ii = l >> 4, jj = l & 15;
        float v = acc + bias[o];
        v = fmaxf(v * (gg[o] * BNS) + bet[o], 0.f);
        size_t oidx = ((size_t)((b0g + bb) * 64 + o) * 128 + (2 * ii + kq)) * 32 + (2 * jj + l2);
        outf[oidx] = v + xres[oidx];
    }
}

// ---------------- LayerNorm over C=128: main_in (nb,128,1024) -> xn (rows,128) ----------------
__global__ __launch_bounds__(256) void ln_s7(const float* mainin, const float* g,
                                             const float* bt, float* xn) {
    int idx = blockIdx.x * 256 + threadIdx.x;   // chunk rows
    int bb = idx >> 10, l = idx & 1023;
    const float* src = mainin + (((size_t)bb * 128) << 10) + l;
    float s = 0.f, s2 = 0.f;
    for (int c = 0; c < 128; ++c) {
        float v = src[(size_t)c << 10];
        s += v; s2 = fmaf(v, v, s2);
    }
    float mu = s * (1.f / 128.f);
    float rs = rsqrtf(s2 * (1.f / 128.f) - mu * mu + 1e-5f);
    float* dst = xn + (size_t)idx * 128;
    for (int c = 0; c < 128; ++c) {
        float v = (src[(size_t)c << 10] - mu) * rs * g[c] + bt[c];
        dst[c] = v;
    }
}

// ---------------- causal conv (k=4) + SiLU: xz[:,:256] -> xc ----------------
__global__ __launch_bounds__(256) void conv_s7(const float* xz, const float* cw,
                                               const float* cb, float* xc) {
    int m = blockIdx.x, d = threadIdx.x;
    int l = m & 1023;
    float acc = cb[d];
    const float* w = cw + d * 4;
    for (int k = 0; k < 4; ++k) {
        int ls = l - 3 + k;
        if (ls >= 0) acc = fmaf(xz[(size_t)(m - 3 + k) * 512 + d], w[k], acc);
    }
    xc[(size_t)m * 256 + d] = silu_f(acc);
}

// ---------------- dt projection (K=8) + softplus ----------------
__global__ __launch_bounds__(256) void dtp_s7(const float* xdbl, const float* dtw,
                                              const float* dtbias, float* dtout) {
    __shared__ float x8[8];
    int m = blockIdx.x, d = threadIdx.x;
    if (d < 8) x8[d] = xdbl[(size_t)m * 40 + d];
    __syncthreads();
    float acc = dtbias[d];
    const float* w = dtw + d * 8;
    for (int r = 0; r < 8; ++r) acc = fmaf(x8[r], w[r], acc);
    float sp = (acc > 15.f) ? acc : log1pf(__expf(acc));
    dtout[(size_t)m * 256 + d] = sp;
}

// ---------------- selective scan (yg overlays xz cols 0..255, ld 512) ----------------
__global__ __launch_bounds__(256) void scan_s7(
    const float* dt0, const float* dt1, const float* xc0, const float* xc1,
    const float* xz0, const float* xz1, const float* xd0, const float* xd1,
    const float* al0, const float* al1, const float* D0, const float* D1,
    float* yg0, float* yg1) {
    const int b = blockIdx.x;        // chunk-local batch
    const int dir = blockIdx.y;
    const int d = blockIdx.z * 64 + (threadIdx.x >> 2);
    const int q = threadIdx.x & 3;

    const float* dtb = dir ? dt1 : dt0;
    const float* xcb = dir ? xc1 : xc0;
    const float* xzb = dir ? xz1 : xz0;
    const float* xdb = dir ? xd1 : xd0;
    const float* alog = (dir ? al1 : al0) + d * 16 + q * 4;
    const float* Dp = dir ? D1 : D0;
    float* ygb = dir ? yg1 : yg0;

    const float* dtp = dtb + (size_t)b * L_ * 256 + d;
    const float* xcp = xcb + (size_t)b * L_ * 256 + d;
    const float* zp  = xzb + (size_t)b * L_ * 512 + 256 + d;
    const float* bcp = xdb + (size_t)b * L_ * 40 + 8 + q * 4;   // B at +0, C at +16
    float* yp = ygb + (size_t)b * L_ * 512 + d;                  // ld = 512 (overlay)

    const float LOG2E = 1.44269504088896340736f;
    float al2[4];
    for (int n = 0; n < 4; ++n) al2[n] = -__expf(alog[n]) * LOG2E;
    const float Dd = Dp[d];
    float h0 = 0.f, h1 = 0.f, h2 = 0.f, h3 = 0.f;

    float dt_c = dtp[0], xv_c = xcp[0], zz_c = zp[0];
    float4 Bc = *(const float4*)(bcp);
    float4 Cc = *(const float4*)(bcp + 16);

    for (int l = 0; l < L_; ++l) {
        float dt = dt_c, xv = xv_c, zz = zz_c;
        float4 Bv = Bc, Cv = Cc;
        if (l + 1 < L_) {
            dt_c = dtp[(size_t)(l + 1) * 256];
            xv_c = xcp[(size_t)(l + 1) * 256];
            zz_c = zp[(size_t)(l + 1) * 512];
            Bc = *(const float4*)(bcp + (size_t)(l + 1) * 40);
            Cc = *(const float4*)(bcp + (size_t)(l + 1) * 40 + 16);
        }
        float dtx = dt * xv;
        float e0 = exp2f(dt * al2[0]);
        float e1 = exp2f(dt * al2[1]);
        float e2 = exp2f(dt * al2[2]);
        float e3 = exp2f(dt * al2[3]);
        h0 = fmaf(e0, h0, dtx * Bv.x);
        h1 = fmaf(e1, h1, dtx * Bv.y);
        h2 = fmaf(e2, h2, dtx * Bv.z);
        h3 = fmaf(e3, h3, dtx * Bv.w);
        float acc = fmaf(h3, Cv.w, fmaf(h2, Cv.z, fmaf(h1, Cv.y, h0 * Cv.x)));
        acc += __shfl_xor(acc, 1);
        acc += __shfl_xor(acc, 2);
        if (q == 0) {
            float y = fmaf(Dd, xv, acc);
            yp[(size_t)l * 512] = y * silu_f(zz);
        }
    }
}

// ---------------- depthwise conv 3x3 / 5x5 + BN + SiLU ----------------
__global__ __launch_bounds__(256) void dwconv_s7(const float* auxin,
                                                 const float* mk3w, const float* mk3b,
                                                 const float* mk5w, const float* mk5b,
                                                 const float* mkg, const float* mkbeta,
                                                 float* xout) {
    int idx = blockIdx.x * 256 + threadIdx.x;   // nb*65536
    int j = idx & 15, i = (idx >> 4) & 63, c = (idx >> 10) & 63, b = idx >> 16;
    const float* src = auxin + ((size_t)(b * 64 + c) << 10);
    float acc;
    if (c < 32) {
        acc = mk3b[c];
        for (int di = -1; di <= 1; ++di)
            for (int dj = -1; dj <= 1; ++dj) {
                int ii = i + di, jj = j + dj;
                if (ii >= 0 && ii < 64 && jj >= 0 && jj < 16)
                    acc = fmaf(src[ii * 16 + jj], mk3w[(c * 3 + di + 1) * 3 + dj + 1], acc);
            }
    } else {
        int cc = c - 32;
        acc = mk5b[cc];
        for (int di = -2; di <= 2; ++di)
            for (int dj = -2; dj <= 2; ++dj) {
                int ii = i + di, jj = j + dj;
                if (ii >= 0 && ii < 64 && jj >= 0 && jj < 16)
                    acc = fmaf(src[ii * 16 + jj], mk5w[(cc * 5 + di + 2) * 5 + dj + 2], acc);
            }
    }
    float v = acc * (mkg[c] * BNS) + mkbeta[c];
    v = silu_f(v);
    xout[(size_t)((b << 10) + i * 16 + j) * 192 + 128 + c] = v;
}

// ---------------- host ----------------
extern "C" void kernel_launch(void* const* d_in, const int* in_sizes, int n_in,
                              void* d_out, int out_size, void* d_ws, size_t ws_size,
                              hipStream_t stream) {
    (void)in_sizes; (void)n_in;
    const float* X         = (const float*)d_in[0];
    const float* main_w    = (const float*)d_in[1];
    const float* main_b    = (const float*)d_in[2];
    const float* main_g    = (const float*)d_in[3];
    const float* main_beta = (const float*)d_in[4];
    const float* aux_w     = (const float*)d_in[5];
    const float* aux_b     = (const float*)d_in[6];
    const float* aux_g     = (const float*)d_in[7];
    const float* aux_beta  = (const float*)d_in[8];
    const float* ln_g      = (const float*)d_in[9];
    const float* ln_b      = (const float*)d_in[10];
    const float* vim_w     = (const float*)d_in[11];
    const float* vim_b     = (const float*)d_in[12];
    const float* mk3_w     = (const float*)d_in[13];
    const float* mk3_b     = (const float*)d_in[14];
    const float* mk5_w     = (const float*)d_in[15];
    const float* mk5_b     = (const float*)d_in[16];
    const float* mk_g      = (const float*)d_in[17];
    const float* mk_beta   = (const float*)d_in[18];
    const float* fus_w     = (const float*)d_in[19];
    const float* fus_b     = (const float*)d_in[20];
    const float* fus_g     = (const float*)d_in[21];
    const float* fus_beta  = (const float*)d_in[22];
    const float* rec_w     = (const float*)d_in[23];
    const float* rec_b     = (const float*)d_in[24];
    const float* rec_g     = (const float*)d_in[25];
    const float* rec_beta  = (const float*)d_in[26];
    const float* in_w0    = (const float*)d_in[27];
    const float* conv_w0  = (const float*)d_in[28];
    const float* conv_b0  = (const float*)d_in[29];
    const float* xproj_w0 = (const float*)d_in[30];
    const float* dt_w0    = (const float*)d_in[31];
    const float* dt_b0    = (const float*)d_in[32];
    const float* Alog0    = (const float*)d_in[33];
    const float* Dvec0    = (const float*)d_in[34];
    const float* out_w0   = (const float*)d_in[35];
    const float* in_w1    = (const float*)d_in[36];
    const float* conv_w1  = (const float*)d_in[37];
    const float* conv_b1  = (const float*)d_in[38];
    const float* xproj_w1 = (const float*)d_in[39];
    const float* dt_w1    = (const float*)d_in[40];
    const float* dt_b1    = (const float*)d_in[41];
    const float* Alog1    = (const float*)d_in[42];
    const float* Dvec1    = (const float*)d_in[43];
    const float* out_w1   = (const float*)d_in[44];

    // Kernel-free base copy: out = x (float32). REC later overwrites every element.
    hipMemcpyAsync(d_out, d_in[0], (size_t)out_size * sizeof(float),
                   hipMemcpyDeviceToDevice, stream);

    // choose batches-per-chunk so the fp32 workspace fits ws_size
    const size_t wf = ws_size / sizeof(float);
    int nb = 0;
    if      (49152 + (size_t)8 * 1024 * 2576 <= wf) nb = 8;
    else if (49152 + (size_t)4 * 1024 * 2576 <= wf) nb = 4;
    else if (49152 + (size_t)2 * 1024 * 2576 <= wf) nb = 2;
    else if (49152 + (size_t)1 * 1024 * 2576 <= wf) nb = 1;
    if (nb == 0) {
        sentinel_s7<<<(out_size + 255) / 256, 256, 0, stream>>>((float*)d_out, out_size);
        return;
    }

    float* ws = (float*)d_ws;
    float* recwT = ws;                       // 49152 floats
    const size_t R = (size_t)nb * 1024;
    float* xzf    = ws + 49152;
    float* xzb    = xzf + R * 512;
    float* mainin = xzb + R * 512;
    float* auxin  = mainin + R * 128;
    float* xn     = auxin + R * 64;
    float* ofb    = xn;                      // overlay (xn dead after in_proj_b)
    float* lowb   = xn + R * 128;
    float* highb  = lowb + R * 128;
    float* dtf    = lowb;                    // overlay (low+high dead after patch)
    float* xcf    = highb + R * 128;
    float* xcb    = xcf + R * 256;
    float* xoutc  = xcf;                     // overlay (xc_f dead after scan)
    float* xfused = xcb;                     // overlay (xc_b dead after scan)
    float* xdblf  = xcb + R * 256;
    float* xdblb  = xdblf + R * 40;
    float* dtbk   = xdblb + R * 40;
    float* obb    = dtbk + R * 256;

    recwT_s7<<<192, 256, 0, stream>>>(rec_w, recwT);

    for (int b0 = 0; b0 < 8; b0 += nb) {
        wavelet_s7<<<nb * 512, 256, 0, stream>>>(X, lowb, highb, b0);

        // patch_proj main/aux                                         [epi 1]
        gemm_s7<<<dim3((unsigned)R, 1), 256, 0, stream>>>(
            lowb, nullptr, main_w, mainin, 128, 128, 128, 128, 0, 0, 0, 1, 0,
            main_b, main_g, main_beta, nullptr, nullptr, nullptr, nullptr);
        gemm_s7<<<dim3((unsigned)R, 1), 256, 0, stream>>>(
            highb, nullptr, aux_w, auxin, 64, 128, 128, 128, 0, 0, 0, 1, 0,
            aux_b, aux_g, aux_beta, nullptr, nullptr, nullptr, nullptr);
        ln_s7<<<nb * 4, 256, 0, stream>>>(mainin, ln_g, ln_b, xn);

        // forward mamba branch
        gemm_s7<<<dim3((unsigned)R, 2), 256, 0, stream>>>(
            xn, nullptr, in_w0, xzf, 512, 128, 128, 128, 512, 0, 0, 0, 0,
            nullptr, nullptr, nullptr, nullptr, nullptr, nullptr, nullptr);
        conv_s7<<<(unsigned)R, 256, 0, stream>>>(xzf, conv_w0, conv_b0, xcf);
        gemm_s7<<<dim3((unsigned)R, 1), 256, 0, stream>>>(
            xcf, nullptr, xproj_w0, xdblf, 40, 256, 256, 256, 40, 0, 0, 0, 0,
            nullptr, nullptr, nullptr, nullptr, nullptr, nullptr, nullptr);
        dtp_s7<<<(unsigned)R, 256, 0, stream>>>(xdblf, dt_w0, dt_b0, dtf);

        // backward mamba branch (A-read flipped within each batch)
        gemm_s7<<<dim3((unsigned)R, 2), 256, 0, stream>>>(
            xn, nullptr, in_w1, xzb, 512, 128, 128, 128, 512, 1, 0, 0, 0,
            nullptr, nullptr, nullptr, nullptr, nullptr, nullptr, nullptr);
        conv_s7<<<(unsigned)R, 256, 0, stream>>>(xzb, conv_w1, conv_b1, xcb);
        gemm_s7<<<dim3((unsigned)R, 1), 256, 0, stream>>>(
            xcb, nullptr, xproj_w1, xdblb, 40, 256, 256, 256, 40, 0, 0, 0, 0,
            nullptr, nullptr, nullptr, nullptr, nullptr, nullptr, nullptr);
        dtp_s7<<<(unsigned)R, 256, 0, stream>>>(xdblb, dt_w1, dt_b1, dtbk);

        scan_s7<<<dim3(nb, 2, 4), 256, 0, stream>>>(
            dtf, dtbk, xcf, xcb, xzf, xzb, xdblf, xdblb,
            Alog0, Alog1, Dvec0, Dvec1, xzf, xzb);

        // out_proj: yg (=xz cols 0..255, lda 512) -> of / ob (flipped store)
        gemm_s7<<<dim3((unsigned)R, 1), 256, 0, stream>>>(
            xzf, nullptr, out_w0, ofb, 128, 256, 512, 256, 128, 0, 0, 0, 0,
            nullptr, nullptr, nullptr, nullptr, nullptr, nullptr, nullptr);
        gemm_s7<<<dim3((unsigned)R, 1), 256, 0, stream>>>(
            xzb, nullptr, out_w1, obb, 128, 256, 512, 256, 128, 0, 1, 0, 0,
            nullptr, nullptr, nullptr, nullptr, nullptr, nullptr, nullptr);

        // vim: (of+ob) @ vim_w + vim_b + x_seq -> xout cols 0..127    [epi 2]
        gemm_s7<<<dim3((unsigned)R, 1), 256, 0, stream>>>(
            ofb, obb, vim_w, xoutc, 128, 128, 128, 128, 192, 0, 0, 2, 0,
            vim_b, nullptr, nullptr, mainin, nullptr, nullptr, nullptr);

        dwconv_s7<<<nb * 256, 256, 0, stream>>>(
            auxin, mk3_w, mk3_b, mk5_w, mk5_b, mk_g, mk_beta, xoutc);

        // fusion: xout @ fus_w + x_in + BN -> x_fused                 [epi 3]
        gemm_s7<<<dim3((unsigned)R, 1), 256, 0, stream>>>(
            xoutc, nullptr, fus_w, xfused, 192, 192, 192, 192, 192, 0, 0, 3, 0,
            fus_b, fus_g, fus_beta, mainin, auxin, nullptr, nullptr);

        // reconstruction: x_fused @ rec_wT + BN + ReLU + x -> d_out   [epi 4]
        gemm_s7<<<dim3((unsigned)R, 1), 256, 0, stream>>>(
            xfused, nullptr, recwT, nullptr, 256, 192, 192, 192, 0, 0, 0, 4, b0,
            rec_b, rec_g, rec_beta, nullptr, nullptr, X, (float*)d_out);
    }
}

// Round 8
// 931.272 us; speedup vs baseline: 1.9814x; 1.9814x over previous
//
#include <hip/hip_runtime.h>
#include <hip/hip_bf16.h>

#define SQ2F 0.70710678f
#define BNS 0.9999950000374997f   /* 1/sqrt(1+1e-5) */
#define L_ 1024
#define SD 8                      /* scan prefetch depth */

__device__ __forceinline__ float silu_f(float v) { return v / (1.f + __expf(-v)); }

// ---------------- sentinel: only if even 1-batch chunk doesn't fit ----------------
__global__ __launch_bounds__(256) void sentinel_s8(float* out, int n) {
    int i = blockIdx.x * 256 + threadIdx.x;
    if (i < n) out[i] = 1.0e6f;
}

// ---------------- wavelet (chunk of nb batches starting at b0) ----------------
__global__ __launch_bounds__(256) void wavelet_s8(const float* x, float* low, float* high, int b0) {
    int idx = blockIdx.x * 256 + threadIdx.x;      // nb*131072
    int fq = idx & 31, i = (idx >> 5) & 63, c = (idx >> 11) & 63, bl = idx >> 17;
    size_t base = ((size_t)((b0 + bl) * 64 + c) * 128 + 2 * i) * 32 + fq;
    float xe = x[base];
    float xo = x[base + 32];
    int m = (bl * 64 + i) * 16 + (fq >> 1);        // chunk-local row
    int k = c * 2 + (fq & 1);
    low[(size_t)m * 128 + k]  = (xe + xo) * SQ2F;
    high[(size_t)m * 128 + k] = (xo - xe) * SQ2F;
}

// ---------------- rec_w transpose: (c,o,k,l) -> (n=(o,k,l), c) ----------------
__global__ __launch_bounds__(256) void recwT_s8(const float* rec_w, float* recwT) {
    int idx = blockIdx.x * 256 + threadIdx.x;
    if (idx >= 49152) return;
    int c = idx % 192, n = idx / 192;
    int o = n >> 2, k = (n >> 1) & 1, l2 = n & 1;
    recwT[(size_t)n * 192 + c] = rec_w[((size_t)(c * 64 + o) * 2 + k) * 2 + l2];
}

// ---------------- tiled GEMM: BM=128 BN=64 BK=16, 256 thr, 8x4 microtile ----------------
// C[m,n] = sum_k A[m,k]*W[n,k]; runtime epilogue flags (uniform per launch).
// epi: 0 plain(cflip), 1 patch(+bias,BN,ReLU -> channel-major), 2 vim(+bias+x_seq),
//      3 fus(+bias,BN,+x_in), 4 rec(+bias,BN,ReLU,+x -> scatter, global batch b0g+bb)
__global__ __launch_bounds__(256) void gemm_s8(
    const float* A, const float* A2, const float* W, float* C,
    int N, int K, int lda, int ldw, int ldc,
    int aflip, int cflip, int epi, int b0g,
    const float* bias, const float* gg, const float* bet,
    const float* xm, const float* xa, const float* xres, float* outf) {
    __shared__ float As[16][132];
    __shared__ float Ws[16][68];
    const int tid = threadIdx.x;
    const int m0 = blockIdx.x * 128;
    const int n0 = blockIdx.y * 64;
    const int tm = tid >> 4, tn = tid & 15;
    const int ra = tid >> 1, ka = (tid & 1) * 8;   // A stage: row ra, k-offset ka (8 wide)
    const int rw = tid >> 2, kw = (tid & 3) * 4;   // W stage: row rw, k-offset kw (4 wide)

    float acc[8][4];
#pragma unroll
    for (int i = 0; i < 8; ++i)
#pragma unroll
        for (int j = 0; j < 4; ++j) acc[i][j] = 0.f;

    int m_a = m0 + ra;
    if (aflip) m_a ^= 1023;
    const float* Abase = A + (size_t)m_a * lda + ka;
    const float* A2base = A2 ? (A2 + (size_t)m_a * lda + ka) : (const float*)0;
    const int nw = n0 + rw;
    const bool wok = nw < N;
    const float* Wbase = W + (size_t)nw * ldw + kw;

    for (int k0 = 0; k0 < K; k0 += 16) {
        float4 v0 = *(const float4*)(Abase + k0);
        float4 v1 = *(const float4*)(Abase + k0 + 4);
        if (A2base) {
            float4 w0 = *(const float4*)(A2base + k0);
            float4 w1 = *(const float4*)(A2base + k0 + 4);
            v0.x += w0.x; v0.y += w0.y; v0.z += w0.z; v0.w += w0.w;
            v1.x += w1.x; v1.y += w1.y; v1.z += w1.z; v1.w += w1.w;
        }
        As[ka + 0][ra] = v0.x; As[ka + 1][ra] = v0.y; As[ka + 2][ra] = v0.z; As[ka + 3][ra] = v0.w;
        As[ka + 4][ra] = v1.x; As[ka + 5][ra] = v1.y; As[ka + 6][ra] = v1.z; As[ka + 7][ra] = v1.w;
        if (wok) {
            float4 wv = *(const float4*)(Wbase + k0);
            Ws[kw + 0][rw] = wv.x; Ws[kw + 1][rw] = wv.y;
            Ws[kw + 2][rw] = wv.z; Ws[kw + 3][rw] = wv.w;
        } else {
            Ws[kw + 0][rw] = 0.f; Ws[kw + 1][rw] = 0.f;
            Ws[kw + 2][rw] = 0.f; Ws[kw + 3][rw] = 0.f;
        }
        __syncthreads();
#pragma unroll
        for (int kk = 0; kk < 16; ++kk) {
            float a[8], w[4];
#pragma unroll
            for (int i = 0; i < 8; ++i) a[i] = As[kk][tm * 8 + i];
#pragma unroll
            for (int j = 0; j < 4; ++j) w[j] = Ws[kk][tn * 4 + j];
#pragma unroll
            for (int i = 0; i < 8; ++i)
#pragma unroll
                for (int j = 0; j < 4; ++j) acc[i][j] = fmaf(a[i], w[j], acc[i][j]);
        }
        __syncthreads();
    }

#pragma unroll
    for (int i = 0; i < 8; ++i) {
        int m = m0 + tm * 8 + i;
        int bb = m >> 10, l = m & 1023;
#pragma unroll
        for (int j = 0; j < 4; ++j) {
            int n = n0 + tn * 4 + j;
            if (n >= N) continue;
            float v = acc[i][j];
            if (epi == 0) {
                int mm = cflip ? (m ^ 1023) : m;
                C[(size_t)mm * ldc + n] = v;
            } else if (epi == 1) {
                v += bias[n];
                v = v * (gg[n] * BNS) + bet[n];
                C[((size_t)(bb * N + n) << 10) + l] = fmaxf(v, 0.f);
            } else if (epi == 2) {
                C[(size_t)m * ldc + n] = v + bias[n] + xm[((size_t)(bb * 128 + n) << 10) + l];
            } else if (epi == 3) {
                float xin = (n < 128) ? xm[((size_t)(bb * 128 + n) << 10) + l]
                                      : xa[((size_t)(bb * 64 + (n - 128)) << 10) + l];
                C[(size_t)m * ldc + n] = xin + (v + bias[n]) * (gg[n] * BNS) + bet[n];
            } else {
                int o = n >> 2, kq = (n >> 1) & 1, l2 = n & 1;
                int ii = l >> 4, jj = l & 15;
                v += bias[o];
                v = fmaxf(v * (gg[o] * BNS) + bet[o], 0.f);
                size_t oidx = ((size_t)((b0g + bb) * 64 + o) * 128 + (2 * ii + kq)) * 32 + (2 * jj + l2);
                outf[oidx] = v + xres[oidx];
            }
        }
    }
}

// ---------------- LayerNorm over C=128: main_in (nb,128,1024) -> xn (rows,128) ----------------
__global__ __launch_bounds__(256) void ln_s8(const float* mainin, const float* g,
                                             const float* bt, float* xn) {
    int idx = blockIdx.x * 256 + threadIdx.x;   // chunk rows
    int bb = idx >> 10, l = idx & 1023;
    const float* src = mainin + (((size_t)bb * 128) << 10) + l;
    float s = 0.f, s2 = 0.f;
    for (int c = 0; c < 128; ++c) {
        float v = src[(size_t)c << 10];
        s += v; s2 = fmaf(v, v, s2);
    }
    float mu = s * (1.f / 128.f);
    float rs = rsqrtf(s2 * (1.f / 128.f) - mu * mu + 1e-5f);
    float* dst = xn + (size_t)idx * 128;
    for (int c = 0; c < 128; ++c) {
        float v = (src[(size_t)c << 10] - mu) * rs * g[c] + bt[c];
        dst[c] = v;
    }
}

// ---------------- causal conv (k=4) + SiLU: xz[:,:256] -> xc ----------------
__global__ __launch_bounds__(256) void conv_s8(const float* xz, const float* cw,
                                               const float* cb, float* xc) {
    int m = blockIdx.x, d = threadIdx.x;
    int l = m & 1023;
    float acc = cb[d];
    const float* w = cw + d * 4;
    for (int k = 0; k < 4; ++k) {
        int ls = l - 3 + k;
        if (ls >= 0) acc = fmaf(xz[(size_t)(m - 3 + k) * 512 + d], w[k], acc);
    }
    xc[(size_t)m * 256 + d] = silu_f(acc);
}

// ---------------- dt projection (K=8) + softplus ----------------
__global__ __launch_bounds__(256) void dtp_s8(const float* xdbl, const float* dtw,
                                              const float* dtbias, float* dtout) {
    __shared__ float x8[8];
    int m = blockIdx.x, d = threadIdx.x;
    if (d < 8) x8[d] = xdbl[(size_t)m * 40 + d];
    __syncthreads();
    float acc = dtbias[d];
    const float* w = dtw + d * 8;
    for (int r = 0; r < 8; ++r) acc = fmaf(x8[r], w[r], acc);
    float sp = (acc > 15.f) ? acc : log1pf(__expf(acc));
    dtout[(size_t)m * 256 + d] = sp;
}

// ---------------- selective scan, depth-8 prefetch, 64-thr blocks over 256 CUs ------------
// yg overlays xz cols 0..255 (ld 512); z read from cols 256..511 -> disjoint.
__global__ __launch_bounds__(64) void scan_s8(
    const float* dt0, const float* dt1, const float* xc0, const float* xc1,
    const float* xz0, const float* xz1, const float* xd0, const float* xd1,
    const float* al0, const float* al1, const float* D0, const float* D1,
    float* yg0, float* yg1) {
    const int b = blockIdx.x;                       // chunk-local batch
    const int dir = blockIdx.y;
    const int d = blockIdx.z * 16 + (threadIdx.x >> 2);
    const int q = threadIdx.x & 3;

    const float* dtb = dir ? dt1 : dt0;
    const float* xcb = dir ? xc1 : xc0;
    const float* xzb = dir ? xz1 : xz0;
    const float* xdb = dir ? xd1 : xd0;
    const float* alog = (dir ? al1 : al0) + d * 16 + q * 4;
    const float* Dp = dir ? D1 : D0;
    float* ygb = dir ? yg1 : yg0;

    const float* dtp = dtb + (size_t)b * L_ * 256 + d;
    const float* xcp = xcb + (size_t)b * L_ * 256 + d;
    const float* zp  = xzb + (size_t)b * L_ * 512 + 256 + d;
    const float* bcp = xdb + (size_t)b * L_ * 40 + 8 + q * 4;   // B at +0, C at +16
    float* yp = ygb + (size_t)b * L_ * 512 + d;                  // ld = 512 (overlay)

    const float LOG2E = 1.44269504088896340736f;
    float al2[4];
#pragma unroll
    for (int n = 0; n < 4; ++n) al2[n] = -__expf(alog[n]) * LOG2E;
    const float Dd = Dp[d];
    float h0 = 0.f, h1 = 0.f, h2 = 0.f, h3 = 0.f;

    float dtv[SD], xvv[SD], zzv[SD];
    float4 Bv_[SD], Cv_[SD];
#pragma unroll
    for (int j = 0; j < SD; ++j) {
        dtv[j] = dtp[(size_t)j * 256];
        xvv[j] = xcp[(size_t)j * 256];
        zzv[j] = zp[(size_t)j * 512];
        Bv_[j] = *(const float4*)(bcp + (size_t)j * 40);
        Cv_[j] = *(const float4*)(bcp + (size_t)j * 40 + 16);
    }

    for (int l0 = 0; l0 < L_; l0 += SD) {
#pragma unroll
        for (int j = 0; j < SD; ++j) {
            const int l = l0 + j;
            float dt = dtv[j], xv = xvv[j], zz = zzv[j];
            float4 Bv = Bv_[j], Cv = Cv_[j];
            const int ln = l + SD;
            if (ln < L_) {
                dtv[j] = dtp[(size_t)ln * 256];
                xvv[j] = xcp[(size_t)ln * 256];
                zzv[j] = zp[(size_t)ln * 512];
                Bv_[j] = *(const float4*)(bcp + (size_t)ln * 40);
                Cv_[j] = *(const float4*)(bcp + (size_t)ln * 40 + 16);
            }
            float dtx = dt * xv;
            float e0 = exp2f(dt * al2[0]);
            float e1 = exp2f(dt * al2[1]);
            float e2 = exp2f(dt * al2[2]);
            float e3 = exp2f(dt * al2[3]);
            h0 = fmaf(e0, h0, dtx * Bv.x);
            h1 = fmaf(e1, h1, dtx * Bv.y);
            h2 = fmaf(e2, h2, dtx * Bv.z);
            h3 = fmaf(e3, h3, dtx * Bv.w);
            float acc = fmaf(h3, Cv.w, fmaf(h2, Cv.z, fmaf(h1, Cv.y, h0 * Cv.x)));
            acc += __shfl_xor(acc, 1);
            acc += __shfl_xor(acc, 2);
            if (q == 0) {
                float y = fmaf(Dd, xv, acc);
                yp[(size_t)l * 512] = y * silu_f(zz);
            }
        }
    }
}

// ---------------- depthwise conv 3x3 / 5x5 + BN + SiLU ----------------
__global__ __launch_bounds__(256) void dwconv_s8(const float* auxin,
                                                 const float* mk3w, const float* mk3b,
                                                 const float* mk5w, const float* mk5b,
                                                 const float* mkg, const float* mkbeta,
                                                 float* xout) {
    int idx = blockIdx.x * 256 + threadIdx.x;   // nb*65536
    int j = idx & 15, i = (idx >> 4) & 63, c = (idx >> 10) & 63, b = idx >> 16;
    const float* src = auxin + ((size_t)(b * 64 + c) << 10);
    float acc;
    if (c < 32) {
        acc = mk3b[c];
        for (int di = -1; di <= 1; ++di)
            for (int dj = -1; dj <= 1; ++dj) {
                int ii = i + di, jj = j + dj;
                if (ii >= 0 && ii < 64 && jj >= 0 && jj < 16)
                    acc = fmaf(src[ii * 16 + jj], mk3w[(c * 3 + di + 1) * 3 + dj + 1], acc);
            }
    } else {
        int cc = c - 32;
        acc = mk5b[cc];
        for (int di = -2; di <= 2; ++di)
            for (int dj = -2; dj <= 2; ++dj) {
                int ii = i + di, jj = j + dj;
                if (ii >= 0 && ii < 64 && jj >= 0 && jj < 16)
                    acc = fmaf(src[ii * 16 + jj], mk5w[(cc * 5 + di + 2) * 5 + dj + 2], acc);
            }
    }
    float v = acc * (mkg[c] * BNS) + mkbeta[c];
    v = silu_f(v);
    xout[(size_t)((b << 10) + i * 16 + j) * 192 + 128 + c] = v;
}

// ---------------- host ----------------
extern "C" void kernel_launch(void* const* d_in, const int* in_sizes, int n_in,
                              void* d_out, int out_size, void* d_ws, size_t ws_size,
                              hipStream_t stream) {
    (void)in_sizes; (void)n_in;
    const float* X         = (const float*)d_in[0];
    const float* main_w    = (const float*)d_in[1];
    const float* main_b    = (const float*)d_in[2];
    const float* main_g    = (const float*)d_in[3];
    const float* main_beta = (const float*)d_in[4];
    const float* aux_w     = (const float*)d_in[5];
    const float* aux_b     = (const float*)d_in[6];
    const float* aux_g     = (const float*)d_in[7];
    const float* aux_beta  = (const float*)d_in[8];
    const float* ln_g      = (const float*)d_in[9];
    const float* ln_b      = (const float*)d_in[10];
    const float* vim_w     = (const float*)d_in[11];
    const float* vim_b     = (const float*)d_in[12];
    const float* mk3_w     = (const float*)d_in[13];
    const float* mk3_b     = (const float*)d_in[14];
    const float* mk5_w     = (const float*)d_in[15];
    const float* mk5_b     = (const float*)d_in[16];
    const float* mk_g      = (const float*)d_in[17];
    const float* mk_beta   = (const float*)d_in[18];
    const float* fus_w     = (const float*)d_in[19];
    const float* fus_b     = (const float*)d_in[20];
    const float* fus_g     = (const float*)d_in[21];
    const float* fus_beta  = (const float*)d_in[22];
    const float* rec_w     = (const float*)d_in[23];
    const float* rec_b     = (const float*)d_in[24];
    const float* rec_g     = (const float*)d_in[25];
    const float* rec_beta  = (const float*)d_in[26];
    const float* in_w0    = (const float*)d_in[27];
    const float* conv_w0  = (const float*)d_in[28];
    const float* conv_b0  = (const float*)d_in[29];
    const float* xproj_w0 = (const float*)d_in[30];
    const float* dt_w0    = (const float*)d_in[31];
    const float* dt_b0    = (const float*)d_in[32];
    const float* Alog0    = (const float*)d_in[33];
    const float* Dvec0    = (const float*)d_in[34];
    const float* out_w0   = (const float*)d_in[35];
    const float* in_w1    = (const float*)d_in[36];
    const float* conv_w1  = (const float*)d_in[37];
    const float* conv_b1  = (const float*)d_in[38];
    const float* xproj_w1 = (const float*)d_in[39];
    const float* dt_w1    = (const float*)d_in[40];
    const float* dt_b1    = (const float*)d_in[41];
    const float* Alog1    = (const float*)d_in[42];
    const float* Dvec1    = (const float*)d_in[43];
    const float* out_w1   = (const float*)d_in[44];

    // choose batches-per-chunk so the fp32 workspace fits ws_size
    const size_t wf = ws_size / sizeof(float);
    int nb = 0;
    if      (49152 + (size_t)8 * 1024 * 2576 <= wf) nb = 8;
    else if (49152 + (size_t)4 * 1024 * 2576 <= wf) nb = 4;
    else if (49152 + (size_t)2 * 1024 * 2576 <= wf) nb = 2;
    else if (49152 + (size_t)1 * 1024 * 2576 <= wf) nb = 1;
    if (nb == 0) {
        sentinel_s8<<<(out_size + 255) / 256, 256, 0, stream>>>((float*)d_out, out_size);
        return;
    }

    float* ws = (float*)d_ws;
    float* recwT = ws;                       // 49152 floats
    const size_t R = (size_t)nb * 1024;
    float* xzf    = ws + 49152;
    float* xzb    = xzf + R * 512;
    float* mainin = xzb + R * 512;
    float* auxin  = mainin + R * 128;
    float* xn     = auxin + R * 64;
    float* ofb    = xn;                      // overlay (xn dead after in_proj_b)
    float* lowb   = xn + R * 128;
    float* highb  = lowb + R * 128;
    float* dtf    = lowb;                    // overlay (low+high dead after patch)
    float* xcf    = highb + R * 128;
    float* xcb    = xcf + R * 256;
    float* xoutc  = xcf;                     // overlay (xc_f dead after scan)
    float* xfused = xcb;                     // overlay (xc_b dead after scan)
    float* xdblf  = xcb + R * 256;
    float* xdblb  = xdblf + R * 40;
    float* dtbk   = xdblb + R * 40;
    float* obb    = dtbk + R * 256;

    recwT_s8<<<192, 256, 0, stream>>>(rec_w, recwT);
    const unsigned GM = (unsigned)(R / 128);   // M-tiles per chunk

    for (int b0 = 0; b0 < 8; b0 += nb) {
        wavelet_s8<<<nb * 512, 256, 0, stream>>>(X, lowb, highb, b0);

        // patch_proj main/aux                                         [epi 1]
        gemm_s8<<<dim3(GM, 2), 256, 0, stream>>>(
            lowb, nullptr, main_w, mainin, 128, 128, 128, 128, 0, 0, 0, 1, 0,
            main_b, main_g, main_beta, nullptr, nullptr, nullptr, nullptr);
        gemm_s8<<<dim3(GM, 1), 256, 0, stream>>>(
            highb, nullptr, aux_w, auxin, 64, 128, 128, 128, 0, 0, 0, 1, 0,
            aux_b, aux_g, aux_beta, nullptr, nullptr, nullptr, nullptr);
        ln_s8<<<nb * 4, 256, 0, stream>>>(mainin, ln_g, ln_b, xn);

        // forward mamba branch
        gemm_s8<<<dim3(GM, 8), 256, 0, stream>>>(
            xn, nullptr, in_w0, xzf, 512, 128, 128, 128, 512, 0, 0, 0, 0,
            nullptr, nullptr, nullptr, nullptr, nullptr, nullptr, nullptr);
        conv_s8<<<(unsigned)R, 256, 0, stream>>>(xzf, conv_w0, conv_b0, xcf);
        gemm_s8<<<dim3(GM, 1), 256, 0, stream>>>(
            xcf, nullptr, xproj_w0, xdblf, 40, 256, 256, 256, 40, 0, 0, 0, 0,
            nullptr, nullptr, nullptr, nullptr, nullptr, nullptr, nullptr);
        dtp_s8<<<(unsigned)R, 256, 0, stream>>>(xdblf, dt_w0, dt_b0, dtf);

        // backward mamba branch (A-read flipped within each batch)
        gemm_s8<<<dim3(GM, 8), 256, 0, stream>>>(
            xn, nullptr, in_w1, xzb, 512, 128, 128, 128, 512, 1, 0, 0, 0,
            nullptr, nullptr, nullptr, nullptr, nullptr, nullptr, nullptr);
        conv_s8<<<(unsigned)R, 256, 0, stream>>>(xzb, conv_w1, conv_b1, xcb);
        gemm_s8<<<dim3(GM, 1), 256, 0, stream>>>(
            xcb, nullptr, xproj_w1, xdblb, 40, 256, 256, 256, 40, 0, 0, 0, 0,
            nullptr, nullptr, nullptr, nullptr, nullptr, nullptr, nullptr);
        dtp_s8<<<(unsigned)R, 256, 0, stream>>>(xdblb, dt_w1, dt_b1, dtbk);

        scan_s8<<<dim3(nb, 2, 16), 64, 0, stream>>>(
            dtf, dtbk, xcf, xcb, xzf, xzb, xdblf, xdblb,
            Alog0, Alog1, Dvec0, Dvec1, xzf, xzb);

        // out_proj: yg (=xz cols 0..255, lda 512) -> of / ob (flipped store)
        gemm_s8<<<dim3(GM, 2), 256, 0, stream>>>(
            xzf, nullptr, out_w0, ofb, 128, 256, 512, 256, 128, 0, 0, 0, 0,
            nullptr, nullptr, nullptr, nullptr, nullptr, nullptr, nullptr);
        gemm_s8<<<dim3(GM, 2), 256, 0, stream>>>(
            xzb, nullptr, out_w1, obb, 128, 256, 512, 256, 128, 0, 1, 0, 0,
            nullptr, nullptr, nullptr, nullptr, nullptr, nullptr, nullptr);

        // vim: (of+ob) @ vim_w + vim_b + x_seq -> xout cols 0..127    [epi 2]
        gemm_s8<<<dim3(GM, 2), 256, 0, stream>>>(
            ofb, obb, vim_w, xoutc, 128, 128, 128, 128, 192, 0, 0, 2, 0,
            vim_b, nullptr, nullptr, mainin, nullptr, nullptr, nullptr);

        dwconv_s8<<<nb * 256, 256, 0, stream>>>(
            auxin, mk3_w, mk3_b, mk5_w, mk5_b, mk_g, mk_beta, xoutc);

        // fusion: xout @ fus_w + x_in + BN -> x_fused                 [epi 3]
        gemm_s8<<<dim3(GM, 3), 256, 0, stream>>>(
            xoutc, nullptr, fus_w, xfused, 192, 192, 192, 192, 192, 0, 0, 3, 0,
            fus_b, fus_g, fus_beta, mainin, auxin, nullptr, nullptr);

        // reconstruction: x_fused @ rec_wT + BN + ReLU + x -> d_out   [epi 4]
        gemm_s8<<<dim3(GM, 4), 256, 0, stream>>>(
            xfused, nullptr, recwT, nullptr, 256, 192, 192, 192, 0, 0, 0, 4, b0,
            rec_b, rec_g, rec_beta, nullptr, nullptr, X, (float*)d_out);
    }
}

// Round 9
// 629.598 us; speedup vs baseline: 2.9308x; 1.4792x over previous
//
#include <hip/hip_runtime.h>
#include <hip/hip_bf16.h>

#define SQ2F 0.70710678f
#define BNS 0.9999950000374997f   /* 1/sqrt(1+1e-5) */
#define L_ 1024
#define TS 128                    /* scan LDS tile (steps) */
#define NT (L_ / TS)

__device__ __forceinline__ float silu_f(float v) { return v / (1.f + __expf(-v)); }

// ---------------- sentinel: only if even 1-batch chunk doesn't fit ----------------
__global__ __launch_bounds__(256) void sentinel_s9(float* out, int n) {
    int i = blockIdx.x * 256 + threadIdx.x;
    if (i < n) out[i] = 1.0e6f;
}

// ---------------- wavelet (chunk of nb batches starting at b0) ----------------
__global__ __launch_bounds__(256) void wavelet_s9(const float* x, float* low, float* high, int b0) {
    int idx = blockIdx.x * 256 + threadIdx.x;      // nb*131072
    int fq = idx & 31, i = (idx >> 5) & 63, c = (idx >> 11) & 63, bl = idx >> 17;
    size_t base = ((size_t)((b0 + bl) * 64 + c) * 128 + 2 * i) * 32 + fq;
    float xe = x[base];
    float xo = x[base + 32];
    int m = (bl * 64 + i) * 16 + (fq >> 1);        // chunk-local row
    int k = c * 2 + (fq & 1);
    low[(size_t)m * 128 + k]  = (xe + xo) * SQ2F;
    high[(size_t)m * 128 + k] = (xo - xe) * SQ2F;
}

// ---------------- rec_w transpose: (c,o,k,l) -> (n=(o,k,l), c) ----------------
__global__ __launch_bounds__(256) void recwT_s9(const float* rec_w, float* recwT) {
    int idx = blockIdx.x * 256 + threadIdx.x;
    if (idx >= 49152) return;
    int c = idx % 192, n = idx / 192;
    int o = n >> 2, k = (n >> 1) & 1, l2 = n & 1;
    recwT[(size_t)n * 192 + c] = rec_w[((size_t)(c * 64 + o) * 2 + k) * 2 + l2];
}

// ---------------- tiled GEMM: BM=128 BN=64 BK=16, 256 thr, 8x4 microtile ----------------
// epi: 0 plain(cflip), 1 patch(+bias,BN,ReLU -> channel-major), 2 vim(+bias+x_seq),
//      3 fus(+bias,BN,+x_in), 4 rec(+bias,BN,ReLU,+x -> scatter, global batch b0g+bb)
__global__ __launch_bounds__(256) void gemm_s9(
    const float* A, const float* A2, const float* W, float* C,
    int N, int K, int lda, int ldw, int ldc,
    int aflip, int cflip, int epi, int b0g,
    const float* bias, const float* gg, const float* bet,
    const float* xm, const float* xa, const float* xres, float* outf) {
    __shared__ float As[16][132];
    __shared__ float Ws[16][68];
    const int tid = threadIdx.x;
    const int m0 = blockIdx.x * 128;
    const int n0 = blockIdx.y * 64;
    const int tm = tid >> 4, tn = tid & 15;
    const int ra = tid >> 1, ka = (tid & 1) * 8;   // A stage: row ra, k-offset ka (8 wide)
    const int rw = tid >> 2, kw = (tid & 3) * 4;   // W stage: row rw, k-offset kw (4 wide)

    float acc[8][4];
#pragma unroll
    for (int i = 0; i < 8; ++i)
#pragma unroll
        for (int j = 0; j < 4; ++j) acc[i][j] = 0.f;

    int m_a = m0 + ra;
    if (aflip) m_a ^= 1023;
    const float* Abase = A + (size_t)m_a * lda + ka;
    const float* A2base = A2 ? (A2 + (size_t)m_a * lda + ka) : (const float*)0;
    const int nw = n0 + rw;
    const bool wok = nw < N;
    const float* Wbase = W + (size_t)nw * ldw + kw;

    for (int k0 = 0; k0 < K; k0 += 16) {
        float4 v0 = *(const float4*)(Abase + k0);
        float4 v1 = *(const float4*)(Abase + k0 + 4);
        if (A2base) {
            float4 w0 = *(const float4*)(A2base + k0);
            float4 w1 = *(const float4*)(A2base + k0 + 4);
            v0.x += w0.x; v0.y += w0.y; v0.z += w0.z; v0.w += w0.w;
            v1.x += w1.x; v1.y += w1.y; v1.z += w1.z; v1.w += w1.w;
        }
        As[ka + 0][ra] = v0.x; As[ka + 1][ra] = v0.y; As[ka + 2][ra] = v0.z; As[ka + 3][ra] = v0.w;
        As[ka + 4][ra] = v1.x; As[ka + 5][ra] = v1.y; As[ka + 6][ra] = v1.z; As[ka + 7][ra] = v1.w;
        if (wok) {
            float4 wv = *(const float4*)(Wbase + k0);
            Ws[kw + 0][rw] = wv.x; Ws[kw + 1][rw] = wv.y;
            Ws[kw + 2][rw] = wv.z; Ws[kw + 3][rw] = wv.w;
        } else {
            Ws[kw + 0][rw] = 0.f; Ws[kw + 1][rw] = 0.f;
            Ws[kw + 2][rw] = 0.f; Ws[kw + 3][rw] = 0.f;
        }
        __syncthreads();
#pragma unroll
        for (int kk = 0; kk < 16; ++kk) {
            float a[8], w[4];
#pragma unroll
            for (int i = 0; i < 8; ++i) a[i] = As[kk][tm * 8 + i];
#pragma unroll
            for (int j = 0; j < 4; ++j) w[j] = Ws[kk][tn * 4 + j];
#pragma unroll
            for (int i = 0; i < 8; ++i)
#pragma unroll
                for (int j = 0; j < 4; ++j) acc[i][j] = fmaf(a[i], w[j], acc[i][j]);
        }
        __syncthreads();
    }

#pragma unroll
    for (int i = 0; i < 8; ++i) {
        int m = m0 + tm * 8 + i;
        int bb = m >> 10, l = m & 1023;
#pragma unroll
        for (int j = 0; j < 4; ++j) {
            int n = n0 + tn * 4 + j;
            if (n >= N) continue;
            float v = acc[i][j];
            if (epi == 0) {
                int mm = cflip ? (m ^ 1023) : m;
                C[(size_t)mm * ldc + n] = v;
            } else if (epi == 1) {
                v += bias[n];
                v = v * (gg[n] * BNS) + bet[n];
                C[((size_t)(bb * N + n) << 10) + l] = fmaxf(v, 0.f);
            } else if (epi == 2) {
                C[(size_t)m * ldc + n] = v + bias[n] + xm[((size_t)(bb * 128 + n) << 10) + l];
            } else if (epi == 3) {
                float xin = (n < 128) ? xm[((size_t)(bb * 128 + n) << 10) + l]
                                      : xa[((size_t)(bb * 64 + (n - 128)) << 10) + l];
                C[(size_t)m * ldc + n] = xin + (v + bias[n]) * (gg[n] * BNS) + bet[n];
            } else {
                int o = n >> 2, kq = (n >> 1) & 1, l2 = n & 1;
                int ii = l >> 4, jj = l & 15;
                v += bias[o];
                v = fmaxf(v * (gg[o] * BNS) + bet[o], 0.f);
                size_t oidx = ((size_t)((b0g + bb) * 64 + o) * 128 + (2 * ii + kq)) * 32 + (2 * jj + l2);
                outf[oidx] = v + xres[oidx];
            }
        }
    }
}

// ---------------- LayerNorm over C=128: main_in (nb,128,1024) -> xn (rows,128) ----------------
__global__ __launch_bounds__(256) void ln_s9(const float* mainin, const float* g,
                                             const float* bt, float* xn) {
    int idx = blockIdx.x * 256 + threadIdx.x;   // chunk rows
    int bb = idx >> 10, l = idx & 1023;
    const float* src = mainin + (((size_t)bb * 128) << 10) + l;
    float s = 0.f, s2 = 0.f;
    for (int c = 0; c < 128; ++c) {
        float v = src[(size_t)c << 10];
        s += v; s2 = fmaf(v, v, s2);
    }
    float mu = s * (1.f / 128.f);
    float rs = rsqrtf(s2 * (1.f / 128.f) - mu * mu + 1e-5f);
    float* dst = xn + (size_t)idx * 128;
    for (int c = 0; c < 128; ++c) {
        float v = (src[(size_t)c << 10] - mu) * rs * g[c] + bt[c];
        dst[c] = v;
    }
}

// ---------------- causal conv (k=4) + SiLU: xz[:,:256] -> xc ----------------
__global__ __launch_bounds__(256) void conv_s9(const float* xz, const float* cw,
                                               const float* cb, float* xc) {
    int m = blockIdx.x, d = threadIdx.x;
    int l = m & 1023;
    float acc = cb[d];
    const float* w = cw + d * 4;
    for (int k = 0; k < 4; ++k) {
        int ls = l - 3 + k;
        if (ls >= 0) acc = fmaf(xz[(size_t)(m - 3 + k) * 512 + d], w[k], acc);
    }
    xc[(size_t)m * 256 + d] = silu_f(acc);
}

// ---------------- dt projection (K=8) + softplus ----------------
__global__ __launch_bounds__(256) void dtp_s9(const float* xdbl, const float* dtw,
                                              const float* dtbias, float* dtout) {
    __shared__ float x8[8];
    int m = blockIdx.x, d = threadIdx.x;
    if (d < 8) x8[d] = xdbl[(size_t)m * 40 + d];
    __syncthreads();
    float acc = dtbias[d];
    const float* w = dtw + d * 8;
    for (int r = 0; r < 8; ++r) acc = fmaf(x8[r], w[r], acc);
    float sp = (acc > 15.f) ? acc : log1pf(__expf(acc));
    dtout[(size_t)m * 256 + d] = sp;
}

// ---------------- selective scan: producer/consumer wave pair, LDS double-buffer --------
// Block = 128 thr = 2 waves. Wave1 stages tile t+1 global->LDS; wave0 computes tile t.
// yg overlays xz cols 0..255 (ld 512); z read from cols 256..511 -> disjoint.
__global__ __launch_bounds__(128) void scan_s9(
    const float* dt0, const float* dt1, const float* xc0, const float* xc1,
    const float* xz0, const float* xz1, const float* xd0, const float* xd1,
    const float* al0, const float* al1, const float* D0, const float* D1,
    float* yg0, float* yg1) {
    __shared__ float dts[2][TS][16];
    __shared__ float xvs[2][TS][16];
    __shared__ float zzs[2][TS][16];
    __shared__ float bcs[2][TS][32];

    const int b = blockIdx.x;                       // chunk-local batch
    const int dir = blockIdx.y;
    const int d0 = blockIdx.z * 16;
    const int tid = threadIdx.x;

    const float* dtb = dir ? dt1 : dt0;
    const float* xcb = dir ? xc1 : xc0;
    const float* xzb = dir ? xz1 : xz0;
    const float* xdb = dir ? xd1 : xd0;
    float* ygb = dir ? yg1 : yg0;

    const size_t base256 = (size_t)b * L_ * 256 + d0;
    const size_t base512 = (size_t)b * L_ * 512 + 256 + d0;
    const size_t base40  = (size_t)b * L_ * 40 + 8;

    const int isStage = tid >> 6;                   // wave 1 stages
    const int t2 = tid & 63;

    // compute-wave state
    const int dg = t2 >> 2, q = t2 & 3;
    const float LOG2E = 1.44269504088896340736f;
    float al2[4];
    float Dd = 0.f;
    float h0 = 0.f, h1 = 0.f, h2 = 0.f, h3 = 0.f;
    if (!isStage) {
        const float* alog = (dir ? al1 : al0) + (d0 + dg) * 16 + q * 4;
#pragma unroll
        for (int n = 0; n < 4; ++n) al2[n] = -__expf(alog[n]) * LOG2E;
        Dd = (dir ? D1 : D0)[d0 + dg];
    }
    float* yp = ygb + (size_t)b * L_ * 512 + d0 + dg;   // ld = 512 (overlay)

    // stage tile 0
    if (isStage) {
        const int l0 = 0, sb = 0;
#pragma unroll 2
        for (int f = t2; f < TS * 4; f += 64) {
            int l = f >> 2, sg = (f & 3) * 4;
            *(float4*)&dts[sb][l][sg] = *(const float4*)(dtb + base256 + (size_t)(l0 + l) * 256 + sg);
            *(float4*)&xvs[sb][l][sg] = *(const float4*)(xcb + base256 + (size_t)(l0 + l) * 256 + sg);
            *(float4*)&zzs[sb][l][sg] = *(const float4*)(xzb + base512 + (size_t)(l0 + l) * 512 + sg);
        }
#pragma unroll 2
        for (int f = t2; f < TS * 8; f += 64) {
            int l = f >> 3, sg = (f & 7) * 4;
            *(float4*)&bcs[sb][l][sg] = *(const float4*)(xdb + base40 + (size_t)(l0 + l) * 40 + sg);
        }
    }
    __syncthreads();

    for (int t = 0; t < NT; ++t) {
        if (isStage) {
            if (t + 1 < NT) {
                const int l0 = (t + 1) * TS, sb = (t + 1) & 1;
#pragma unroll 2
                for (int f = t2; f < TS * 4; f += 64) {
                    int l = f >> 2, sg = (f & 3) * 4;
                    *(float4*)&dts[sb][l][sg] = *(const float4*)(dtb + base256 + (size_t)(l0 + l) * 256 + sg);
                    *(float4*)&xvs[sb][l][sg] = *(const float4*)(xcb + base256 + (size_t)(l0 + l) * 256 + sg);
                    *(float4*)&zzs[sb][l][sg] = *(const float4*)(xzb + base512 + (size_t)(l0 + l) * 512 + sg);
                }
#pragma unroll 2
                for (int f = t2; f < TS * 8; f += 64) {
                    int l = f >> 3, sg = (f & 7) * 4;
                    *(float4*)&bcs[sb][l][sg] = *(const float4*)(xdb + base40 + (size_t)(l0 + l) * 40 + sg);
                }
            }
        } else {
            const int cb = t & 1;
#pragma unroll 4
            for (int l = 0; l < TS; ++l) {
                float dt = dts[cb][l][dg];
                float xv = xvs[cb][l][dg];
                float zz = zzs[cb][l][dg];
                float4 Bv = *(const float4*)&bcs[cb][l][q * 4];
                float4 Cv = *(const float4*)&bcs[cb][l][16 + q * 4];
                float dtx = dt * xv;
                float e0 = exp2f(dt * al2[0]);
                float e1 = exp2f(dt * al2[1]);
                float e2 = exp2f(dt * al2[2]);
                float e3 = exp2f(dt * al2[3]);
                h0 = fmaf(e0, h0, dtx * Bv.x);
                h1 = fmaf(e1, h1, dtx * Bv.y);
                h2 = fmaf(e2, h2, dtx * Bv.z);
                h3 = fmaf(e3, h3, dtx * Bv.w);
                float acc = fmaf(h3, Cv.w, fmaf(h2, Cv.z, fmaf(h1, Cv.y, h0 * Cv.x)));
                acc += __shfl_xor(acc, 1);
                acc += __shfl_xor(acc, 2);
                if (q == 0) {
                    float y = fmaf(Dd, xv, acc);
                    yp[(size_t)(t * TS + l) * 512] = y * silu_f(zz);
                }
            }
        }
        __syncthreads();
    }
}

// ---------------- depthwise conv 3x3 / 5x5 + BN + SiLU ----------------
__global__ __launch_bounds__(256) void dwconv_s9(const float* auxin,
                                                 const float* mk3w, const float* mk3b,
                                                 const float* mk5w, const float* mk5b,
                                                 const float* mkg, const float* mkbeta,
                                                 float* xout) {
    int idx = blockIdx.x * 256 + threadIdx.x;   // nb*65536
    int j = idx & 15, i = (idx >> 4) & 63, c = (idx >> 10) & 63, b = idx >> 16;
    const float* src = auxin + ((size_t)(b * 64 + c) << 10);
    float acc;
    if (c < 32) {
        acc = mk3b[c];
        for (int di = -1; di <= 1; ++di)
            for (int dj = -1; dj <= 1; ++dj) {
                int ii = i + di, jj = j + dj;
                if (ii >= 0 && ii < 64 && jj >= 0 && jj < 16)
                    acc = fmaf(src[ii * 16 + jj], mk3w[(c * 3 + di + 1) * 3 + dj + 1], acc);
            }
    } else {
        int cc = c - 32;
        acc = mk5b[cc];
        for (int di = -2; di <= 2; ++di)
            for (int dj = -2; dj <= 2; ++dj) {
                int ii = i + di, jj = j + dj;
                if (ii >= 0 && ii < 64 && jj >= 0 && jj < 16)
                    acc = fmaf(src[ii * 16 + jj], mk5w[(cc * 5 + di + 2) * 5 + dj + 2], acc);
            }
    }
    float v = acc * (mkg[c] * BNS) + mkbeta[c];
    v = silu_f(v);
    xout[(size_t)((b << 10) + i * 16 + j) * 192 + 128 + c] = v;
}

// ---------------- host ----------------
extern "C" void kernel_launch(void* const* d_in, const int* in_sizes, int n_in,
                              void* d_out, int out_size, void* d_ws, size_t ws_size,
                              hipStream_t stream) {
    (void)in_sizes; (void)n_in;
    const float* X         = (const float*)d_in[0];
    const float* main_w    = (const float*)d_in[1];
    const float* main_b    = (const float*)d_in[2];
    const float* main_g    = (const float*)d_in[3];
    const float* main_beta = (const float*)d_in[4];
    const float* aux_w     = (const float*)d_in[5];
    const float* aux_b     = (const float*)d_in[6];
    const float* aux_g     = (const float*)d_in[7];
    const float* aux_beta  = (const float*)d_in[8];
    const float* ln_g      = (const float*)d_in[9];
    const float* ln_b      = (const float*)d_in[10];
    const float* vim_w     = (const float*)d_in[11];
    const float* vim_b     = (const float*)d_in[12];
    const float* mk3_w     = (const float*)d_in[13];
    const float* mk3_b     = (const float*)d_in[14];
    const float* mk5_w     = (const float*)d_in[15];
    const float* mk5_b     = (const float*)d_in[16];
    const float* mk_g      = (const float*)d_in[17];
    const float* mk_beta   = (const float*)d_in[18];
    const float* fus_w     = (const float*)d_in[19];
    const float* fus_b     = (const float*)d_in[20];
    const float* fus_g     = (const float*)d_in[21];
    const float* fus_beta  = (const float*)d_in[22];
    const float* rec_w     = (const float*)d_in[23];
    const float* rec_b     = (const float*)d_in[24];
    const float* rec_g     = (const float*)d_in[25];
    const float* rec_beta  = (const float*)d_in[26];
    const float* in_w0    = (const float*)d_in[27];
    const float* conv_w0  = (const float*)d_in[28];
    const float* conv_b0  = (const float*)d_in[29];
    const float* xproj_w0 = (const float*)d_in[30];
    const float* dt_w0    = (const float*)d_in[31];
    const float* dt_b0    = (const float*)d_in[32];
    const float* Alog0    = (const float*)d_in[33];
    const float* Dvec0    = (const float*)d_in[34];
    const float* out_w0   = (const float*)d_in[35];
    const float* in_w1    = (const float*)d_in[36];
    const float* conv_w1  = (const float*)d_in[37];
    const float* conv_b1  = (const float*)d_in[38];
    const float* xproj_w1 = (const float*)d_in[39];
    const float* dt_w1    = (const float*)d_in[40];
    const float* dt_b1    = (const float*)d_in[41];
    const float* Alog1    = (const float*)d_in[42];
    const float* Dvec1    = (const float*)d_in[43];
    const float* out_w1   = (const float*)d_in[44];

    // choose batches-per-chunk so the fp32 workspace fits ws_size
    const size_t wf = ws_size / sizeof(float);
    int nb = 0;
    if      (49152 + (size_t)8 * 1024 * 2576 <= wf) nb = 8;
    else if (49152 + (size_t)4 * 1024 * 2576 <= wf) nb = 4;
    else if (49152 + (size_t)2 * 1024 * 2576 <= wf) nb = 2;
    else if (49152 + (size_t)1 * 1024 * 2576 <= wf) nb = 1;
    if (nb == 0) {
        sentinel_s9<<<(out_size + 255) / 256, 256, 0, stream>>>((float*)d_out, out_size);
        return;
    }

    float* ws = (float*)d_ws;
    float* recwT = ws;                       // 49152 floats
    const size_t R = (size_t)nb * 1024;
    float* xzf    = ws + 49152;
    float* xzb    = xzf + R * 512;
    float* mainin = xzb + R * 512;
    float* auxin  = mainin + R * 128;
    float* xn     = auxin + R * 64;
    float* ofb    = xn;                      // overlay (xn dead after in_proj_b)
    float* lowb   = xn + R * 128;
    float* highb  = lowb + R * 128;
    float* dtf    = lowb;                    // overlay (low+high dead after patch)
    float* xcf    = highb + R * 128;
    float* xcb    = xcf + R * 256;
    float* xoutc  = xcf;                     // overlay (xc_f dead after scan)
    float* xfused = xcb;                     // overlay (xc_b dead after scan)
    float* xdblf  = xcb + R * 256;
    float* xdblb  = xdblf + R * 40;
    float* dtbk   = xdblb + R * 40;
    float* obb    = dtbk + R * 256;

    recwT_s9<<<192, 256, 0, stream>>>(rec_w, recwT);
    const unsigned GM = (unsigned)(R / 128);   // M-tiles per chunk

    for (int b0 = 0; b0 < 8; b0 += nb) {
        wavelet_s9<<<nb * 512, 256, 0, stream>>>(X, lowb, highb, b0);

        // patch_proj main/aux                                         [epi 1]
        gemm_s9<<<dim3(GM, 2), 256, 0, stream>>>(
            lowb, nullptr, main_w, mainin, 128, 128, 128, 128, 0, 0, 0, 1, 0,
            main_b, main_g, main_beta, nullptr, nullptr, nullptr, nullptr);
        gemm_s9<<<dim3(GM, 1), 256, 0, stream>>>(
            highb, nullptr, aux_w, auxin, 64, 128, 128, 128, 0, 0, 0, 1, 0,
            aux_b, aux_g, aux_beta, nullptr, nullptr, nullptr, nullptr);
        ln_s9<<<nb * 4, 256, 0, stream>>>(mainin, ln_g, ln_b, xn);

        // forward mamba branch
        gemm_s9<<<dim3(GM, 8), 256, 0, stream>>>(
            xn, nullptr, in_w0, xzf, 512, 128, 128, 128, 512, 0, 0, 0, 0,
            nullptr, nullptr, nullptr, nullptr, nullptr, nullptr, nullptr);
        conv_s9<<<(unsigned)R, 256, 0, stream>>>(xzf, conv_w0, conv_b0, xcf);
        gemm_s9<<<dim3(GM, 1), 256, 0, stream>>>(
            xcf, nullptr, xproj_w0, xdblf, 40, 256, 256, 256, 40, 0, 0, 0, 0,
            nullptr, nullptr, nullptr, nullptr, nullptr, nullptr, nullptr);
        dtp_s9<<<(unsigned)R, 256, 0, stream>>>(xdblf, dt_w0, dt_b0, dtf);

        // backward mamba branch (A-read flipped within each batch)
        gemm_s9<<<dim3(GM, 8), 256, 0, stream>>>(
            xn, nullptr, in_w1, xzb, 512, 128, 128, 128, 512, 1, 0, 0, 0,
            nullptr, nullptr, nullptr, nullptr, nullptr, nullptr, nullptr);
        conv_s9<<<(unsigned)R, 256, 0, stream>>>(xzb, conv_w1, conv_b1, xcb);
        gemm_s9<<<dim3(GM, 1), 256, 0, stream>>>(
            xcb, nullptr, xproj_w1, xdblb, 40, 256, 256, 256, 40, 0, 0, 0, 0,
            nullptr, nullptr, nullptr, nullptr, nullptr, nullptr, nullptr);
        dtp_s9<<<(unsigned)R, 256, 0, stream>>>(xdblb, dt_w1, dt_b1, dtbk);

        scan_s9<<<dim3(nb, 2, 16), 128, 0, stream>>>(
            dtf, dtbk, xcf, xcb, xzf, xzb, xdblf, xdblb,
            Alog0, Alog1, Dvec0, Dvec1, xzf, xzb);

        // out_proj: yg (=xz cols 0..255, lda 512) -> of / ob (flipped store)
        gemm_s9<<<dim3(GM, 2), 256, 0, stream>>>(
            xzf, nullptr, out_w0, ofb, 128, 256, 512, 256, 128, 0, 0, 0, 0,
            nullptr, nullptr, nullptr, nullptr, nullptr, nullptr, nullptr);
        gemm_s9<<<dim3(GM, 2), 256, 0, stream>>>(
            xzb, nullptr, out_w1, obb, 128, 256, 512, 256, 128, 0, 1, 0, 0,
            nullptr, nullptr, nullptr, nullptr, nullptr, nullptr, nullptr);

        // vim: (of+ob) @ vim_w + vim_b + x_seq -> xout cols 0..127    [epi 2]
        gemm_s9<<<dim3(GM, 2), 256, 0, stream>>>(
            ofb, obb, vim_w, xoutc, 128, 128, 128, 128, 192, 0, 0, 2, 0,
            vim_b, nullptr, nullptr, mainin, nullptr, nullptr, nullptr);

        dwconv_s9<<<nb * 256, 256, 0, stream>>>(
            auxin, mk3_w, mk3_b, mk5_w, mk5_b, mk_g, mk_beta, xoutc);

        // fusion: xout @ fus_w + x_in + BN -> x_fused                 [epi 3]
        gemm_s9<<<dim3(GM, 3), 256, 0, stream>>>(
            xoutc, nullptr, fus_w, xfused, 192, 192, 192, 192, 192, 0, 0, 3, 0,
            fus_b, fus_g, fus_beta, mainin, auxin, nullptr, nullptr);

        // reconstruction: x_fused @ rec_wT + BN + ReLU + x -> d_out   [epi 4]
        gemm_s9<<<dim3(GM, 4), 256, 0, stream>>>(
            xfused, nullptr, recwT, nullptr, 256, 192, 192, 192, 0, 0, 0, 4, b0,
            rec_b, rec_g, rec_beta, nullptr, nullptr, X, (float*)d_out);
    }
}

// Round 10
// 453.464 us; speedup vs baseline: 4.0692x; 1.3884x over previous
//
#include <hip/hip_runtime.h>
#include <hip/hip_bf16.h>

#define SQ2F 0.70710678f
#define BNS 0.9999950000374997f   /* 1/sqrt(1+1e-5) */
#define L_ 1024
#define TS 32                     /* scan LDS tile (steps) */
#define SEGL 128                  /* real steps per segment */
#define WARM 64                   /* warmup steps (h-reconstruction) */

__device__ __forceinline__ float silu_f(float v) { return v / (1.f + __expf(-v)); }

// ---------------- sentinel: only if even 1-batch chunk doesn't fit ----------------
__global__ __launch_bounds__(256) void sentinel_sA(float* out, int n) {
    int i = blockIdx.x * 256 + threadIdx.x;
    if (i < n) out[i] = 1.0e6f;
}

// ---------------- wavelet (chunk of nb batches starting at b0) ----------------
__global__ __launch_bounds__(256) void wavelet_sA(const float* x, float* low, float* high, int b0) {
    int idx = blockIdx.x * 256 + threadIdx.x;      // nb*131072
    int fq = idx & 31, i = (idx >> 5) & 63, c = (idx >> 11) & 63, bl = idx >> 17;
    size_t base = ((size_t)((b0 + bl) * 64 + c) * 128 + 2 * i) * 32 + fq;
    float xe = x[base];
    float xo = x[base + 32];
    int m = (bl * 64 + i) * 16 + (fq >> 1);        // chunk-local row
    int k = c * 2 + (fq & 1);
    low[(size_t)m * 128 + k]  = (xe + xo) * SQ2F;
    high[(size_t)m * 128 + k] = (xo - xe) * SQ2F;
}

// ---------------- rec_w transpose: (c,o,k,l) -> (n=(o,k,l), c) ----------------
__global__ __launch_bounds__(256) void recwT_sA(const float* rec_w, float* recwT) {
    int idx = blockIdx.x * 256 + threadIdx.x;
    if (idx >= 49152) return;
    int c = idx % 192, n = idx / 192;
    int o = n >> 2, k = (n >> 1) & 1, l2 = n & 1;
    recwT[(size_t)n * 192 + c] = rec_w[((size_t)(c * 64 + o) * 2 + k) * 2 + l2];
}

// ---------------- tiled GEMM: BM=128 BN=64 BK=16, 256 thr, 8x4 microtile ----------------
// epi: 0 plain(cflip), 1 patch(+bias,BN,ReLU -> channel-major), 2 vim(+bias+x_seq),
//      3 fus(+bias,BN,+x_in), 4 rec(+bias,BN,ReLU,+x -> scatter, global batch b0g+bb)
__global__ __launch_bounds__(256) void gemm_sA(
    const float* A, const float* A2, const float* W, float* C,
    int N, int K, int lda, int ldw, int ldc,
    int aflip, int cflip, int epi, int b0g,
    const float* bias, const float* gg, const float* bet,
    const float* xm, const float* xa, const float* xres, float* outf) {
    __shared__ float As[16][132];
    __shared__ float Ws[16][68];
    const int tid = threadIdx.x;
    const int m0 = blockIdx.x * 128;
    const int n0 = blockIdx.y * 64;
    const int tm = tid >> 4, tn = tid & 15;
    const int ra = tid >> 1, ka = (tid & 1) * 8;   // A stage: row ra, k-offset ka (8 wide)
    const int rw = tid >> 2, kw = (tid & 3) * 4;   // W stage: row rw, k-offset kw (4 wide)

    float acc[8][4];
#pragma unroll
    for (int i = 0; i < 8; ++i)
#pragma unroll
        for (int j = 0; j < 4; ++j) acc[i][j] = 0.f;

    int m_a = m0 + ra;
    if (aflip) m_a ^= 1023;
    const float* Abase = A + (size_t)m_a * lda + ka;
    const float* A2base = A2 ? (A2 + (size_t)m_a * lda + ka) : (const float*)0;
    const int nw = n0 + rw;
    const bool wok = nw < N;
    const float* Wbase = W + (size_t)nw * ldw + kw;

    for (int k0 = 0; k0 < K; k0 += 16) {
        float4 v0 = *(const float4*)(Abase + k0);
        float4 v1 = *(const float4*)(Abase + k0 + 4);
        if (A2base) {
            float4 w0 = *(const float4*)(A2base + k0);
            float4 w1 = *(const float4*)(A2base + k0 + 4);
            v0.x += w0.x; v0.y += w0.y; v0.z += w0.z; v0.w += w0.w;
            v1.x += w1.x; v1.y += w1.y; v1.z += w1.z; v1.w += w1.w;
        }
        As[ka + 0][ra] = v0.x; As[ka + 1][ra] = v0.y; As[ka + 2][ra] = v0.z; As[ka + 3][ra] = v0.w;
        As[ka + 4][ra] = v1.x; As[ka + 5][ra] = v1.y; As[ka + 6][ra] = v1.z; As[ka + 7][ra] = v1.w;
        if (wok) {
            float4 wv = *(const float4*)(Wbase + k0);
            Ws[kw + 0][rw] = wv.x; Ws[kw + 1][rw] = wv.y;
            Ws[kw + 2][rw] = wv.z; Ws[kw + 3][rw] = wv.w;
        } else {
            Ws[kw + 0][rw] = 0.f; Ws[kw + 1][rw] = 0.f;
            Ws[kw + 2][rw] = 0.f; Ws[kw + 3][rw] = 0.f;
        }
        __syncthreads();
#pragma unroll
        for (int kk = 0; kk < 16; ++kk) {
            float a[8], w[4];
#pragma unroll
            for (int i = 0; i < 8; ++i) a[i] = As[kk][tm * 8 + i];
#pragma unroll
            for (int j = 0; j < 4; ++j) w[j] = Ws[kk][tn * 4 + j];
#pragma unroll
            for (int i = 0; i < 8; ++i)
#pragma unroll
                for (int j = 0; j < 4; ++j) acc[i][j] = fmaf(a[i], w[j], acc[i][j]);
        }
        __syncthreads();
    }

#pragma unroll
    for (int i = 0; i < 8; ++i) {
        int m = m0 + tm * 8 + i;
        int bb = m >> 10, l = m & 1023;
#pragma unroll
        for (int j = 0; j < 4; ++j) {
            int n = n0 + tn * 4 + j;
            if (n >= N) continue;
            float v = acc[i][j];
            if (epi == 0) {
                int mm = cflip ? (m ^ 1023) : m;
                C[(size_t)mm * ldc + n] = v;
            } else if (epi == 1) {
                v += bias[n];
                v = v * (gg[n] * BNS) + bet[n];
                C[((size_t)(bb * N + n) << 10) + l] = fmaxf(v, 0.f);
            } else if (epi == 2) {
                C[(size_t)m * ldc + n] = v + bias[n] + xm[((size_t)(bb * 128 + n) << 10) + l];
            } else if (epi == 3) {
                float xin = (n < 128) ? xm[((size_t)(bb * 128 + n) << 10) + l]
                                      : xa[((size_t)(bb * 64 + (n - 128)) << 10) + l];
                C[(size_t)m * ldc + n] = xin + (v + bias[n]) * (gg[n] * BNS) + bet[n];
            } else {
                int o = n >> 2, kq = (n >> 1) & 1, l2 = n & 1;
                int ii = l >> 4, jj = l & 15;
                v += bias[o];
                v = fmaxf(v * (gg[o] * BNS) + bet[o], 0.f);
                size_t oidx = ((size_t)((b0g + bb) * 64 + o) * 128 + (2 * ii + kq)) * 32 + (2 * jj + l2);
                outf[oidx] = v + xres[oidx];
            }
        }
    }
}

// ---------------- LayerNorm over C=128: main_in (nb,128,1024) -> xn (rows,128) ----------------
__global__ __launch_bounds__(256) void ln_sA(const float* mainin, const float* g,
                                             const float* bt, float* xn) {
    int idx = blockIdx.x * 256 + threadIdx.x;   // chunk rows
    int bb = idx >> 10, l = idx & 1023;
    const float* src = mainin + (((size_t)bb * 128) << 10) + l;
    float s = 0.f, s2 = 0.f;
    for (int c = 0; c < 128; ++c) {
        float v = src[(size_t)c << 10];
        s += v; s2 = fmaf(v, v, s2);
    }
    float mu = s * (1.f / 128.f);
    float rs = rsqrtf(s2 * (1.f / 128.f) - mu * mu + 1e-5f);
    float* dst = xn + (size_t)idx * 128;
    for (int c = 0; c < 128; ++c) {
        float v = (src[(size_t)c << 10] - mu) * rs * g[c] + bt[c];
        dst[c] = v;
    }
}

// ---------------- causal conv (k=4) + SiLU: xz[:,:256] -> xc ----------------
__global__ __launch_bounds__(256) void conv_sA(const float* xz, const float* cw,
                                               const float* cb, float* xc) {
    int m = blockIdx.x, d = threadIdx.x;
    int l = m & 1023;
    float acc = cb[d];
    const float* w = cw + d * 4;
    for (int k = 0; k < 4; ++k) {
        int ls = l - 3 + k;
        if (ls >= 0) acc = fmaf(xz[(size_t)(m - 3 + k) * 512 + d], w[k], acc);
    }
    xc[(size_t)m * 256 + d] = silu_f(acc);
}

// ---------------- dt projection (K=8) + softplus ----------------
__global__ __launch_bounds__(256) void dtp_sA(const float* xdbl, const float* dtw,
                                              const float* dtbias, float* dtout) {
    __shared__ float x8[8];
    int m = blockIdx.x, d = threadIdx.x;
    if (d < 8) x8[d] = xdbl[(size_t)m * 40 + d];
    __syncthreads();
    float acc = dtbias[d];
    const float* w = dtw + d * 8;
    for (int r = 0; r < 8; ++r) acc = fmaf(x8[r], w[r], acc);
    float sp = (acc > 15.f) ? acc : log1pf(__expf(acc));
    dtout[(size_t)m * 256 + d] = sp;
}

// ---------------- segmented selective scan -----------------------------------------------
// 8 segments of 128 steps; segment s>0 starts WARM=64 steps early with h=0 (decay product
// over 64 steps <= e^-19 -> contribution of older state below fp32 noise; threshold 0.111).
// Block = 128 thr = 2 waves: wave1 stages tile t+1 global->LDS; wave0 computes tile t.
// yg overlays xz cols 0..255 (ld 512); z read from cols 256..511 -> disjoint.
#define STAGE_SA(L0V, SBV)                                                                  \
    {                                                                                       \
        const int l0_ = (L0V), sb_ = (SBV);                                                 \
        _Pragma("unroll")                                                                   \
        for (int f = t2; f < TS * 4; f += 64) {                                             \
            int l = f >> 2, sg = (f & 3) * 4;                                               \
            *(float4*)&dts[sb_][l][sg] = *(const float4*)(dtb + base256 + (size_t)(l0_ + l) * 256 + sg); \
            *(float4*)&xvs[sb_][l][sg] = *(const float4*)(xcb + base256 + (size_t)(l0_ + l) * 256 + sg); \
            *(float4*)&zzs[sb_][l][sg] = *(const float4*)(xzb + base512 + (size_t)(l0_ + l) * 512 + sg); \
        }                                                                                   \
        _Pragma("unroll")                                                                   \
        for (int f = t2; f < TS * 8; f += 64) {                                             \
            int l = f >> 3, sg = (f & 7) * 4;                                               \
            *(float4*)&bcs[sb_][l][sg] = *(const float4*)(xdb + base40 + (size_t)(l0_ + l) * 40 + sg);   \
        }                                                                                   \
    }

__global__ __launch_bounds__(128) void scan_sA(
    const float* dt0, const float* dt1, const float* xc0, const float* xc1,
    const float* xz0, const float* xz1, const float* xd0, const float* xd1,
    const float* al0, const float* al1, const float* D0, const float* D1,
    float* yg0, float* yg1) {
    __shared__ float dts[2][TS][16];
    __shared__ float xvs[2][TS][16];
    __shared__ float zzs[2][TS][16];
    __shared__ float bcs[2][TS][32];

    const int b = blockIdx.x;                       // chunk-local batch
    const int dir = blockIdx.y;
    const int seg = blockIdx.z >> 4;                // 0..7
    const int d0 = (blockIdx.z & 15) * 16;
    const int tid = threadIdx.x;

    const float* dtb = dir ? dt1 : dt0;
    const float* xcb = dir ? xc1 : xc0;
    const float* xzb = dir ? xz1 : xz0;
    const float* xdb = dir ? xd1 : xd0;
    float* ygb = dir ? yg1 : yg0;

    const size_t base256 = (size_t)b * L_ * 256 + d0;
    const size_t base512 = (size_t)b * L_ * 512 + 256 + d0;
    const size_t base40  = (size_t)b * L_ * 40 + 8;

    const int lstart = seg * SEGL - (seg ? WARM : 0);
    const int ntiles = (seg ? (SEGL + WARM) : SEGL) / TS;   // 6 or 4
    const int wtiles = seg ? (WARM / TS) : 0;               // warmup tiles (no store)

    const int isStage = tid >> 6;                   // wave 1 stages
    const int t2 = tid & 63;
    const int dg = t2 >> 2, q = t2 & 3;

    const float LOG2E = 1.44269504088896340736f;
    float al2[4];
    float Dd = 0.f;
    float h0 = 0.f, h1 = 0.f, h2 = 0.f, h3 = 0.f;
    if (!isStage) {
        const float* alog = (dir ? al1 : al0) + (d0 + dg) * 16 + q * 4;
#pragma unroll
        for (int n = 0; n < 4; ++n) al2[n] = -__expf(alog[n]) * LOG2E;
        Dd = (dir ? D1 : D0)[d0 + dg];
    }
    float* yp = ygb + (size_t)b * L_ * 512 + d0 + dg;   // ld = 512 (overlay)

    if (isStage) STAGE_SA(lstart, 0);
    __syncthreads();

    for (int t = 0; t < ntiles; ++t) {
        if (isStage) {
            if (t + 1 < ntiles) STAGE_SA(lstart + (t + 1) * TS, (t + 1) & 1);
        } else {
            const int cb = t & 1;
            const bool dostore = (t >= wtiles);
#pragma unroll 4
            for (int l = 0; l < TS; ++l) {
                float dt = dts[cb][l][dg];
                float xv = xvs[cb][l][dg];
                float zz = zzs[cb][l][dg];
                float4 Bv = *(const float4*)&bcs[cb][l][q * 4];
                float4 Cv = *(const float4*)&bcs[cb][l][16 + q * 4];
                float dtx = dt * xv;
                float e0 = exp2f(dt * al2[0]);
                float e1 = exp2f(dt * al2[1]);
                float e2 = exp2f(dt * al2[2]);
                float e3 = exp2f(dt * al2[3]);
                h0 = fmaf(e0, h0, dtx * Bv.x);
                h1 = fmaf(e1, h1, dtx * Bv.y);
                h2 = fmaf(e2, h2, dtx * Bv.z);
                h3 = fmaf(e3, h3, dtx * Bv.w);
                float acc = fmaf(h3, Cv.w, fmaf(h2, Cv.z, fmaf(h1, Cv.y, h0 * Cv.x)));
                acc += __shfl_xor(acc, 1);
                acc += __shfl_xor(acc, 2);
                if (dostore && q == 0) {
                    float y = fmaf(Dd, xv, acc);
                    yp[(size_t)(lstart + t * TS + l) * 512] = y * silu_f(zz);
                }
            }
        }
        __syncthreads();
    }
}

// ---------------- depthwise conv 3x3 / 5x5 + BN + SiLU ----------------
__global__ __launch_bounds__(256) void dwconv_sA(const float* auxin,
                                                 const float* mk3w, const float* mk3b,
                                                 const float* mk5w, const float* mk5b,
                                                 const float* mkg, const float* mkbeta,
                                                 float* xout) {
    int idx = blockIdx.x * 256 + threadIdx.x;   // nb*65536
    int j = idx & 15, i = (idx >> 4) & 63, c = (idx >> 10) & 63, b = idx >> 16;
    const float* src = auxin + ((size_t)(b * 64 + c) << 10);
    float acc;
    if (c < 32) {
        acc = mk3b[c];
        for (int di = -1; di <= 1; ++di)
            for (int dj = -1; dj <= 1; ++dj) {
                int ii = i + di, jj = j + dj;
                if (ii >= 0 && ii < 64 && jj >= 0 && jj < 16)
                    acc = fmaf(src[ii * 16 + jj], mk3w[(c * 3 + di + 1) * 3 + dj + 1], acc);
            }
    } else {
        int cc = c - 32;
        acc = mk5b[cc];
        for (int di = -2; di <= 2; ++di)
            for (int dj = -2; dj <= 2; ++dj) {
                int ii = i + di, jj = j + dj;
                if (ii >= 0 && ii < 64 && jj >= 0 && jj < 16)
                    acc = fmaf(src[ii * 16 + jj], mk5w[(cc * 5 + di + 2) * 5 + dj + 2], acc);
            }
    }
    float v = acc * (mkg[c] * BNS) + mkbeta[c];
    v = silu_f(v);
    xout[(size_t)((b << 10) + i * 16 + j) * 192 + 128 + c] = v;
}

// ---------------- host ----------------
extern "C" void kernel_launch(void* const* d_in, const int* in_sizes, int n_in,
                              void* d_out, int out_size, void* d_ws, size_t ws_size,
                              hipStream_t stream) {
    (void)in_sizes; (void)n_in;
    const float* X         = (const float*)d_in[0];
    const float* main_w    = (const float*)d_in[1];
    const float* main_b    = (const float*)d_in[2];
    const float* main_g    = (const float*)d_in[3];
    const float* main_beta = (const float*)d_in[4];
    const float* aux_w     = (const float*)d_in[5];
    const float* aux_b     = (const float*)d_in[6];
    const float* aux_g     = (const float*)d_in[7];
    const float* aux_beta  = (const float*)d_in[8];
    const float* ln_g      = (const float*)d_in[9];
    const float* ln_b      = (const float*)d_in[10];
    const float* vim_w     = (const float*)d_in[11];
    const float* vim_b     = (const float*)d_in[12];
    const float* mk3_w     = (const float*)d_in[13];
    const float* mk3_b     = (const float*)d_in[14];
    const float* mk5_w     = (const float*)d_in[15];
    const float* mk5_b     = (const float*)d_in[16];
    const float* mk_g      = (const float*)d_in[17];
    const float* mk_beta   = (const float*)d_in[18];
    const float* fus_w     = (const float*)d_in[19];
    const float* fus_b     = (const float*)d_in[20];
    const float* fus_g     = (const float*)d_in[21];
    const float* fus_beta  = (const float*)d_in[22];
    const float* rec_w     = (const float*)d_in[23];
    const float* rec_b     = (const float*)d_in[24];
    const float* rec_g     = (const float*)d_in[25];
    const float* rec_beta  = (const float*)d_in[26];
    const float* in_w0    = (const float*)d_in[27];
    const float* conv_w0  = (const float*)d_in[28];
    const float* conv_b0  = (const float*)d_in[29];
    const float* xproj_w0 = (const float*)d_in[30];
    const float* dt_w0    = (const float*)d_in[31];
    const float* dt_b0    = (const float*)d_in[32];
    const float* Alog0    = (const float*)d_in[33];
    const float* Dvec0    = (const float*)d_in[34];
    const float* out_w0   = (const float*)d_in[35];
    const float* in_w1    = (const float*)d_in[36];
    const float* conv_w1  = (const float*)d_in[37];
    const float* conv_b1  = (const float*)d_in[38];
    const float* xproj_w1 = (const float*)d_in[39];
    const float* dt_w1    = (const float*)d_in[40];
    const float* dt_b1    = (const float*)d_in[41];
    const float* Alog1    = (const float*)d_in[42];
    const float* Dvec1    = (const float*)d_in[43];
    const float* out_w1   = (const float*)d_in[44];

    // choose batches-per-chunk so the fp32 workspace fits ws_size
    const size_t wf = ws_size / sizeof(float);
    int nb = 0;
    if      (49152 + (size_t)8 * 1024 * 2576 <= wf) nb = 8;
    else if (49152 + (size_t)4 * 1024 * 2576 <= wf) nb = 4;
    else if (49152 + (size_t)2 * 1024 * 2576 <= wf) nb = 2;
    else if (49152 + (size_t)1 * 1024 * 2576 <= wf) nb = 1;
    if (nb == 0) {
        sentinel_sA<<<(out_size + 255) / 256, 256, 0, stream>>>((float*)d_out, out_size);
        return;
    }

    float* ws = (float*)d_ws;
    float* recwT = ws;                       // 49152 floats
    const size_t R = (size_t)nb * 1024;
    float* xzf    = ws + 49152;
    float* xzb    = xzf + R * 512;
    float* mainin = xzb + R * 512;
    float* auxin  = mainin + R * 128;
    float* xn     = auxin + R * 64;
    float* ofb    = xn;                      // overlay (xn dead after in_proj_b)
    float* lowb   = xn + R * 128;
    float* highb  = lowb + R * 128;
    float* dtf    = lowb;                    // overlay (low+high dead after patch)
    float* xcf    = highb + R * 128;
    float* xcb    = xcf + R * 256;
    float* xoutc  = xcf;                     // overlay (xc_f dead after scan)
    float* xfused = xcb;                     // overlay (xc_b dead after scan)
    float* xdblf  = xcb + R * 256;
    float* xdblb  = xdblf + R * 40;
    float* dtbk   = xdblb + R * 40;
    float* obb    = dtbk + R * 256;

    recwT_sA<<<192, 256, 0, stream>>>(rec_w, recwT);
    const unsigned GM = (unsigned)(R / 128);   // M-tiles per chunk

    for (int b0 = 0; b0 < 8; b0 += nb) {
        wavelet_sA<<<nb * 512, 256, 0, stream>>>(X, lowb, highb, b0);

        // patch_proj main/aux                                         [epi 1]
        gemm_sA<<<dim3(GM, 2), 256, 0, stream>>>(
            lowb, nullptr, main_w, mainin, 128, 128, 128, 128, 0, 0, 0, 1, 0,
            main_b, main_g, main_beta, nullptr, nullptr, nullptr, nullptr);
        gemm_sA<<<dim3(GM, 1), 256, 0, stream>>>(
            highb, nullptr, aux_w, auxin, 64, 128, 128, 128, 0, 0, 0, 1, 0,
            aux_b, aux_g, aux_beta, nullptr, nullptr, nullptr, nullptr);
        ln_sA<<<nb * 4, 256, 0, stream>>>(mainin, ln_g, ln_b, xn);

        // forward mamba branch
        gemm_sA<<<dim3(GM, 8), 256, 0, stream>>>(
            xn, nullptr, in_w0, xzf, 512, 128, 128, 128, 512, 0, 0, 0, 0,
            nullptr, nullptr, nullptr, nullptr, nullptr, nullptr, nullptr);
        conv_sA<<<(unsigned)R, 256, 0, stream>>>(xzf, conv_w0, conv_b0, xcf);
        gemm_sA<<<dim3(GM, 1), 256, 0, stream>>>(
            xcf, nullptr, xproj_w0, xdblf, 40, 256, 256, 256, 40, 0, 0, 0, 0,
            nullptr, nullptr, nullptr, nullptr, nullptr, nullptr, nullptr);
        dtp_sA<<<(unsigned)R, 256, 0, stream>>>(xdblf, dt_w0, dt_b0, dtf);

        // backward mamba branch (A-read flipped within each batch)
        gemm_sA<<<dim3(GM, 8), 256, 0, stream>>>(
            xn, nullptr, in_w1, xzb, 512, 128, 128, 128, 512, 1, 0, 0, 0,
            nullptr, nullptr, nullptr, nullptr, nullptr, nullptr, nullptr);
        conv_sA<<<(unsigned)R, 256, 0, stream>>>(xzb, conv_w1, conv_b1, xcb);
        gemm_sA<<<dim3(GM, 1), 256, 0, stream>>>(
            xcb, nullptr, xproj_w1, xdblb, 40, 256, 256, 256, 40, 0, 0, 0, 0,
            nullptr, nullptr, nullptr, nullptr, nullptr, nullptr, nullptr);
        dtp_sA<<<(unsigned)R, 256, 0, stream>>>(xdblb, dt_w1, dt_b1, dtbk);

        // segmented scan: 8 segs x 16 d-groups in z
        scan_sA<<<dim3(nb, 2, 128), 128, 0, stream>>>(
            dtf, dtbk, xcf, xcb, xzf, xzb, xdblf, xdblb,
            Alog0, Alog1, Dvec0, Dvec1, xzf, xzb);

        // out_proj: yg (=xz cols 0..255, lda 512) -> of / ob (flipped store)
        gemm_sA<<<dim3(GM, 2), 256, 0, stream>>>(
            xzf, nullptr, out_w0, ofb, 128, 256, 512, 256, 128, 0, 0, 0, 0,
            nullptr, nullptr, nullptr, nullptr, nullptr, nullptr, nullptr);
        gemm_sA<<<dim3(GM, 2), 256, 0, stream>>>(
            xzb, nullptr, out_w1, obb, 128, 256, 512, 256, 128, 0, 1, 0, 0,
            nullptr, nullptr, nullptr, nullptr, nullptr, nullptr, nullptr);

        // vim: (of+ob) @ vim_w + vim_b + x_seq -> xout cols 0..127    [epi 2]
        gemm_sA<<<dim3(GM, 2), 256, 0, stream>>>(
            ofb, obb, vim_w, xoutc, 128, 128, 128, 128, 192, 0, 0, 2, 0,
            vim_b, nullptr, nullptr, mainin, nullptr, nullptr, nullptr);

        dwconv_sA<<<nb * 256, 256, 0, stream>>>(
            auxin, mk3_w, mk3_b, mk5_w, mk5_b, mk_g, mk_beta, xoutc);

        // fusion: xout @ fus_w + x_in + BN -> x_fused                 [epi 3]
        gemm_sA<<<dim3(GM, 3), 256, 0, stream>>>(
            xoutc, nullptr, fus_w, xfused, 192, 192, 192, 192, 192, 0, 0, 3, 0,
            fus_b, fus_g, fus_beta, mainin, auxin, nullptr, nullptr);

        // reconstruction: x_fused @ rec_wT + BN + ReLU + x -> d_out   [epi 4]
        gemm_sA<<<dim3(GM, 4), 256, 0, stream>>>(
            xfused, nullptr, recwT, nullptr, 256, 192, 192, 192, 0, 0, 0, 4, b0,
            rec_b, rec_g, rec_beta, nullptr, nullptr, X, (float*)d_out);
    }
}

// Round 11
// 326.871 us; speedup vs baseline: 5.6451x; 1.3873x over previous
//
#include <hip/hip_runtime.h>
#include <hip/hip_bf16.h>

#define SQ2F 0.70710678f
#define BNS 0.9999950000374997f   /* 1/sqrt(1+1e-5) */
#define L_ 1024
#define TS 32                     /* scan LDS tile (steps) */
#define SEGL 128                  /* real steps per segment */
#define WARM 64                   /* warmup steps (h-reconstruction) */

__device__ __forceinline__ float silu_f(float v) { return v / (1.f + __expf(-v)); }

// ---------------- sentinel: only if even 1-batch chunk doesn't fit ----------------
__global__ __launch_bounds__(256) void sentinel_sB(float* out, int n) {
    int i = blockIdx.x * 256 + threadIdx.x;
    if (i < n) out[i] = 1.0e6f;
}

// ---------------- wavelet (chunk of nb batches starting at b0) ----------------
__global__ __launch_bounds__(256) void wavelet_sB(const float* x, float* low, float* high, int b0) {
    int idx = blockIdx.x * 256 + threadIdx.x;      // nb*131072
    int fq = idx & 31, i = (idx >> 5) & 63, c = (idx >> 11) & 63, bl = idx >> 17;
    size_t base = ((size_t)((b0 + bl) * 64 + c) * 128 + 2 * i) * 32 + fq;
    float xe = x[base];
    float xo = x[base + 32];
    int m = (bl * 64 + i) * 16 + (fq >> 1);        // chunk-local row
    int k = c * 2 + (fq & 1);
    low[(size_t)m * 128 + k]  = (xe + xo) * SQ2F;
    high[(size_t)m * 128 + k] = (xo - xe) * SQ2F;
}

// ---------------- rec_w transpose: (c,o,k,l) -> (n=(o,k,l), c) ----------------
__global__ __launch_bounds__(256) void recwT_sB(const float* rec_w, float* recwT) {
    int idx = blockIdx.x * 256 + threadIdx.x;
    if (idx >= 49152) return;
    int c = idx % 192, n = idx / 192;
    int o = n >> 2, k = (n >> 1) & 1, l2 = n & 1;
    recwT[(size_t)n * 192 + c] = rec_w[((size_t)(c * 64 + o) * 2 + k) * 2 + l2];
}

// ---------------- W concat for fused out_proj: wcat[n][0:256]=W0[n], [256:512]=W1[n] ----
__global__ __launch_bounds__(256) void wcat_sB(const float* w0, const float* w1, float* wcat) {
    int idx = blockIdx.x * 256 + threadIdx.x;      // 128*512 = 65536
    int k = idx & 511, n = idx >> 9;
    wcat[(size_t)n * 512 + k] = (k < 256) ? w0[(size_t)n * 256 + k]
                                          : w1[(size_t)n * 256 + (k - 256)];
}

// ---------------- gemm64: BM=64 BN=64 BK=16, 256 thr, 4x4 microtile, double-buffered ----
// C[m,n] = sum_k Asrc[m,k]*W[n,k].
// adual: k<256 from A[row m], k>=256 from A2[row m^1023] (lda applies to both).
// epi: 0 plain(cflip), 1 patch(+bias,BN,ReLU -> channel-major), 2 vim(+bias+x_seq),
//      3 fus(+bias,BN,+x_in), 4 rec(+bias,BN,ReLU,+x -> scatter, global batch b0g+bb)
__global__ __launch_bounds__(256) void gemm64_sB(
    const float* A, const float* A2, const float* W, float* C,
    int N, int K, int lda, int ldw, int ldc,
    int aflip, int cflip, int adual, int epi, int b0g,
    const float* bias, const float* gg, const float* bet,
    const float* xm, const float* xa, const float* xres, float* outf) {
    __shared__ float As[2][16][68];
    __shared__ float Ws[2][16][68];
    const int tid = threadIdx.x;
    const int m0 = blockIdx.x * 64;
    const int n0 = blockIdx.y * 64;
    const int tm = tid >> 4, tn = tid & 15;
    const int rs = tid >> 2, ks = (tid & 3) * 4;   // staging: row rs, k-offset ks (4 wide)

    float acc[4][4];
#pragma unroll
    for (int i = 0; i < 4; ++i)
#pragma unroll
        for (int j = 0; j < 4; ++j) acc[i][j] = 0.f;

    int m_a = m0 + rs;
    if (aflip) m_a ^= 1023;
    const float* Abase = A + (size_t)m_a * lda + ks;
    const float* A2base = adual ? (A2 + (size_t)((m0 + rs) ^ 1023) * lda + ks - 256)
                                : (const float*)0;
    const int nw = n0 + rs;
    const bool wok = nw < N;
    const float* Wbase = W + (size_t)nw * ldw + ks;

    const int nk = K >> 4;
    float4 va, vw;

    // prologue: load tile 0
    va = adual && (0 + ks) >= 256 ? *(const float4*)(A2base + 0)
                                  : *(const float4*)(Abase + 0);
    vw = wok ? *(const float4*)(Wbase + 0) : float4{0.f, 0.f, 0.f, 0.f};
    As[0][ks + 0][rs] = va.x; As[0][ks + 1][rs] = va.y;
    As[0][ks + 2][rs] = va.z; As[0][ks + 3][rs] = va.w;
    Ws[0][ks + 0][rs] = vw.x; Ws[0][ks + 1][rs] = vw.y;
    Ws[0][ks + 2][rs] = vw.z; Ws[0][ks + 3][rs] = vw.w;
    __syncthreads();

    for (int t = 0; t < nk; ++t) {
        if (t + 1 < nk) {
            const int k0 = (t + 1) << 4;
            va = adual && (k0 + ks) >= 256 ? *(const float4*)(A2base + k0)
                                           : *(const float4*)(Abase + k0);
            vw = wok ? *(const float4*)(Wbase + k0) : float4{0.f, 0.f, 0.f, 0.f};
        }
        const int cb = t & 1;
#pragma unroll
        for (int kk = 0; kk < 16; ++kk) {
            float4 a = *(const float4*)&As[cb][kk][tm * 4];
            float4 w = *(const float4*)&Ws[cb][kk][tn * 4];
            acc[0][0] = fmaf(a.x, w.x, acc[0][0]); acc[0][1] = fmaf(a.x, w.y, acc[0][1]);
            acc[0][2] = fmaf(a.x, w.z, acc[0][2]); acc[0][3] = fmaf(a.x, w.w, acc[0][3]);
            acc[1][0] = fmaf(a.y, w.x, acc[1][0]); acc[1][1] = fmaf(a.y, w.y, acc[1][1]);
            acc[1][2] = fmaf(a.y, w.z, acc[1][2]); acc[1][3] = fmaf(a.y, w.w, acc[1][3]);
            acc[2][0] = fmaf(a.z, w.x, acc[2][0]); acc[2][1] = fmaf(a.z, w.y, acc[2][1]);
            acc[2][2] = fmaf(a.z, w.z, acc[2][2]); acc[2][3] = fmaf(a.z, w.w, acc[2][3]);
            acc[3][0] = fmaf(a.w, w.x, acc[3][0]); acc[3][1] = fmaf(a.w, w.y, acc[3][1]);
            acc[3][2] = fmaf(a.w, w.z, acc[3][2]); acc[3][3] = fmaf(a.w, w.w, acc[3][3]);
        }
        if (t + 1 < nk) {
            const int nb2 = (t + 1) & 1;
            As[nb2][ks + 0][rs] = va.x; As[nb2][ks + 1][rs] = va.y;
            As[nb2][ks + 2][rs] = va.z; As[nb2][ks + 3][rs] = va.w;
            Ws[nb2][ks + 0][rs] = vw.x; Ws[nb2][ks + 1][rs] = vw.y;
            Ws[nb2][ks + 2][rs] = vw.z; Ws[nb2][ks + 3][rs] = vw.w;
        }
        __syncthreads();
    }

#pragma unroll
    for (int i = 0; i < 4; ++i) {
        int m = m0 + tm * 4 + i;
        int bb = m >> 10, l = m & 1023;
#pragma unroll
        for (int j = 0; j < 4; ++j) {
            int n = n0 + tn * 4 + j;
            if (n >= N) continue;
            float v = acc[i][j];
            if (epi == 0) {
                int mm = cflip ? (m ^ 1023) : m;
                C[(size_t)mm * ldc + n] = v;
            } else if (epi == 1) {
                v += bias[n];
                v = v * (gg[n] * BNS) + bet[n];
                C[((size_t)(bb * N + n) << 10) + l] = fmaxf(v, 0.f);
            } else if (epi == 2) {
                C[(size_t)m * ldc + n] = v + bias[n] + xm[((size_t)(bb * 128 + n) << 10) + l];
            } else if (epi == 3) {
                float xin = (n < 128) ? xm[((size_t)(bb * 128 + n) << 10) + l]
                                      : xa[((size_t)(bb * 64 + (n - 128)) << 10) + l];
                C[(size_t)m * ldc + n] = xin + (v + bias[n]) * (gg[n] * BNS) + bet[n];
            } else {
                int o = n >> 2, kq = (n >> 1) & 1, l2 = n & 1;
                int ii = l >> 4, jj = l & 15;
                v += bias[o];
                v = fmaxf(v * (gg[o] * BNS) + bet[o], 0.f);
                size_t oidx = ((size_t)((b0g + bb) * 64 + o) * 128 + (2 * ii + kq)) * 32 + (2 * jj + l2);
                outf[oidx] = v + xres[oidx];
            }
        }
    }
}

// ---------------- LayerNorm via LDS transpose: main_in (nb,128,1024) -> xn (rows,128) ----
__global__ __launch_bounds__(256) void ln_sB(const float* mainin, const float* g,
                                             const float* bt, float* xn) {
    __shared__ float tile[128][65];
    __shared__ float red0[4][64];
    __shared__ float red1[4][64];
    __shared__ float mu_s[64];
    __shared__ float rs_s[64];
    const int bb = blockIdx.y;
    const int l0 = blockIdx.x * 64;
    const int tid = threadIdx.x;
    for (int idx = tid; idx < 128 * 64; idx += 256) {
        int c = idx >> 6, l = idx & 63;
        tile[c][l] = mainin[((size_t)(bb * 128 + c) << 10) + l0 + l];
    }
    __syncthreads();
    {
        int l = tid & 63, q = tid >> 6;
        float s = 0.f, s2 = 0.f;
#pragma unroll
        for (int c0 = 0; c0 < 32; ++c0) {
            float v = tile[q * 32 + c0][l];
            s += v; s2 = fmaf(v, v, s2);
        }
        red0[q][l] = s; red1[q][l] = s2;
    }
    __syncthreads();
    if (tid < 64) {
        float S = red0[0][tid] + red0[1][tid] + red0[2][tid] + red0[3][tid];
        float S2 = red1[0][tid] + red1[1][tid] + red1[2][tid] + red1[3][tid];
        float mu = S * (1.f / 128.f);
        float var = S2 * (1.f / 128.f) - mu * mu;
        mu_s[tid] = mu;
        rs_s[tid] = rsqrtf(var + 1e-5f);
    }
    __syncthreads();
    for (int idx = tid; idx < 128 * 64; idx += 256) {
        int l = idx >> 7, c = idx & 127;
        float v = (tile[c][l] - mu_s[l]) * rs_s[l] * g[c] + bt[c];
        xn[((size_t)(bb << 10) + l0 + l) * 128 + c] = v;
    }
}

// ---------------- causal conv (k=4) + SiLU: xz[:,:256] -> xc ----------------
__global__ __launch_bounds__(256) void conv_sB(const float* xz, const float* cw,
                                               const float* cb, float* xc) {
    int m = blockIdx.x, d = threadIdx.x;
    int l = m & 1023;
    float acc = cb[d];
    const float* w = cw + d * 4;
    for (int k = 0; k < 4; ++k) {
        int ls = l - 3 + k;
        if (ls >= 0) acc = fmaf(xz[(size_t)(m - 3 + k) * 512 + d], w[k], acc);
    }
    xc[(size_t)m * 256 + d] = silu_f(acc);
}

// ---------------- dt projection (K=8) + softplus ----------------
__global__ __launch_bounds__(256) void dtp_sB(const float* xdbl, const float* dtw,
                                              const float* dtbias, float* dtout) {
    __shared__ float x8[8];
    int m = blockIdx.x, d = threadIdx.x;
    if (d < 8) x8[d] = xdbl[(size_t)m * 40 + d];
    __syncthreads();
    float acc = dtbias[d];
    const float* w = dtw + d * 8;
    for (int r = 0; r < 8; ++r) acc = fmaf(x8[r], w[r], acc);
    float sp = (acc > 15.f) ? acc : log1pf(__expf(acc));
    dtout[(size_t)m * 256 + d] = sp;
}

// ---------------- segmented selective scan (as round 10; 76 us verified) ----------------
#define STAGE_SB(L0V, SBV)                                                                  \
    {                                                                                       \
        const int l0_ = (L0V), sb_ = (SBV);                                                 \
        _Pragma("unroll")                                                                   \
        for (int f = t2; f < TS * 4; f += 64) {                                             \
            int l = f >> 2, sg = (f & 3) * 4;                                               \
            *(float4*)&dts[sb_][l][sg] = *(const float4*)(dtb + base256 + (size_t)(l0_ + l) * 256 + sg); \
            *(float4*)&xvs[sb_][l][sg] = *(const float4*)(xcb + base256 + (size_t)(l0_ + l) * 256 + sg); \
            *(float4*)&zzs[sb_][l][sg] = *(const float4*)(xzb + base512 + (size_t)(l0_ + l) * 512 + sg); \
        }                                                                                   \
        _Pragma("unroll")                                                                   \
        for (int f = t2; f < TS * 8; f += 64) {                                             \
            int l = f >> 3, sg = (f & 7) * 4;                                               \
            *(float4*)&bcs[sb_][l][sg] = *(const float4*)(xdb + base40 + (size_t)(l0_ + l) * 40 + sg);   \
        }                                                                                   \
    }

__global__ __launch_bounds__(128) void scan_sB(
    const float* dt0, const float* dt1, const float* xc0, const float* xc1,
    const float* xz0, const float* xz1, const float* xd0, const float* xd1,
    const float* al0, const float* al1, const float* D0, const float* D1,
    float* yg0, float* yg1) {
    __shared__ float dts[2][TS][16];
    __shared__ float xvs[2][TS][16];
    __shared__ float zzs[2][TS][16];
    __shared__ float bcs[2][TS][32];

    const int b = blockIdx.x;
    const int dir = blockIdx.y;
    const int seg = blockIdx.z >> 4;                // 0..7
    const int d0 = (blockIdx.z & 15) * 16;
    const int tid = threadIdx.x;

    const float* dtb = dir ? dt1 : dt0;
    const float* xcb = dir ? xc1 : xc0;
    const float* xzb = dir ? xz1 : xz0;
    const float* xdb = dir ? xd1 : xd0;
    float* ygb = dir ? yg1 : yg0;

    const size_t base256 = (size_t)b * L_ * 256 + d0;
    const size_t base512 = (size_t)b * L_ * 512 + 256 + d0;
    const size_t base40  = (size_t)b * L_ * 40 + 8;

    const int lstart = seg * SEGL - (seg ? WARM : 0);
    const int ntiles = (seg ? (SEGL + WARM) : SEGL) / TS;   // 6 or 4
    const int wtiles = seg ? (WARM / TS) : 0;

    const int isStage = tid >> 6;
    const int t2 = tid & 63;
    const int dg = t2 >> 2, q = t2 & 3;

    const float LOG2E = 1.44269504088896340736f;
    float al2[4];
    float Dd = 0.f;
    float h0 = 0.f, h1 = 0.f, h2 = 0.f, h3 = 0.f;
    if (!isStage) {
        const float* alog = (dir ? al1 : al0) + (d0 + dg) * 16 + q * 4;
#pragma unroll
        for (int n = 0; n < 4; ++n) al2[n] = -__expf(alog[n]) * LOG2E;
        Dd = (dir ? D1 : D0)[d0 + dg];
    }
    float* yp = ygb + (size_t)b * L_ * 512 + d0 + dg;   // ld = 512 (overlay)

    if (isStage) STAGE_SB(lstart, 0);
    __syncthreads();

    for (int t = 0; t < ntiles; ++t) {
        if (isStage) {
            if (t + 1 < ntiles) STAGE_SB(lstart + (t + 1) * TS, (t + 1) & 1);
        } else {
            const int cb = t & 1;
            const bool dostore = (t >= wtiles);
#pragma unroll 4
            for (int l = 0; l < TS; ++l) {
                float dt = dts[cb][l][dg];
                float xv = xvs[cb][l][dg];
                float zz = zzs[cb][l][dg];
                float4 Bv = *(const float4*)&bcs[cb][l][q * 4];
                float4 Cv = *(const float4*)&bcs[cb][l][16 + q * 4];
                float dtx = dt * xv;
                float e0 = exp2f(dt * al2[0]);
                float e1 = exp2f(dt * al2[1]);
                float e2 = exp2f(dt * al2[2]);
                float e3 = exp2f(dt * al2[3]);
                h0 = fmaf(e0, h0, dtx * Bv.x);
                h1 = fmaf(e1, h1, dtx * Bv.y);
                h2 = fmaf(e2, h2, dtx * Bv.z);
                h3 = fmaf(e3, h3, dtx * Bv.w);
                float acc = fmaf(h3, Cv.w, fmaf(h2, Cv.z, fmaf(h1, Cv.y, h0 * Cv.x)));
                acc += __shfl_xor(acc, 1);
                acc += __shfl_xor(acc, 2);
                if (dostore && q == 0) {
                    float y = fmaf(Dd, xv, acc);
                    yp[(size_t)(lstart + t * TS + l) * 512] = y * silu_f(zz);
                }
            }
        }
        __syncthreads();
    }
}

// ---------------- depthwise conv 3x3 / 5x5 + BN + SiLU ----------------
__global__ __launch_bounds__(256) void dwconv_sB(const float* auxin,
                                                 const float* mk3w, const float* mk3b,
                                                 const float* mk5w, const float* mk5b,
                                                 const float* mkg, const float* mkbeta,
                                                 float* xout) {
    int idx = blockIdx.x * 256 + threadIdx.x;   // nb*65536
    int j = idx & 15, i = (idx >> 4) & 63, c = (idx >> 10) & 63, b = idx >> 16;
    const float* src = auxin + ((size_t)(b * 64 + c) << 10);
    float acc;
    if (c < 32) {
        acc = mk3b[c];
        for (int di = -1; di <= 1; ++di)
            for (int dj = -1; dj <= 1; ++dj) {
                int ii = i + di, jj = j + dj;
                if (ii >= 0 && ii < 64 && jj >= 0 && jj < 16)
                    acc = fmaf(src[ii * 16 + jj], mk3w[(c * 3 + di + 1) * 3 + dj + 1], acc);
            }
    } else {
        int cc = c - 32;
        acc = mk5b[cc];
        for (int di = -2; di <= 2; ++di)
            for (int dj = -2; dj <= 2; ++dj) {
                int ii = i + di, jj = j + dj;
                if (ii >= 0 && ii < 64 && jj >= 0 && jj < 16)
                    acc = fmaf(src[ii * 16 + jj], mk5w[(cc * 5 + di + 2) * 5 + dj + 2], acc);
            }
    }
    float v = acc * (mkg[c] * BNS) + mkbeta[c];
    v = silu_f(v);
    xout[(size_t)((b << 10) + i * 16 + j) * 192 + 128 + c] = v;
}

// ---------------- host ----------------
extern "C" void kernel_launch(void* const* d_in, const int* in_sizes, int n_in,
                              void* d_out, int out_size, void* d_ws, size_t ws_size,
                              hipStream_t stream) {
    (void)in_sizes; (void)n_in;
    const float* X         = (const float*)d_in[0];
    const float* main_w    = (const float*)d_in[1];
    const float* main_b    = (const float*)d_in[2];
    const float* main_g    = (const float*)d_in[3];
    const float* main_beta = (const float*)d_in[4];
    const float* aux_w     = (const float*)d_in[5];
    const float* aux_b     = (const float*)d_in[6];
    const float* aux_g     = (const float*)d_in[7];
    const float* aux_beta  = (const float*)d_in[8];
    const float* ln_g      = (const float*)d_in[9];
    const float* ln_b      = (const float*)d_in[10];
    const float* vim_w     = (const float*)d_in[11];
    const float* vim_b     = (const float*)d_in[12];
    const float* mk3_w     = (const float*)d_in[13];
    const float* mk3_b     = (const float*)d_in[14];
    const float* mk5_w     = (const float*)d_in[15];
    const float* mk5_b     = (const float*)d_in[16];
    const float* mk_g      = (const float*)d_in[17];
    const float* mk_beta   = (const float*)d_in[18];
    const float* fus_w     = (const float*)d_in[19];
    const float* fus_b     = (const float*)d_in[20];
    const float* fus_g     = (const float*)d_in[21];
    const float* fus_beta  = (const float*)d_in[22];
    const float* rec_w     = (const float*)d_in[23];
    const float* rec_b     = (const float*)d_in[24];
    const float* rec_g     = (const float*)d_in[25];
    const float* rec_beta  = (const float*)d_in[26];
    const float* in_w0    = (const float*)d_in[27];
    const float* conv_w0  = (const float*)d_in[28];
    const float* conv_b0  = (const float*)d_in[29];
    const float* xproj_w0 = (const float*)d_in[30];
    const float* dt_w0    = (const float*)d_in[31];
    const float* dt_b0    = (const float*)d_in[32];
    const float* Alog0    = (const float*)d_in[33];
    const float* Dvec0    = (const float*)d_in[34];
    const float* out_w0   = (const float*)d_in[35];
    const float* in_w1    = (const float*)d_in[36];
    const float* conv_w1  = (const float*)d_in[37];
    const float* conv_b1  = (const float*)d_in[38];
    const float* xproj_w1 = (const float*)d_in[39];
    const float* dt_w1    = (const float*)d_in[40];
    const float* dt_b1    = (const float*)d_in[41];
    const float* Alog1    = (const float*)d_in[42];
    const float* Dvec1    = (const float*)d_in[43];
    const float* out_w1   = (const float*)d_in[44];

    // workspace: wcat (65536) + recwT (49152) + chunk buffers
    const size_t wf = ws_size / sizeof(float);
    const size_t FIX = 65536 + 49152;
    int nb = 0;
    if      (FIX + (size_t)8 * 1024 * 2576 <= wf) nb = 8;
    else if (FIX + (size_t)4 * 1024 * 2576 <= wf) nb = 4;
    else if (FIX + (size_t)2 * 1024 * 2576 <= wf) nb = 2;
    else if (FIX + (size_t)1 * 1024 * 2576 <= wf) nb = 1;
    if (nb == 0) {
        sentinel_sB<<<(out_size + 255) / 256, 256, 0, stream>>>((float*)d_out, out_size);
        return;
    }

    float* ws = (float*)d_ws;
    float* wcat  = ws;                       // 65536 floats (128x512)
    float* recwT = ws + 65536;               // 49152 floats
    const size_t R = (size_t)nb * 1024;
    float* xzf    = ws + FIX;
    float* xzb    = xzf + R * 512;
    float* mainin = xzb + R * 512;
    float* auxin  = mainin + R * 128;
    float* xn     = auxin + R * 64;
    float* vimin  = xn;                      // overlay (xn dead after in_proj_b)
    float* lowb   = xn + R * 128;
    float* highb  = lowb + R * 128;
    float* dtf    = lowb;                    // overlay (low+high dead after patch)
    float* xcf    = highb + R * 128;
    float* xcb    = xcf + R * 256;
    float* xoutc  = xcf;                     // overlay (xc_f dead after scan)
    float* xfused = xcb;                     // overlay (xc_b dead after scan)
    float* xdblf  = xcb + R * 256;
    float* xdblb  = xdblf + R * 40;
    float* dtbk   = xdblb + R * 40;

    recwT_sB<<<192, 256, 0, stream>>>(rec_w, recwT);
    wcat_sB<<<256, 256, 0, stream>>>(out_w0, out_w1, wcat);
    const unsigned GM = (unsigned)(R / 64);    // 64-row M-tiles per chunk

    for (int b0 = 0; b0 < 8; b0 += nb) {
        wavelet_sB<<<nb * 512, 256, 0, stream>>>(X, lowb, highb, b0);

        // patch_proj main/aux                                         [epi 1]
        gemm64_sB<<<dim3(GM, 2), 256, 0, stream>>>(
            lowb, nullptr, main_w, mainin, 128, 128, 128, 128, 0, 0, 0, 0, 1, 0,
            main_b, main_g, main_beta, nullptr, nullptr, nullptr, nullptr);
        gemm64_sB<<<dim3(GM, 1), 256, 0, stream>>>(
            highb, nullptr, aux_w, auxin, 64, 128, 128, 128, 0, 0, 0, 0, 1, 0,
            aux_b, aux_g, aux_beta, nullptr, nullptr, nullptr, nullptr);
        ln_sB<<<dim3(16, nb), 256, 0, stream>>>(mainin, ln_g, ln_b, xn);

        // forward mamba branch
        gemm64_sB<<<dim3(GM, 8), 256, 0, stream>>>(
            xn, nullptr, in_w0, xzf, 512, 128, 128, 128, 512, 0, 0, 0, 0, 0,
            nullptr, nullptr, nullptr, nullptr, nullptr, nullptr, nullptr);
        conv_sB<<<(unsigned)R, 256, 0, stream>>>(xzf, conv_w0, conv_b0, xcf);
        gemm64_sB<<<dim3(GM, 1), 256, 0, stream>>>(
            xcf, nullptr, xproj_w0, xdblf, 40, 256, 256, 256, 40, 0, 0, 0, 0, 0,
            nullptr, nullptr, nullptr, nullptr, nullptr, nullptr, nullptr);
        dtp_sB<<<(unsigned)R, 256, 0, stream>>>(xdblf, dt_w0, dt_b0, dtf);

        // backward mamba branch (A-read flipped within each batch)
        gemm64_sB<<<dim3(GM, 8), 256, 0, stream>>>(
            xn, nullptr, in_w1, xzb, 512, 128, 128, 128, 512, 1, 0, 0, 0, 0,
            nullptr, nullptr, nullptr, nullptr, nullptr, nullptr, nullptr);
        conv_sB<<<(unsigned)R, 256, 0, stream>>>(xzb, conv_w1, conv_b1, xcb);
        gemm64_sB<<<dim3(GM, 1), 256, 0, stream>>>(
            xcb, nullptr, xproj_w1, xdblb, 40, 256, 256, 256, 40, 0, 0, 0, 0, 0,
            nullptr, nullptr, nullptr, nullptr, nullptr, nullptr, nullptr);
        dtp_sB<<<(unsigned)R, 256, 0, stream>>>(xdblb, dt_w1, dt_b1, dtbk);

        // segmented scan: 8 segs x 16 d-groups in z
        scan_sB<<<dim3(nb, 2, 128), 128, 0, stream>>>(
            dtf, dtbk, xcf, xcb, xzf, xzb, xdblf, xdblb,
            Alog0, Alog1, Dvec0, Dvec1, xzf, xzb);

        // fused out_proj f+b: vimin[l] = yg_f[l]@W0^T + yg_b[l^1023]@W1^T   [adual, K=512]
        gemm64_sB<<<dim3(GM, 2), 256, 0, stream>>>(
            xzf, xzb, wcat, vimin, 128, 512, 512, 512, 128, 0, 0, 1, 0, 0,
            nullptr, nullptr, nullptr, nullptr, nullptr, nullptr, nullptr);

        // vim: vimin @ vim_w + vim_b + x_seq -> xout cols 0..127      [epi 2]
        gemm64_sB<<<dim3(GM, 2), 256, 0, stream>>>(
            vimin, nullptr, vim_w, xoutc, 128, 128, 128, 128, 192, 0, 0, 0, 2, 0,
            vim_b, nullptr, nullptr, mainin, nullptr, nullptr, nullptr);

        dwconv_sB<<<nb * 256, 256, 0, stream>>>(
            auxin, mk3_w, mk3_b, mk5_w, mk5_b, mk_g, mk_beta, xoutc);

        // fusion: xout @ fus_w + x_in + BN -> x_fused                 [epi 3]
        gemm64_sB<<<dim3(GM, 3), 256, 0, stream>>>(
            xoutc, nullptr, fus_w, xfused, 192, 192, 192, 192, 192, 0, 0, 0, 3, 0,
            fus_b, fus_g, fus_beta, mainin, auxin, nullptr, nullptr);

        // reconstruction: x_fused @ rec_wT + BN + ReLU + x -> d_out   [epi 4]
        gemm64_sB<<<dim3(GM, 4), 256, 0, stream>>>(
            xfused, nullptr, recwT, nullptr, 256, 192, 192, 192, 0, 0, 0, 0, 4, b0,
            rec_b, rec_g, rec_beta, nullptr, nullptr, X, (float*)d_out);
    }
}

// Round 12
// 275.659 us; speedup vs baseline: 6.6938x; 1.1858x over previous
//
#include <hip/hip_runtime.h>
#include <hip/hip_bf16.h>

#define SQ2F 0.70710678f
#define BNS 0.9999950000374997f   /* 1/sqrt(1+1e-5) */
#define L_ 1024
#define TS 32                     /* scan LDS tile (steps) */
#define SEGL 128                  /* real steps per segment */
#define WARM 64                   /* warmup steps (h-reconstruction) */

typedef __attribute__((ext_vector_type(8))) short bf16x8;
typedef __attribute__((ext_vector_type(8))) unsigned short us8;
typedef __attribute__((ext_vector_type(4))) float f32x4;

__device__ __forceinline__ float silu_f(float v) { return v / (1.f + __expf(-v)); }
__device__ __forceinline__ unsigned short f2b(float f) {
    unsigned u = __float_as_uint(f);
    return (unsigned short)((u + 0x7FFFu + ((u >> 16) & 1u)) >> 16);   // RNE
}

// ---------------- sentinel ----------------
__global__ __launch_bounds__(256) void sentinel_sC(float* out, int n) {
    int i = blockIdx.x * 256 + threadIdx.x;
    if (i < n) out[i] = 1.0e6f;
}

// ---------------- wavelet ----------------
__global__ __launch_bounds__(256) void wavelet_sC(const float* x, float* low, float* high, int b0) {
    int idx = blockIdx.x * 256 + threadIdx.x;
    int fq = idx & 31, i = (idx >> 5) & 63, c = (idx >> 11) & 63, bl = idx >> 17;
    size_t base = ((size_t)((b0 + bl) * 64 + c) * 128 + 2 * i) * 32 + fq;
    float xe = x[base];
    float xo = x[base + 32];
    int m = (bl * 64 + i) * 16 + (fq >> 1);
    int k = c * 2 + (fq & 1);
    low[(size_t)m * 128 + k]  = (xe + xo) * SQ2F;
    high[(size_t)m * 128 + k] = (xo - xe) * SQ2F;
}

// ---------------- weight conversion: all GEMM weights fp32 -> bf16 arena ----------------
// arena map (bf16 elems): 0 bmain[128x128] | 16384 baux[64x128] | 24576 bin0[512x128]
// | 90112 bin1 | 155648 bxp0[40x256] | 165888 bxp1 | 176128 bvim[128x128]
// | 192512 bfus[192x192] | 229376 bwcat[128x512] | 294912 brec[256x192] | end 344064
__global__ __launch_bounds__(256) void wcvt_sC(
    const float* main_w, const float* aux_w, const float* in_w0, const float* in_w1,
    const float* xp0, const float* xp1, const float* vim_w, const float* fus_w,
    const float* ow0, const float* ow1, const float* rec_w, unsigned short* dst) {
    int i = blockIdx.x * 256 + threadIdx.x;
    float v;
    if      (i < 16384)  v = main_w[i];
    else if (i < 24576)  v = aux_w[i - 16384];
    else if (i < 90112)  v = in_w0[i - 24576];
    else if (i < 155648) v = in_w1[i - 90112];
    else if (i < 165888) v = xp0[i - 155648];
    else if (i < 176128) v = xp1[i - 165888];
    else if (i < 192512) v = vim_w[i - 176128];
    else if (i < 229376) v = fus_w[i - 192512];
    else if (i < 294912) {
        int j = i - 229376; int k = j & 511; int n = j >> 9;
        v = (k < 256) ? ow0[(size_t)n * 256 + k] : ow1[(size_t)n * 256 + (k - 256)];
    } else if (i < 344064) {
        int j = i - 294912; int n = j / 192, c = j % 192;
        v = rec_w[((size_t)(c * 64 + (n >> 2)) * 2 + ((n >> 1) & 1)) * 2 + (n & 1)];
    } else return;
    dst[i] = f2b(v);
}

// ---------------- MFMA GEMM: BM=128 BN=64 BK=32, 256 thr (4 waves), bf16 in / fp32 acc ---
// C[m,n] = sum_k A[m,k]*W[n,k], A fp32 (cvt at staging), W bf16 arena.
// adual: k<256 from A[m], k>=256 from A2[m^1023] (col k-256). aflip: A row m^1023.
// epi: 0 plain(cflip), 1 patch, 2 vim, 3 fus, 4 rec.
__global__ __launch_bounds__(256) void mgemm_sC(
    const float* A, const float* A2, const unsigned short* W, float* C,
    int N, int K, int lda, int ldw, int ldc,
    int aflip, int cflip, int adual, int epi, int b0g,
    const float* bias, const float* gg, const float* bet,
    const float* xm, const float* xa, const float* xres, float* outf) {
    __shared__ unsigned short Ab[2][4][128][8];   // [buf][kgroup][m][j]  16 KB
    __shared__ unsigned short Wl[2][4][64][8];    // [buf][kgroup][n][j]   8 KB
    const int tid = threadIdx.x;
    const int wave = tid >> 6, lane = tid & 63;
    const int m0 = blockIdx.x * 128;
    const int n0 = blockIdx.y * 64;

    // staging indices
    const int rA = tid >> 1, hA = tid & 1;          // A: row, k-half(16)
    const int nS = tid >> 2, gS = tid & 3;          // W: row, k-group(8)
    int m_a = m0 + rA;
    if (aflip) m_a ^= 1023;
    const float* Arow = A + (size_t)m_a * lda;
    const float* A2row = adual ? (A2 + (size_t)((m0 + rA) ^ 1023) * lda - 256) : Arow;
    const bool wok = (n0 + nS) < N;
    const unsigned short* Wrow = W + (size_t)(n0 + nS) * ldw;

    f32x4 acc[2][4];
#pragma unroll
    for (int i = 0; i < 2; ++i)
#pragma unroll
        for (int j = 0; j < 4; ++j) acc[i][j] = f32x4{0.f, 0.f, 0.f, 0.f};

    const int nk = K >> 5;
    float4 v0, v1, v2, v3;
    us8 wv;

    auto loadregs = [&](int kt) {
        const int k0 = kt * 32 + hA * 16;
        const float* src = (adual && k0 >= 256) ? A2row : Arow;
        v0 = *(const float4*)(src + k0);
        v1 = *(const float4*)(src + k0 + 4);
        v2 = *(const float4*)(src + k0 + 8);
        v3 = *(const float4*)(src + k0 + 12);
        if (wok) wv = *(const us8*)(Wrow + kt * 32 + gS * 8);
        else     wv = us8{0, 0, 0, 0, 0, 0, 0, 0};
    };
    auto writelds = [&](int buf) {
        us8 lo, hi;
        lo[0] = f2b(v0.x); lo[1] = f2b(v0.y); lo[2] = f2b(v0.z); lo[3] = f2b(v0.w);
        lo[4] = f2b(v1.x); lo[5] = f2b(v1.y); lo[6] = f2b(v1.z); lo[7] = f2b(v1.w);
        hi[0] = f2b(v2.x); hi[1] = f2b(v2.y); hi[2] = f2b(v2.z); hi[3] = f2b(v2.w);
        hi[4] = f2b(v3.x); hi[5] = f2b(v3.y); hi[6] = f2b(v3.z); hi[7] = f2b(v3.w);
        *(us8*)&Ab[buf][2 * hA][rA][0] = lo;
        *(us8*)&Ab[buf][2 * hA + 1][rA][0] = hi;
        *(us8*)&Wl[buf][gS][nS][0] = wv;
    };

    loadregs(0);
    writelds(0);
    __syncthreads();

    const int li = lane & 15, kg = lane >> 4;
    for (int t = 0; t < nk; ++t) {
        if (t + 1 < nk) loadregs(t + 1);
        const int cb = t & 1;
        bf16x8 af0 = *(const bf16x8*)&Ab[cb][kg][wave * 32 + li][0];
        bf16x8 af1 = *(const bf16x8*)&Ab[cb][kg][wave * 32 + 16 + li][0];
        bf16x8 wf0 = *(const bf16x8*)&Wl[cb][kg][li][0];
        bf16x8 wf1 = *(const bf16x8*)&Wl[cb][kg][16 + li][0];
        bf16x8 wf2 = *(const bf16x8*)&Wl[cb][kg][32 + li][0];
        bf16x8 wf3 = *(const bf16x8*)&Wl[cb][kg][48 + li][0];
        acc[0][0] = __builtin_amdgcn_mfma_f32_16x16x32_bf16(af0, wf0, acc[0][0], 0, 0, 0);
        acc[0][1] = __builtin_amdgcn_mfma_f32_16x16x32_bf16(af0, wf1, acc[0][1], 0, 0, 0);
        acc[0][2] = __builtin_amdgcn_mfma_f32_16x16x32_bf16(af0, wf2, acc[0][2], 0, 0, 0);
        acc[0][3] = __builtin_amdgcn_mfma_f32_16x16x32_bf16(af0, wf3, acc[0][3], 0, 0, 0);
        acc[1][0] = __builtin_amdgcn_mfma_f32_16x16x32_bf16(af1, wf0, acc[1][0], 0, 0, 0);
        acc[1][1] = __builtin_amdgcn_mfma_f32_16x16x32_bf16(af1, wf1, acc[1][1], 0, 0, 0);
        acc[1][2] = __builtin_amdgcn_mfma_f32_16x16x32_bf16(af1, wf2, acc[1][2], 0, 0, 0);
        acc[1][3] = __builtin_amdgcn_mfma_f32_16x16x32_bf16(af1, wf3, acc[1][3], 0, 0, 0);
        if (t + 1 < nk) writelds((t + 1) & 1);
        __syncthreads();
    }

    // epilogue: D[row=(lane>>4)*4+r][col=lane&15] per fragment (verified m89 layout)
#pragma unroll
    for (int mf = 0; mf < 2; ++mf) {
#pragma unroll
        for (int nf = 0; nf < 4; ++nf) {
#pragma unroll
            for (int rr = 0; rr < 4; ++rr) {
                int m = m0 + wave * 32 + mf * 16 + (lane >> 4) * 4 + rr;
                int n = n0 + nf * 16 + (lane & 15);
                if (n >= N) continue;
                float v = acc[mf][nf][rr];
                int bb = m >> 10, l = m & 1023;
                if (epi == 0) {
                    int mm = cflip ? (m ^ 1023) : m;
                    C[(size_t)mm * ldc + n] = v;
                } else if (epi == 1) {
                    v += bias[n];
                    v = v * (gg[n] * BNS) + bet[n];
                    C[((size_t)(bb * N + n) << 10) + l] = fmaxf(v, 0.f);
                } else if (epi == 2) {
                    C[(size_t)m * ldc + n] = v + bias[n] + xm[((size_t)(bb * 128 + n) << 10) + l];
                } else if (epi == 3) {
                    float xin = (n < 128) ? xm[((size_t)(bb * 128 + n) << 10) + l]
                                          : xa[((size_t)(bb * 64 + (n - 128)) << 10) + l];
                    C[(size_t)m * ldc + n] = xin + (v + bias[n]) * (gg[n] * BNS) + bet[n];
                } else {
                    int o = n >> 2, kq = (n >> 1) & 1, l2 = n & 1;
                    int ii = l >> 4, jj = l & 15;
                    v += bias[o];
                    v = fmaxf(v * (gg[o] * BNS) + bet[o], 0.f);
                    size_t oidx = ((size_t)((b0g + bb) * 64 + o) * 128 + (2 * ii + kq)) * 32 + (2 * jj + l2);
                    outf[oidx] = v + xres[oidx];
                }
            }
        }
    }
}

// ---------------- LayerNorm via LDS transpose ----------------
__global__ __launch_bounds__(256) void ln_sC(const float* mainin, const float* g,
                                             const float* bt, float* xn) {
    __shared__ float tile[128][65];
    __shared__ float red0[4][64];
    __shared__ float red1[4][64];
    __shared__ float mu_s[64];
    __shared__ float rs_s[64];
    const int bb = blockIdx.y;
    const int l0 = blockIdx.x * 64;
    const int tid = threadIdx.x;
    for (int idx = tid; idx < 128 * 64; idx += 256) {
        int c = idx >> 6, l = idx & 63;
        tile[c][l] = mainin[((size_t)(bb * 128 + c) << 10) + l0 + l];
    }
    __syncthreads();
    {
        int l = tid & 63, q = tid >> 6;
        float s = 0.f, s2 = 0.f;
#pragma unroll
        for (int c0 = 0; c0 < 32; ++c0) {
            float v = tile[q * 32 + c0][l];
            s += v; s2 = fmaf(v, v, s2);
        }
        red0[q][l] = s; red1[q][l] = s2;
    }
    __syncthreads();
    if (tid < 64) {
        float S = red0[0][tid] + red0[1][tid] + red0[2][tid] + red0[3][tid];
        float S2 = red1[0][tid] + red1[1][tid] + red1[2][tid] + red1[3][tid];
        float mu = S * (1.f / 128.f);
        float var = S2 * (1.f / 128.f) - mu * mu;
        mu_s[tid] = mu;
        rs_s[tid] = rsqrtf(var + 1e-5f);
    }
    __syncthreads();
    for (int idx = tid; idx < 128 * 64; idx += 256) {
        int l = idx >> 7, c = idx & 127;
        float v = (tile[c][l] - mu_s[l]) * rs_s[l] * g[c] + bt[c];
        xn[((size_t)(bb << 10) + l0 + l) * 128 + c] = v;
    }
}

// ---------------- causal conv (k=4) + SiLU ----------------
__global__ __launch_bounds__(256) void conv_sC(const float* xz, const float* cw,
                                               const float* cb, float* xc) {
    int m = blockIdx.x, d = threadIdx.x;
    int l = m & 1023;
    float acc = cb[d];
    const float* w = cw + d * 4;
    for (int k = 0; k < 4; ++k) {
        int ls = l - 3 + k;
        if (ls >= 0) acc = fmaf(xz[(size_t)(m - 3 + k) * 512 + d], w[k], acc);
    }
    xc[(size_t)m * 256 + d] = silu_f(acc);
}

// ---------------- dt projection (K=8) + softplus ----------------
__global__ __launch_bounds__(256) void dtp_sC(const float* xdbl, const float* dtw,
                                              const float* dtbias, float* dtout) {
    __shared__ float x8[8];
    int m = blockIdx.x, d = threadIdx.x;
    if (d < 8) x8[d] = xdbl[(size_t)m * 40 + d];
    __syncthreads();
    float acc = dtbias[d];
    const float* w = dtw + d * 8;
    for (int r = 0; r < 8; ++r) acc = fmaf(x8[r], w[r], acc);
    float sp = (acc > 15.f) ? acc : log1pf(__expf(acc));
    dtout[(size_t)m * 256 + d] = sp;
}

// ---------------- segmented selective scan (76 us verified) ----------------
#define STAGE_SC(L0V, SBV)                                                                  \
    {                                                                                       \
        const int l0_ = (L0V), sb_ = (SBV);                                                 \
        _Pragma("unroll")                                                                   \
        for (int f = t2; f < TS * 4; f += 64) {                                             \
            int l = f >> 2, sg = (f & 3) * 4;                                               \
            *(float4*)&dts[sb_][l][sg] = *(const float4*)(dtb + base256 + (size_t)(l0_ + l) * 256 + sg); \
            *(float4*)&xvs[sb_][l][sg] = *(const float4*)(xcb + base256 + (size_t)(l0_ + l) * 256 + sg); \
            *(float4*)&zzs[sb_][l][sg] = *(const float4*)(xzb + base512 + (size_t)(l0_ + l) * 512 + sg); \
        }                                                                                   \
        _Pragma("unroll")                                                                   \
        for (int f = t2; f < TS * 8; f += 64) {                                             \
            int l = f >> 3, sg = (f & 7) * 4;                                               \
            *(float4*)&bcs[sb_][l][sg] = *(const float4*)(xdb + base40 + (size_t)(l0_ + l) * 40 + sg);   \
        }                                                                                   \
    }

__global__ __launch_bounds__(128) void scan_sC(
    const float* dt0, const float* dt1, const float* xc0, const float* xc1,
    const float* xz0, const float* xz1, const float* xd0, const float* xd1,
    const float* al0, const float* al1, const float* D0, const float* D1,
    float* yg0, float* yg1) {
    __shared__ float dts[2][TS][16];
    __shared__ float xvs[2][TS][16];
    __shared__ float zzs[2][TS][16];
    __shared__ float bcs[2][TS][32];

    const int b = blockIdx.x;
    const int dir = blockIdx.y;
    const int seg = blockIdx.z >> 4;
    const int d0 = (blockIdx.z & 15) * 16;
    const int tid = threadIdx.x;

    const float* dtb = dir ? dt1 : dt0;
    const float* xcb = dir ? xc1 : xc0;
    const float* xzb = dir ? xz1 : xz0;
    const float* xdb = dir ? xd1 : xd0;
    float* ygb = dir ? yg1 : yg0;

    const size_t base256 = (size_t)b * L_ * 256 + d0;
    const size_t base512 = (size_t)b * L_ * 512 + 256 + d0;
    const size_t base40  = (size_t)b * L_ * 40 + 8;

    const int lstart = seg * SEGL - (seg ? WARM : 0);
    const int ntiles = (seg ? (SEGL + WARM) : SEGL) / TS;
    const int wtiles = seg ? (WARM / TS) : 0;

    const int isStage = tid >> 6;
    const int t2 = tid & 63;
    const int dg = t2 >> 2, q = t2 & 3;

    const float LOG2E = 1.44269504088896340736f;
    float al2[4];
    float Dd = 0.f;
    float h0 = 0.f, h1 = 0.f, h2 = 0.f, h3 = 0.f;
    if (!isStage) {
        const float* alog = (dir ? al1 : al0) + (d0 + dg) * 16 + q * 4;
#pragma unroll
        for (int n = 0; n < 4; ++n) al2[n] = -__expf(alog[n]) * LOG2E;
        Dd = (dir ? D1 : D0)[d0 + dg];
    }
    float* yp = ygb + (size_t)b * L_ * 512 + d0 + dg;

    if (isStage) STAGE_SC(lstart, 0);
    __syncthreads();

    for (int t = 0; t < ntiles; ++t) {
        if (isStage) {
            if (t + 1 < ntiles) STAGE_SC(lstart + (t + 1) * TS, (t + 1) & 1);
        } else {
            const int cb = t & 1;
            const bool dostore = (t >= wtiles);
#pragma unroll 4
            for (int l = 0; l < TS; ++l) {
                float dt = dts[cb][l][dg];
                float xv = xvs[cb][l][dg];
                float zz = zzs[cb][l][dg];
                float4 Bv = *(const float4*)&bcs[cb][l][q * 4];
                float4 Cv = *(const float4*)&bcs[cb][l][16 + q * 4];
                float dtx = dt * xv;
                float e0 = exp2f(dt * al2[0]);
                float e1 = exp2f(dt * al2[1]);
                float e2 = exp2f(dt * al2[2]);
                float e3 = exp2f(dt * al2[3]);
                h0 = fmaf(e0, h0, dtx * Bv.x);
                h1 = fmaf(e1, h1, dtx * Bv.y);
                h2 = fmaf(e2, h2, dtx * Bv.z);
                h3 = fmaf(e3, h3, dtx * Bv.w);
                float acc = fmaf(h3, Cv.w, fmaf(h2, Cv.z, fmaf(h1, Cv.y, h0 * Cv.x)));
                acc += __shfl_xor(acc, 1);
                acc += __shfl_xor(acc, 2);
                if (dostore && q == 0) {
                    float y = fmaf(Dd, xv, acc);
                    yp[(size_t)(lstart + t * TS + l) * 512] = y * silu_f(zz);
                }
            }
        }
        __syncthreads();
    }
}

// ---------------- depthwise conv 3x3 / 5x5 + BN + SiLU ----------------
__global__ __launch_bounds__(256) void dwconv_sC(const float* auxin,
                                                 const float* mk3w, const float* mk3b,
                                                 const float* mk5w, const float* mk5b,
                                                 const float* mkg, const float* mkbeta,
                                                 float* xout) {
    int idx = blockIdx.x * 256 + threadIdx.x;
    int j = idx & 15, i = (idx >> 4) & 63, c = (idx >> 10) & 63, b = idx >> 16;
    const float* src = auxin + ((size_t)(b * 64 + c) << 10);
    float acc;
    if (c < 32) {
        acc = mk3b[c];
        for (int di = -1; di <= 1; ++di)
            for (int dj = -1; dj <= 1; ++dj) {
                int ii = i + di, jj = j + dj;
                if (ii >= 0 && ii < 64 && jj >= 0 && jj < 16)
                    acc = fmaf(src[ii * 16 + jj], mk3w[(c * 3 + di + 1) * 3 + dj + 1], acc);
            }
    } else {
        int cc = c - 32;
        acc = mk5b[cc];
        for (int di = -2; di <= 2; ++di)
            for (int dj = -2; dj <= 2; ++dj) {
                int ii = i + di, jj = j + dj;
                if (ii >= 0 && ii < 64 && jj >= 0 && jj < 16)
                    acc = fmaf(src[ii * 16 + jj], mk5w[(cc * 5 + di + 2) * 5 + dj + 2], acc);
            }
    }
    float v = acc * (mkg[c] * BNS) + mkbeta[c];
    v = silu_f(v);
    xout[(size_t)((b << 10) + i * 16 + j) * 192 + 128 + c] = v;
}

// ---------------- host ----------------
extern "C" void kernel_launch(void* const* d_in, const int* in_sizes, int n_in,
                              void* d_out, int out_size, void* d_ws, size_t ws_size,
                              hipStream_t stream) {
    (void)in_sizes; (void)n_in;
    const float* X         = (const float*)d_in[0];
    const float* main_w    = (const float*)d_in[1];
    const float* main_b    = (const float*)d_in[2];
    const float* main_g    = (const float*)d_in[3];
    const float* main_beta = (const float*)d_in[4];
    const float* aux_w     = (const float*)d_in[5];
    const float* aux_b     = (const float*)d_in[6];
    const float* aux_g     = (const float*)d_in[7];
    const float* aux_beta  = (const float*)d_in[8];
    const float* ln_g      = (const float*)d_in[9];
    const float* ln_b      = (const float*)d_in[10];
    const float* vim_w     = (const float*)d_in[11];
    const float* vim_b     = (const float*)d_in[12];
    const float* mk3_w     = (const float*)d_in[13];
    const float* mk3_b     = (const float*)d_in[14];
    const float* mk5_w     = (const float*)d_in[15];
    const float* mk5_b     = (const float*)d_in[16];
    const float* mk_g      = (const float*)d_in[17];
    const float* mk_beta   = (const float*)d_in[18];
    const float* fus_w     = (const float*)d_in[19];
    const float* fus_b     = (const float*)d_in[20];
    const float* fus_g     = (const float*)d_in[21];
    const float* fus_beta  = (const float*)d_in[22];
    const float* rec_w     = (const float*)d_in[23];
    const float* rec_b     = (const float*)d_in[24];
    const float* rec_g     = (const float*)d_in[25];
    const float* rec_beta  = (const float*)d_in[26];
    const float* in_w0    = (const float*)d_in[27];
    const float* conv_w0  = (const float*)d_in[28];
    const float* conv_b0  = (const float*)d_in[29];
    const float* xproj_w0 = (const float*)d_in[30];
    const float* dt_w0    = (const float*)d_in[31];
    const float* dt_b0    = (const float*)d_in[32];
    const float* Alog0    = (const float*)d_in[33];
    const float* Dvec0    = (const float*)d_in[34];
    const float* out_w0   = (const float*)d_in[35];
    const float* in_w1    = (const float*)d_in[36];
    const float* conv_w1  = (const float*)d_in[37];
    const float* conv_b1  = (const float*)d_in[38];
    const float* xproj_w1 = (const float*)d_in[39];
    const float* dt_w1    = (const float*)d_in[40];
    const float* dt_b1    = (const float*)d_in[41];
    const float* Alog1    = (const float*)d_in[42];
    const float* Dvec1    = (const float*)d_in[43];
    const float* out_w1   = (const float*)d_in[44];

    // workspace: bf16 weight arena (344064 bf16 = 172032 float slots) + chunk buffers
    const size_t wf = ws_size / sizeof(float);
    const size_t FIX = 172032;
    int nb = 0;
    if      (FIX + (size_t)8 * 1024 * 2576 <= wf) nb = 8;
    else if (FIX + (size_t)4 * 1024 * 2576 <= wf) nb = 4;
    else if (FIX + (size_t)2 * 1024 * 2576 <= wf) nb = 2;
    else if (FIX + (size_t)1 * 1024 * 2576 <= wf) nb = 1;
    if (nb == 0) {
        sentinel_sC<<<(out_size + 255) / 256, 256, 0, stream>>>((float*)d_out, out_size);
        return;
    }

    float* ws = (float*)d_ws;
    unsigned short* warena = (unsigned short*)ws;
    const unsigned short* bmain = warena;
    const unsigned short* baux  = warena + 16384;
    const unsigned short* bin0  = warena + 24576;
    const unsigned short* bin1  = warena + 90112;
    const unsigned short* bxp0  = warena + 155648;
    const unsigned short* bxp1  = warena + 165888;
    const unsigned short* bvim  = warena + 176128;
    const unsigned short* bfus  = warena + 192512;
    const unsigned short* bwcat = warena + 229376;
    const unsigned short* brec  = warena + 294912;

    const size_t R = (size_t)nb * 1024;
    float* xzf    = ws + FIX;
    float* xzb    = xzf + R * 512;
    float* mainin = xzb + R * 512;
    float* auxin  = mainin + R * 128;
    float* xn     = auxin + R * 64;
    float* vimin  = xn;                      // overlay (xn dead after in_proj_b)
    float* lowb   = xn + R * 128;
    float* highb  = lowb + R * 128;
    float* dtf    = lowb;                    // overlay (low+high dead after patch)
    float* xcf    = highb + R * 128;
    float* xcb    = xcf + R * 256;
    float* xoutc  = xcf;                     // overlay (xc_f dead after scan)
    float* xfused = xcb;                     // overlay (xc_b dead after scan)
    float* xdblf  = xcb + R * 256;
    float* xdblb  = xdblf + R * 40;
    float* dtbk   = xdblb + R * 40;

    wcvt_sC<<<1344, 256, 0, stream>>>(main_w, aux_w, in_w0, in_w1, xproj_w0, xproj_w1,
                                      vim_w, fus_w, out_w0, out_w1, rec_w, warena);
    const unsigned GM = (unsigned)(R / 128);   // 128-row M-tiles per chunk

    for (int b0 = 0; b0 < 8; b0 += nb) {
        wavelet_sC<<<nb * 512, 256, 0, stream>>>(X, lowb, highb, b0);

        // patch_proj main/aux                                         [epi 1]
        mgemm_sC<<<dim3(GM, 2), 256, 0, stream>>>(
            lowb, nullptr, bmain, mainin, 128, 128, 128, 128, 0, 0, 0, 0, 1, 0,
            main_b, main_g, main_beta, nullptr, nullptr, nullptr, nullptr);
        mgemm_sC<<<dim3(GM, 1), 256, 0, stream>>>(
            highb, nullptr, baux, auxin, 64, 128, 128, 128, 0, 0, 0, 0, 1, 0,
            aux_b, aux_g, aux_beta, nullptr, nullptr, nullptr, nullptr);
        ln_sC<<<dim3(16, nb), 256, 0, stream>>>(mainin, ln_g, ln_b, xn);

        // forward mamba branch
        mgemm_sC<<<dim3(GM, 8), 256, 0, stream>>>(
            xn, nullptr, bin0, xzf, 512, 128, 128, 128, 512, 0, 0, 0, 0, 0,
            nullptr, nullptr, nullptr, nullptr, nullptr, nullptr, nullptr);
        conv_sC<<<(unsigned)R, 256, 0, stream>>>(xzf, conv_w0, conv_b0, xcf);
        mgemm_sC<<<dim3(GM, 1), 256, 0, stream>>>(
            xcf, nullptr, bxp0, xdblf, 40, 256, 256, 256, 40, 0, 0, 0, 0, 0,
            nullptr, nullptr, nullptr, nullptr, nullptr, nullptr, nullptr);
        dtp_sC<<<(unsigned)R, 256, 0, stream>>>(xdblf, dt_w0, dt_b0, dtf);

        // backward mamba branch
        mgemm_sC<<<dim3(GM, 8), 256, 0, stream>>>(
            xn, nullptr, bin1, xzb, 512, 128, 128, 128, 512, 1, 0, 0, 0, 0,
            nullptr, nullptr, nullptr, nullptr, nullptr, nullptr, nullptr);
        conv_sC<<<(unsigned)R, 256, 0, stream>>>(xzb, conv_w1, conv_b1, xcb);
        mgemm_sC<<<dim3(GM, 1), 256, 0, stream>>>(
            xcb, nullptr, bxp1, xdblb, 40, 256, 256, 256, 40, 0, 0, 0, 0, 0,
            nullptr, nullptr, nullptr, nullptr, nullptr, nullptr, nullptr);
        dtp_sC<<<(unsigned)R, 256, 0, stream>>>(xdblb, dt_w1, dt_b1, dtbk);

        // segmented scan
        scan_sC<<<dim3(nb, 2, 128), 128, 0, stream>>>(
            dtf, dtbk, xcf, xcb, xzf, xzb, xdblf, xdblb,
            Alog0, Alog1, Dvec0, Dvec1, xzf, xzb);

        // fused out_proj f+b: vimin = yg_f@W0^T + yg_b(flip)@W1^T     [adual, K=512]
        mgemm_sC<<<dim3(GM, 2), 256, 0, stream>>>(
            xzf, xzb, bwcat, vimin, 128, 512, 512, 512, 128, 0, 0, 1, 0, 0,
            nullptr, nullptr, nullptr, nullptr, nullptr, nullptr, nullptr);

        // vim: vimin @ vim_w + vim_b + x_seq -> xout cols 0..127      [epi 2]
        mgemm_sC<<<dim3(GM, 2), 256, 0, stream>>>(
            vimin, nullptr, bvim, xoutc, 128, 128, 128, 128, 192, 0, 0, 0, 2, 0,
            vim_b, nullptr, nullptr, mainin, nullptr, nullptr, nullptr);

        dwconv_sC<<<nb * 256, 256, 0, stream>>>(
            auxin, mk3_w, mk3_b, mk5_w, mk5_b, mk_g, mk_beta, xoutc);

        // fusion: xout @ fus_w + x_in + BN -> x_fused                 [epi 3]
        mgemm_sC<<<dim3(GM, 3), 256, 0, stream>>>(
            xoutc, nullptr, bfus, xfused, 192, 192, 192, 192, 192, 0, 0, 0, 3, 0,
            fus_b, fus_g, fus_beta, mainin, auxin, nullptr, nullptr);

        // reconstruction: x_fused @ recT + BN + ReLU + x -> d_out     [epi 4]
        mgemm_sC<<<dim3(GM, 4), 256, 0, stream>>>(
            xfused, nullptr, brec, nullptr, 256, 192, 192, 192, 0, 0, 0, 0, 4, b0,
            rec_b, rec_g, rec_beta, nullptr, nullptr, X, (float*)d_out);
    }
}

// Round 13
// 247.282 us; speedup vs baseline: 7.4620x; 1.1148x over previous
//
#include <hip/hip_runtime.h>
#include <hip/hip_bf16.h>

#define SQ2F 0.70710678f
#define BNS 0.9999950000374997f   /* 1/sqrt(1+1e-5) */
#define L_ 1024
#define TS 32                     /* scan LDS tile (steps) */
#define SEGL 128                  /* real steps per segment */
#define WARM 64                   /* warmup steps (h-reconstruction) */

typedef __attribute__((ext_vector_type(8))) short bf16x8;
typedef __attribute__((ext_vector_type(8))) unsigned short us8;
typedef __attribute__((ext_vector_type(4))) float f32x4;

__device__ __forceinline__ float silu_f(float v) { return v / (1.f + __expf(-v)); }
__device__ __forceinline__ unsigned short f2b(float f) {
    unsigned u = __float_as_uint(f);
    return (unsigned short)((u + 0x7FFFu + ((u >> 16) & 1u)) >> 16);   // RNE
}

// ---------------- sentinel ----------------
__global__ __launch_bounds__(256) void sentinel_sD(float* out, int n) {
    int i = blockIdx.x * 256 + threadIdx.x;
    if (i < n) out[i] = 1.0e6f;
}

// ---------------- wavelet ----------------
__global__ __launch_bounds__(256) void wavelet_sD(const float* x, float* low, float* high, int b0) {
    int idx = blockIdx.x * 256 + threadIdx.x;
    int fq = idx & 31, i = (idx >> 5) & 63, c = (idx >> 11) & 63, bl = idx >> 17;
    size_t base = ((size_t)((b0 + bl) * 64 + c) * 128 + 2 * i) * 32 + fq;
    float xe = x[base];
    float xo = x[base + 32];
    int m = (bl * 64 + i) * 16 + (fq >> 1);
    int k = c * 2 + (fq & 1);
    low[(size_t)m * 128 + k]  = (xe + xo) * SQ2F;
    high[(size_t)m * 128 + k] = (xo - xe) * SQ2F;
}

// ---------------- weight conversion: all GEMM weights fp32 -> bf16 arena ----------------
__global__ __launch_bounds__(256) void wcvt_sD(
    const float* main_w, const float* aux_w, const float* in_w0, const float* in_w1,
    const float* xp0, const float* xp1, const float* vim_w, const float* fus_w,
    const float* ow0, const float* ow1, const float* rec_w, unsigned short* dst) {
    int i = blockIdx.x * 256 + threadIdx.x;
    float v;
    if      (i < 16384)  v = main_w[i];
    else if (i < 24576)  v = aux_w[i - 16384];
    else if (i < 90112)  v = in_w0[i - 24576];
    else if (i < 155648) v = in_w1[i - 90112];
    else if (i < 165888) v = xp0[i - 155648];
    else if (i < 176128) v = xp1[i - 165888];
    else if (i < 192512) v = vim_w[i - 176128];
    else if (i < 229376) v = fus_w[i - 192512];
    else if (i < 294912) {
        int j = i - 229376; int k = j & 511; int n = j >> 9;
        v = (k < 256) ? ow0[(size_t)n * 256 + k] : ow1[(size_t)n * 256 + (k - 256)];
    } else if (i < 344064) {
        int j = i - 294912; int n = j / 192, c = j % 192;
        v = rec_w[((size_t)(c * 64 + (n >> 2)) * 2 + ((n >> 1) & 1)) * 2 + (n & 1)];
    } else return;
    dst[i] = f2b(v);
}

// ---------------- MFMA GEMM: BM=128 BN=64 BK=32, 256 thr, bf16 in / fp32 acc -------------
// z-merged: blockIdx.z==1 -> (A1, W1, C1, N1, aflip1, bias1, gg1, bet1).
// adual: k<256 from A[m], k>=256 from A2[m^1023]. agate: a *= silu(src[k+256]).
// epi: 0 plain(cflip), 1 patch, 2 vim, 3 fus, 4 rec.
__global__ __launch_bounds__(256) void mgemm_sD(
    const float* A, const float* A2, const unsigned short* W, float* C,
    int N, int K, int lda, int ldw, int ldc,
    int aflip, int cflip, int adual, int epi, int b0g, int agate,
    const float* bias, const float* gg, const float* bet,
    const float* xm, const float* xa, const float* xres, float* outf,
    const float* A1, const unsigned short* W1, float* C1, int N1, int aflip1,
    const float* bias1, const float* gg1, const float* bet1) {
    if (blockIdx.z) {
        A = A1; W = W1; C = C1; N = N1; aflip = aflip1;
        bias = bias1; gg = gg1; bet = bet1;
    }
    __shared__ unsigned short Ab[2][4][128][8];
    __shared__ unsigned short Wl[2][4][64][8];
    const int tid = threadIdx.x;
    const int wave = tid >> 6, lane = tid & 63;
    const int m0 = blockIdx.x * 128;
    const int n0 = blockIdx.y * 64;

    const int rA = tid >> 1, hA = tid & 1;
    const int nS = tid >> 2, gS = tid & 3;
    int m_a = m0 + rA;
    if (aflip) m_a ^= 1023;
    const float* Arow = A + (size_t)m_a * lda;
    const float* A2row = adual ? (A2 + (size_t)((m0 + rA) ^ 1023) * lda - 256) : Arow;
    const bool wok = (n0 + nS) < N;
    const unsigned short* Wrow = W + (size_t)(n0 + nS) * ldw;

    f32x4 acc[2][4];
#pragma unroll
    for (int i = 0; i < 2; ++i)
#pragma unroll
        for (int j = 0; j < 4; ++j) acc[i][j] = f32x4{0.f, 0.f, 0.f, 0.f};

    const int nk = K >> 5;
    float4 v0, v1, v2, v3;
    us8 wv;

    auto loadregs = [&](int kt) {
        const int k0 = kt * 32 + hA * 16;
        const float* src = (adual && k0 >= 256) ? A2row : Arow;
        v0 = *(const float4*)(src + k0);
        v1 = *(const float4*)(src + k0 + 4);
        v2 = *(const float4*)(src + k0 + 8);
        v3 = *(const float4*)(src + k0 + 12);
        if (agate) {
            float4 g0 = *(const float4*)(src + k0 + 256);
            float4 g1 = *(const float4*)(src + k0 + 260);
            float4 g2 = *(const float4*)(src + k0 + 264);
            float4 g3 = *(const float4*)(src + k0 + 268);
            v0.x *= silu_f(g0.x); v0.y *= silu_f(g0.y); v0.z *= silu_f(g0.z); v0.w *= silu_f(g0.w);
            v1.x *= silu_f(g1.x); v1.y *= silu_f(g1.y); v1.z *= silu_f(g1.z); v1.w *= silu_f(g1.w);
            v2.x *= silu_f(g2.x); v2.y *= silu_f(g2.y); v2.z *= silu_f(g2.z); v2.w *= silu_f(g2.w);
            v3.x *= silu_f(g3.x); v3.y *= silu_f(g3.y); v3.z *= silu_f(g3.z); v3.w *= silu_f(g3.w);
        }
        if (wok) wv = *(const us8*)(Wrow + kt * 32 + gS * 8);
        else     wv = us8{0, 0, 0, 0, 0, 0, 0, 0};
    };
    auto writelds = [&](int buf) {
        us8 lo, hi;
        lo[0] = f2b(v0.x); lo[1] = f2b(v0.y); lo[2] = f2b(v0.z); lo[3] = f2b(v0.w);
        lo[4] = f2b(v1.x); lo[5] = f2b(v1.y); lo[6] = f2b(v1.z); lo[7] = f2b(v1.w);
        hi[0] = f2b(v2.x); hi[1] = f2b(v2.y); hi[2] = f2b(v2.z); hi[3] = f2b(v2.w);
        hi[4] = f2b(v3.x); hi[5] = f2b(v3.y); hi[6] = f2b(v3.z); hi[7] = f2b(v3.w);
        *(us8*)&Ab[buf][2 * hA][rA][0] = lo;
        *(us8*)&Ab[buf][2 * hA + 1][rA][0] = hi;
        *(us8*)&Wl[buf][gS][nS][0] = wv;
    };

    loadregs(0);
    writelds(0);
    __syncthreads();

    const int li = lane & 15, kg = lane >> 4;
    for (int t = 0; t < nk; ++t) {
        if (t + 1 < nk) loadregs(t + 1);
        const int cb = t & 1;
        bf16x8 af0 = *(const bf16x8*)&Ab[cb][kg][wave * 32 + li][0];
        bf16x8 af1 = *(const bf16x8*)&Ab[cb][kg][wave * 32 + 16 + li][0];
        bf16x8 wf0 = *(const bf16x8*)&Wl[cb][kg][li][0];
        bf16x8 wf1 = *(const bf16x8*)&Wl[cb][kg][16 + li][0];
        bf16x8 wf2 = *(const bf16x8*)&Wl[cb][kg][32 + li][0];
        bf16x8 wf3 = *(const bf16x8*)&Wl[cb][kg][48 + li][0];
        acc[0][0] = __builtin_amdgcn_mfma_f32_16x16x32_bf16(af0, wf0, acc[0][0], 0, 0, 0);
        acc[0][1] = __builtin_amdgcn_mfma_f32_16x16x32_bf16(af0, wf1, acc[0][1], 0, 0, 0);
        acc[0][2] = __builtin_amdgcn_mfma_f32_16x16x32_bf16(af0, wf2, acc[0][2], 0, 0, 0);
        acc[0][3] = __builtin_amdgcn_mfma_f32_16x16x32_bf16(af0, wf3, acc[0][3], 0, 0, 0);
        acc[1][0] = __builtin_amdgcn_mfma_f32_16x16x32_bf16(af1, wf0, acc[1][0], 0, 0, 0);
        acc[1][1] = __builtin_amdgcn_mfma_f32_16x16x32_bf16(af1, wf1, acc[1][1], 0, 0, 0);
        acc[1][2] = __builtin_amdgcn_mfma_f32_16x16x32_bf16(af1, wf2, acc[1][2], 0, 0, 0);
        acc[1][3] = __builtin_amdgcn_mfma_f32_16x16x32_bf16(af1, wf3, acc[1][3], 0, 0, 0);
        if (t + 1 < nk) writelds((t + 1) & 1);
        __syncthreads();
    }

#pragma unroll
    for (int mf = 0; mf < 2; ++mf) {
#pragma unroll
        for (int nf = 0; nf < 4; ++nf) {
#pragma unroll
            for (int rr = 0; rr < 4; ++rr) {
                int m = m0 + wave * 32 + mf * 16 + (lane >> 4) * 4 + rr;
                int n = n0 + nf * 16 + (lane & 15);
                if (n >= N) continue;
                float v = acc[mf][nf][rr];
                int bb = m >> 10, l = m & 1023;
                if (epi == 0) {
                    int mm = cflip ? (m ^ 1023) : m;
                    C[(size_t)mm * ldc + n] = v;
                } else if (epi == 1) {
                    v += bias[n];
                    v = v * (gg[n] * BNS) + bet[n];
                    C[((size_t)(bb * N + n) << 10) + l] = fmaxf(v, 0.f);
                } else if (epi == 2) {
                    C[(size_t)m * ldc + n] = v + bias[n] + xm[((size_t)(bb * 128 + n) << 10) + l];
                } else if (epi == 3) {
                    float xin = (n < 128) ? xm[((size_t)(bb * 128 + n) << 10) + l]
                                          : xa[((size_t)(bb * 64 + (n - 128)) << 10) + l];
                    C[(size_t)m * ldc + n] = xin + (v + bias[n]) * (gg[n] * BNS) + bet[n];
                } else {
                    int o = n >> 2, kq = (n >> 1) & 1, l2 = n & 1;
                    int ii = l >> 4, jj = l & 15;
                    v += bias[o];
                    v = fmaxf(v * (gg[o] * BNS) + bet[o], 0.f);
                    size_t oidx = ((size_t)((b0g + bb) * 64 + o) * 128 + (2 * ii + kq)) * 32 + (2 * jj + l2);
                    outf[oidx] = v + xres[oidx];
                }
            }
        }
    }
}

// ---------------- LayerNorm via LDS transpose ----------------
__global__ __launch_bounds__(256) void ln_sD(const float* mainin, const float* g,
                                             const float* bt, float* xn) {
    __shared__ float tile[128][65];
    __shared__ float red0[4][64];
    __shared__ float red1[4][64];
    __shared__ float mu_s[64];
    __shared__ float rs_s[64];
    const int bb = blockIdx.y;
    const int l0 = blockIdx.x * 64;
    const int tid = threadIdx.x;
    for (int idx = tid; idx < 128 * 64; idx += 256) {
        int c = idx >> 6, l = idx & 63;
        tile[c][l] = mainin[((size_t)(bb * 128 + c) << 10) + l0 + l];
    }
    __syncthreads();
    {
        int l = tid & 63, q = tid >> 6;
        float s = 0.f, s2 = 0.f;
#pragma unroll
        for (int c0 = 0; c0 < 32; ++c0) {
            float v = tile[q * 32 + c0][l];
            s += v; s2 = fmaf(v, v, s2);
        }
        red0[q][l] = s; red1[q][l] = s2;
    }
    __syncthreads();
    if (tid < 64) {
        float S = red0[0][tid] + red0[1][tid] + red0[2][tid] + red0[3][tid];
        float S2 = red1[0][tid] + red1[1][tid] + red1[2][tid] + red1[3][tid];
        float mu = S * (1.f / 128.f);
        float var = S2 * (1.f / 128.f) - mu * mu;
        mu_s[tid] = mu;
        rs_s[tid] = rsqrtf(var + 1e-5f);
    }
    __syncthreads();
    for (int idx = tid; idx < 128 * 64; idx += 256) {
        int l = idx >> 7, c = idx & 127;
        float v = (tile[c][l] - mu_s[l]) * rs_s[l] * g[c] + bt[c];
        xn[((size_t)(bb << 10) + l0 + l) * 128 + c] = v;
    }
}

// ---------------- causal conv (k=4) + SiLU, both dirs via grid.y ----------------
__global__ __launch_bounds__(256) void conv_sD(const float* xzf, const float* xzb,
                                               const float* cw0, const float* cb0,
                                               const float* cw1, const float* cb1,
                                               float* xcf, float* xcb2) {
    int m = blockIdx.x, d = threadIdx.x, dir = blockIdx.y;
    const float* xz = dir ? xzb : xzf;
    const float* cw = dir ? cw1 : cw0;
    const float* cb = dir ? cb1 : cb0;
    float* xc = dir ? xcb2 : xcf;
    int l = m & 1023;
    float acc = cb[d];
    const float* w = cw + d * 4;
    for (int k = 0; k < 4; ++k) {
        int ls = l - 3 + k;
        if (ls >= 0) acc = fmaf(xz[(size_t)(m - 3 + k) * 512 + d], w[k], acc);
    }
    xc[(size_t)m * 256 + d] = silu_f(acc);
}

// ---------------- segmented scan with fused dt-projection; gate moved to out_proj -------
// stage wave: loads xc (16 d's) + xdbl cols 0..39; computes dt = softplus(xdbl[0:8]@dtw^T+b)
// in-wave; compute wave: h-recurrence, stores RAW y (gating in out_proj staging).
#define STAGE_SD(L0V, SBV)                                                                  \
    {                                                                                       \
        const int l0_ = (L0V), sb_ = (SBV);                                                 \
        _Pragma("unroll")                                                                   \
        for (int f = t2; f < TS * 4; f += 64) {                                             \
            int l = f >> 2, sg = (f & 3) * 4;                                               \
            *(float4*)&xvs[sb_][l][sg] = *(const float4*)(xcb + base256 + (size_t)(l0_ + l) * 256 + sg); \
        }                                                                                   \
        _Pragma("unroll")                                                                   \
        for (int f = t2; f < TS * 10; f += 64) {                                            \
            int l = f / 10, p = f % 10;                                                     \
            float4 v = *(const float4*)(xdb + base40 + (size_t)(l0_ + l) * 40 + p * 4);     \
            if (p < 2) *(float4*)&xd8[sb_][l][p * 4] = v;                                   \
            else       *(float4*)&bcs[sb_][l][p * 4 - 8] = v;                               \
        }                                                                                   \
        {                                                                                   \
            int dd = t2 & 15, lb = (t2 >> 4) * 8;                                           \
            float4 wA = *(const float4*)&dtw_s[dd][0];                                      \
            float4 wB = *(const float4*)&dtw_s[dd][4];                                      \
            float bsv = dtb_s[dd];                                                          \
            _Pragma("unroll")                                                               \
            for (int vv = 0; vv < 8; ++vv) {                                                \
                int l = lb + vv;                                                            \
                float4 xA = *(const float4*)&xd8[sb_][l][0];                                \
                float4 xB = *(const float4*)&xd8[sb_][l][4];                                \
                float a_ = bsv;                                                             \
                a_ = fmaf(xA.x, wA.x, a_); a_ = fmaf(xA.y, wA.y, a_);                       \
                a_ = fmaf(xA.z, wA.z, a_); a_ = fmaf(xA.w, wA.w, a_);                       \
                a_ = fmaf(xB.x, wB.x, a_); a_ = fmaf(xB.y, wB.y, a_);                       \
                a_ = fmaf(xB.z, wB.z, a_); a_ = fmaf(xB.w, wB.w, a_);                       \
                dts[sb_][l][dd] = (a_ > 15.f) ? a_ : log1pf(__expf(a_));                    \
            }                                                                               \
        }                                                                                   \
    }

__global__ __launch_bounds__(128) void scan_sD(
    const float* xc0, const float* xc1, const float* xd0, const float* xd1,
    const float* dtw0, const float* dtw1, const float* dtbv0, const float* dtbv1,
    const float* al0, const float* al1, const float* D0, const float* D1,
    float* y0, float* y1) {
    __shared__ float dts[2][TS][16];
    __shared__ float xvs[2][TS][16];
    __shared__ float bcs[2][TS][32];
    __shared__ float xd8[2][TS][8];
    __shared__ float dtw_s[16][8];
    __shared__ float dtb_s[16];

    const int b = blockIdx.x;
    const int dir = blockIdx.y;
    const int seg = blockIdx.z >> 4;
    const int d0 = (blockIdx.z & 15) * 16;
    const int tid = threadIdx.x;

    const float* xcb = dir ? xc1 : xc0;
    const float* xdb = dir ? xd1 : xd0;
    float* ygb = dir ? y1 : y0;

    const size_t base256 = (size_t)b * L_ * 256 + d0;
    const size_t base40  = (size_t)b * L_ * 40;

    const int lstart = seg * SEGL - (seg ? WARM : 0);
    const int ntiles = (seg ? (SEGL + WARM) : SEGL) / TS;
    const int wtiles = seg ? (WARM / TS) : 0;

    const int isStage = tid >> 6;
    const int t2 = tid & 63;
    const int dg = t2 >> 2, q = t2 & 3;

    const float LOG2E = 1.44269504088896340736f;
    float al2[4];
    float Dd = 0.f;
    float h0 = 0.f, h1 = 0.f, h2 = 0.f, h3 = 0.f;
    if (!isStage) {
        const float* alog = (dir ? al1 : al0) + (d0 + dg) * 16 + q * 4;
#pragma unroll
        for (int n = 0; n < 4; ++n) al2[n] = -__expf(alog[n]) * LOG2E;
        Dd = (dir ? D1 : D0)[d0 + dg];
    } else {
        const float* dtw = dir ? dtw1 : dtw0;
        const float* dtbv = dir ? dtbv1 : dtbv0;
        for (int i = t2; i < 128; i += 64)
            dtw_s[i >> 3][i & 7] = dtw[(size_t)(d0 + (i >> 3)) * 8 + (i & 7)];
        if (t2 < 16) dtb_s[t2] = dtbv[d0 + t2];
    }
    float* yp = ygb + (size_t)b * L_ * 512 + d0 + dg;   // ld = 512 (overlay)

    if (isStage) STAGE_SD(lstart, 0);
    __syncthreads();

    for (int t = 0; t < ntiles; ++t) {
        if (isStage) {
            if (t + 1 < ntiles) STAGE_SD(lstart + (t + 1) * TS, (t + 1) & 1);
        } else {
            const int cb = t & 1;
            const bool dostore = (t >= wtiles);
#pragma unroll 4
            for (int l = 0; l < TS; ++l) {
                float dt = dts[cb][l][dg];
                float xv = xvs[cb][l][dg];
                float4 Bv = *(const float4*)&bcs[cb][l][q * 4];
                float4 Cv = *(const float4*)&bcs[cb][l][16 + q * 4];
                float dtx = dt * xv;
                float e0 = exp2f(dt * al2[0]);
                float e1 = exp2f(dt * al2[1]);
                float e2 = exp2f(dt * al2[2]);
                float e3 = exp2f(dt * al2[3]);
                h0 = fmaf(e0, h0, dtx * Bv.x);
                h1 = fmaf(e1, h1, dtx * Bv.y);
                h2 = fmaf(e2, h2, dtx * Bv.z);
                h3 = fmaf(e3, h3, dtx * Bv.w);
                float acc = fmaf(h3, Cv.w, fmaf(h2, Cv.z, fmaf(h1, Cv.y, h0 * Cv.x)));
                acc += __shfl_xor(acc, 1);
                acc += __shfl_xor(acc, 2);
                if (dostore && q == 0) {
                    yp[(size_t)(lstart + t * TS + l) * 512] = fmaf(Dd, xv, acc);
                }
            }
        }
        __syncthreads();
    }
}

// ---------------- depthwise conv 3x3 / 5x5 + BN + SiLU ----------------
__global__ __launch_bounds__(256) void dwconv_sD(const float* auxin,
                                                 const float* mk3w, const float* mk3b,
                                                 const float* mk5w, const float* mk5b,
                                                 const float* mkg, const float* mkbeta,
                                                 float* xout) {
    int idx = blockIdx.x * 256 + threadIdx.x;
    int j = idx & 15, i = (idx >> 4) & 63, c = (idx >> 10) & 63, b = idx >> 16;
    const float* src = auxin + ((size_t)(b * 64 + c) << 10);
    float acc;
    if (c < 32) {
        acc = mk3b[c];
        for (int di = -1; di <= 1; ++di)
            for (int dj = -1; dj <= 1; ++dj) {
                int ii = i + di, jj = j + dj;
                if (ii >= 0 && ii < 64 && jj >= 0 && jj < 16)
                    acc = fmaf(src[ii * 16 + jj], mk3w[(c * 3 + di + 1) * 3 + dj + 1], acc);
            }
    } else {
        int cc = c - 32;
        acc = mk5b[cc];
        for (int di = -2; di <= 2; ++di)
            for (int dj = -2; dj <= 2; ++dj) {
                int ii = i + di, jj = j + dj;
                if (ii >= 0 && ii < 64 && jj >= 0 && jj < 16)
                    acc = fmaf(src[ii * 16 + jj], mk5w[(cc * 5 + di + 2) * 5 + dj + 2], acc);
            }
    }
    float v = acc * (mkg[c] * BNS) + mkbeta[c];
    v = silu_f(v);
    xout[(size_t)((b << 10) + i * 16 + j) * 192 + 128 + c] = v;
}

// ---------------- host ----------------
extern "C" void kernel_launch(void* const* d_in, const int* in_sizes, int n_in,
                              void* d_out, int out_size, void* d_ws, size_t ws_size,
                              hipStream_t stream) {
    (void)in_sizes; (void)n_in;
    const float* X         = (const float*)d_in[0];
    const float* main_w    = (const float*)d_in[1];
    const float* main_b    = (const float*)d_in[2];
    const float* main_g    = (const float*)d_in[3];
    const float* main_beta = (const float*)d_in[4];
    const float* aux_w     = (const float*)d_in[5];
    const float* aux_b     = (const float*)d_in[6];
    const float* aux_g     = (const float*)d_in[7];
    const float* aux_beta  = (const float*)d_in[8];
    const float* ln_g      = (const float*)d_in[9];
    const float* ln_b      = (const float*)d_in[10];
    const float* vim_w     = (const float*)d_in[11];
    const float* vim_b     = (const float*)d_in[12];
    const float* mk3_w     = (const float*)d_in[13];
    const float* mk3_b     = (const float*)d_in[14];
    const float* mk5_w     = (const float*)d_in[15];
    const float* mk5_b     = (const float*)d_in[16];
    const float* mk_g      = (const float*)d_in[17];
    const float* mk_beta   = (const float*)d_in[18];
    const float* fus_w     = (const float*)d_in[19];
    const float* fus_b     = (const float*)d_in[20];
    const float* fus_g     = (const float*)d_in[21];
    const float* fus_beta  = (const float*)d_in[22];
    const float* rec_w     = (const float*)d_in[23];
    const float* rec_b     = (const float*)d_in[24];
    const float* rec_g     = (const float*)d_in[25];
    const float* rec_beta  = (const float*)d_in[26];
    const float* in_w0    = (const float*)d_in[27];
    const float* conv_w0  = (const float*)d_in[28];
    const float* conv_b0  = (const float*)d_in[29];
    const float* xproj_w0 = (const float*)d_in[30];
    const float* dt_w0    = (const float*)d_in[31];
    const float* dt_b0    = (const float*)d_in[32];
    const float* Alog0    = (const float*)d_in[33];
    const float* Dvec0    = (const float*)d_in[34];
    const float* out_w0   = (const float*)d_in[35];
    const float* in_w1    = (const float*)d_in[36];
    const float* conv_w1  = (const float*)d_in[37];
    const float* conv_b1  = (const float*)d_in[38];
    const float* xproj_w1 = (const float*)d_in[39];
    const float* dt_w1    = (const float*)d_in[40];
    const float* dt_b1    = (const float*)d_in[41];
    const float* Alog1    = (const float*)d_in[42];
    const float* Dvec1    = (const float*)d_in[43];
    const float* out_w1   = (const float*)d_in[44];

    const size_t wf = ws_size / sizeof(float);
    const size_t FIX = 172032;
    int nb = 0;
    if      (FIX + (size_t)8 * 1024 * 2576 <= wf) nb = 8;
    else if (FIX + (size_t)4 * 1024 * 2576 <= wf) nb = 4;
    else if (FIX + (size_t)2 * 1024 * 2576 <= wf) nb = 2;
    else if (FIX + (size_t)1 * 1024 * 2576 <= wf) nb = 1;
    if (nb == 0) {
        sentinel_sD<<<(out_size + 255) / 256, 256, 0, stream>>>((float*)d_out, out_size);
        return;
    }

    float* ws = (float*)d_ws;
    unsigned short* warena = (unsigned short*)ws;
    const unsigned short* bmain = warena;
    const unsigned short* baux  = warena + 16384;
    const unsigned short* bin0  = warena + 24576;
    const unsigned short* bin1  = warena + 90112;
    const unsigned short* bxp0  = warena + 155648;
    const unsigned short* bxp1  = warena + 165888;
    const unsigned short* bvim  = warena + 176128;
    const unsigned short* bfus  = warena + 192512;
    const unsigned short* bwcat = warena + 229376;
    const unsigned short* brec  = warena + 294912;

    const size_t R = (size_t)nb * 1024;
    float* xzf    = ws + FIX;
    float* xzb    = xzf + R * 512;
    float* mainin = xzb + R * 512;
    float* auxin  = mainin + R * 128;
    float* xn     = auxin + R * 64;
    float* vimin  = xn;                      // overlay (xn dead after in_proj)
    float* lowb   = xn + R * 128;
    float* highb  = lowb + R * 128;
    float* xcf    = highb + R * 128;
    float* xcb    = xcf + R * 256;
    float* xoutc  = xcf;                     // overlay (xc_f dead after scan)
    float* xfused = xcb;                     // overlay (xc_b dead after scan)
    float* xdblf  = xcb + R * 256;
    float* xdblb  = xdblf + R * 40;

    wcvt_sD<<<1344, 256, 0, stream>>>(main_w, aux_w, in_w0, in_w1, xproj_w0, xproj_w1,
                                      vim_w, fus_w, out_w0, out_w1, rec_w, warena);
    const unsigned GM = (unsigned)(R / 128);

    for (int b0 = 0; b0 < 8; b0 += nb) {
        wavelet_sD<<<nb * 512, 256, 0, stream>>>(X, lowb, highb, b0);

        // patch_proj main (z=0) + aux (z=1)                            [epi 1]
        mgemm_sD<<<dim3(GM, 2, 2), 256, 0, stream>>>(
            lowb, nullptr, bmain, mainin, 128, 128, 128, 128, 0, 0, 0, 0, 1, 0, 0,
            main_b, main_g, main_beta, nullptr, nullptr, nullptr, nullptr,
            highb, baux, auxin, 64, 0, aux_b, aux_g, aux_beta);
        ln_sD<<<dim3(16, nb), 256, 0, stream>>>(mainin, ln_g, ln_b, xn);

        // in_proj fwd (z=0) + bwd flipped (z=1)                        [epi 0]
        mgemm_sD<<<dim3(GM, 8, 2), 256, 0, stream>>>(
            xn, nullptr, bin0, xzf, 512, 128, 128, 128, 512, 0, 0, 0, 0, 0, 0,
            nullptr, nullptr, nullptr, nullptr, nullptr, nullptr, nullptr,
            xn, bin1, xzb, 512, 1, nullptr, nullptr, nullptr);

        // conv f+b
        conv_sD<<<dim3((unsigned)R, 2), 256, 0, stream>>>(
            xzf, xzb, conv_w0, conv_b0, conv_w1, conv_b1, xcf, xcb);

        // xproj f (z=0) + b (z=1)                                      [epi 0]
        mgemm_sD<<<dim3(GM, 1, 2), 256, 0, stream>>>(
            xcf, nullptr, bxp0, xdblf, 40, 256, 256, 256, 40, 0, 0, 0, 0, 0, 0,
            nullptr, nullptr, nullptr, nullptr, nullptr, nullptr, nullptr,
            xcb, bxp1, xdblb, 40, 0, nullptr, nullptr, nullptr);

        // segmented scan with fused dt-projection; writes RAW y into xz cols 0..255
        scan_sD<<<dim3(nb, 2, 128), 128, 0, stream>>>(
            xcf, xcb, xdblf, xdblb, dt_w0, dt_w1, dt_b0, dt_b1,
            Alog0, Alog1, Dvec0, Dvec1, xzf, xzb);

        // fused out_proj f+b with silu(z) gating in staging            [adual+agate]
        mgemm_sD<<<dim3(GM, 2, 1), 256, 0, stream>>>(
            xzf, xzb, bwcat, vimin, 128, 512, 512, 512, 128, 0, 0, 1, 0, 0, 1,
            nullptr, nullptr, nullptr, nullptr, nullptr, nullptr, nullptr,
            nullptr, nullptr, nullptr, 0, 0, nullptr, nullptr, nullptr);

        // vim: vimin @ vim_w + vim_b + x_seq -> xout cols 0..127       [epi 2]
        mgemm_sD<<<dim3(GM, 2, 1), 256, 0, stream>>>(
            vimin, nullptr, bvim, xoutc, 128, 128, 128, 128, 192, 0, 0, 0, 2, 0, 0,
            vim_b, nullptr, nullptr, mainin, nullptr, nullptr, nullptr,
            nullptr, nullptr, nullptr, 0, 0, nullptr, nullptr, nullptr);

        dwconv_sD<<<nb * 256, 256, 0, stream>>>(
            auxin, mk3_w, mk3_b, mk5_w, mk5_b, mk_g, mk_beta, xoutc);

        // fusion: xout @ fus_w + x_in + BN -> x_fused                  [epi 3]
        mgemm_sD<<<dim3(GM, 3, 1), 256, 0, stream>>>(
            xoutc, nullptr, bfus, xfused, 192, 192, 192, 192, 192, 0, 0, 0, 3, 0, 0,
            fus_b, fus_g, fus_beta, mainin, auxin, nullptr, nullptr,
            nullptr, nullptr, nullptr, 0, 0, nullptr, nullptr, nullptr);

        // reconstruction: x_fused @ recT + BN + ReLU + x -> d_out      [epi 4]
        mgemm_sD<<<dim3(GM, 4, 1), 256, 0, stream>>>(
            xfused, nullptr, brec, nullptr, 256, 192, 192, 192, 0, 0, 0, 0, 4, b0, 0,
            rec_b, rec_g, rec_beta, nullptr, nullptr, X, (float*)d_out,
            nullptr, nullptr, nullptr, 0, 0, nullptr, nullptr, nullptr);
    }
}

// Round 14
// 241.627 us; speedup vs baseline: 7.6367x; 1.0234x over previous
//
#include <hip/hip_runtime.h>
#include <hip/hip_bf16.h>

#define SQ2F 0.70710678f
#define BNS 0.9999950000374997f   /* 1/sqrt(1+1e-5) */
#define L_ 1024
#define TS 32                     /* scan LDS tile (steps) */
#define SEGL 128                  /* real steps per segment */
#define WARM 64                   /* warmup steps (h-reconstruction) */

typedef __attribute__((ext_vector_type(8))) short bf16x8;
typedef __attribute__((ext_vector_type(8))) unsigned short us8;
typedef __attribute__((ext_vector_type(4))) float f32x4;

__device__ __forceinline__ float silu_f(float v) { return v / (1.f + __expf(-v)); }
__device__ __forceinline__ unsigned short f2b(float f) {
    unsigned u = __float_as_uint(f);
    return (unsigned short)((u + 0x7FFFu + ((u >> 16) & 1u)) >> 16);   // RNE
}

// bf16 weight arena map (bf16-element offsets):
// 0 bmain[128x128] | 16384 baux[64x128] | 24576 bin0[512x128] | 90112 bin1
// | 155648 bxpc0[288x256] (rows0..31 = xproj rows 8..39; rows32..287 = dt_w@xproj[:8])
// | 229376 bxpc1 | 303104 bvim[128x128] | 319488 bfus[192x192]
// | 356352 bwcat[128x512] | 421888 brec[256x192] | end 471040
#define AR_XPC0 155648
#define AR_XPC1 229376
#define AR_END  471040

// ---------------- sentinel ----------------
__global__ __launch_bounds__(256) void sentinel_sE(float* out, int n) {
    int i = blockIdx.x * 256 + threadIdx.x;
    if (i < n) out[i] = 1.0e6f;
}

// ---------------- wavelet ----------------
__global__ __launch_bounds__(256) void wavelet_sE(const float* x, float* low, float* high, int b0) {
    int idx = blockIdx.x * 256 + threadIdx.x;
    int fq = idx & 31, i = (idx >> 5) & 63, c = (idx >> 11) & 63, bl = idx >> 17;
    size_t base = ((size_t)((b0 + bl) * 64 + c) * 128 + 2 * i) * 32 + fq;
    float xe = x[base];
    float xo = x[base + 32];
    int m = (bl * 64 + i) * 16 + (fq >> 1);
    int k = c * 2 + (fq & 1);
    low[(size_t)m * 128 + k]  = (xe + xo) * SQ2F;
    high[(size_t)m * 128 + k] = (xo - xe) * SQ2F;
}

// ---------------- weight conversion (skips composed regions; wcomp fills them) ----------
__global__ __launch_bounds__(256) void wcvt_sE(
    const float* main_w, const float* aux_w, const float* in_w0, const float* in_w1,
    const float* xp0, const float* xp1, const float* vim_w, const float* fus_w,
    const float* ow0, const float* ow1, const float* rec_w, unsigned short* dst) {
    int i = blockIdx.x * 256 + threadIdx.x;
    float v;
    if      (i < 16384)  v = main_w[i];
    else if (i < 24576)  v = aux_w[i - 16384];
    else if (i < 90112)  v = in_w0[i - 24576];
    else if (i < 155648) v = in_w1[i - 90112];
    else if (i < 163840) { int j = i - 155648; v = xp0[(size_t)((j >> 8) + 8) * 256 + (j & 255)]; }
    else if (i < 229376) return;                       // bxpc0 rows 32..287 (wcomp)
    else if (i < 237568) { int j = i - 229376; v = xp1[(size_t)((j >> 8) + 8) * 256 + (j & 255)]; }
    else if (i < 303104) return;                       // bxpc1 rows 32..287 (wcomp)
    else if (i < 319488) v = vim_w[i - 303104];
    else if (i < 356352) v = fus_w[i - 319488];
    else if (i < 421888) {
        int j = i - 356352; int k = j & 511; int n = j >> 9;
        v = (k < 256) ? ow0[(size_t)n * 256 + k] : ow1[(size_t)n * 256 + (k - 256)];
    } else if (i < AR_END) {
        int j = i - 421888; int n = j / 192, c = j % 192;
        v = rec_w[((size_t)(c * 64 + (n >> 2)) * 2 + ((n >> 1) & 1)) * 2 + (n & 1)];
    } else return;
    dst[i] = f2b(v);
}

// ---------------- composed dt weight: Wcomp[d][k] = sum_r dt_w[d][r]*xproj_w[r][k] ------
__global__ __launch_bounds__(256) void wcomp_sE(const float* xp0, const float* xp1,
                                                const float* dtw0, const float* dtw1,
                                                unsigned short* arena) {
    int idx = blockIdx.x * 256 + threadIdx.x;   // 65536 per dir
    int dir = blockIdx.y;
    int d = idx >> 8, k = idx & 255;
    const float* xp = dir ? xp1 : xp0;
    const float* dtw = dir ? dtw1 : dtw0;
    float v = 0.f;
#pragma unroll
    for (int r = 0; r < 8; ++r) v = fmaf(dtw[d * 8 + r], xp[(size_t)r * 256 + k], v);
    arena[(size_t)(dir ? AR_XPC1 : AR_XPC0) + (size_t)(32 + d) * 256 + k] = f2b(v);
}

// ---------------- MFMA GEMM: BM=128 BN=64 BK=32, 256 thr, bf16 in / fp32 acc -------------
// z-merged: blockIdx.z==1 -> (A1,W1,C1,N1,aflip1,bias1,gg1,bet1,outf1).
// adual: k<256 from A[m], k>=256 from A2[m^1023]. agate: a *= silu(src[k+256]).
// epi: 0 plain(cflip), 1 patch, 2 vim, 3 fus, 4 rec,
//      5 xproj+dt: n<32 -> C[m*32+n] (B,C); n>=32 -> outf[m*256+n-32] = softplus(v+bias[n-32])
__global__ __launch_bounds__(256) void mgemm_sE(
    const float* A, const float* A2, const unsigned short* W, float* C,
    int N, int K, int lda, int ldw, int ldc,
    int aflip, int cflip, int adual, int epi, int b0g, int agate,
    const float* bias, const float* gg, const float* bet,
    const float* xm, const float* xa, const float* xres, float* outf,
    const float* A1, const unsigned short* W1, float* C1, int N1, int aflip1,
    const float* bias1, const float* gg1, const float* bet1, float* outf1) {
    if (blockIdx.z) {
        A = A1; W = W1; C = C1; N = N1; aflip = aflip1;
        bias = bias1; gg = gg1; bet = bet1; outf = outf1;
    }
    __shared__ unsigned short Ab[2][4][128][8];
    __shared__ unsigned short Wl[2][4][64][8];
    const int tid = threadIdx.x;
    const int wave = tid >> 6, lane = tid & 63;
    const int m0 = blockIdx.x * 128;
    const int n0 = blockIdx.y * 64;

    const int rA = tid >> 1, hA = tid & 1;
    const int nS = tid >> 2, gS = tid & 3;
    int m_a = m0 + rA;
    if (aflip) m_a ^= 1023;
    const float* Arow = A + (size_t)m_a * lda;
    const float* A2row = adual ? (A2 + (size_t)((m0 + rA) ^ 1023) * lda - 256) : Arow;
    const bool wok = (n0 + nS) < N;
    const unsigned short* Wrow = W + (size_t)(n0 + nS) * ldw;

    f32x4 acc[2][4];
#pragma unroll
    for (int i = 0; i < 2; ++i)
#pragma unroll
        for (int j = 0; j < 4; ++j) acc[i][j] = f32x4{0.f, 0.f, 0.f, 0.f};

    const int nk = K >> 5;
    float4 v0, v1, v2, v3;
    us8 wv;

    auto loadregs = [&](int kt) {
        const int k0 = kt * 32 + hA * 16;
        const float* src = (adual && k0 >= 256) ? A2row : Arow;
        v0 = *(const float4*)(src + k0);
        v1 = *(const float4*)(src + k0 + 4);
        v2 = *(const float4*)(src + k0 + 8);
        v3 = *(const float4*)(src + k0 + 12);
        if (agate) {
            float4 g0 = *(const float4*)(src + k0 + 256);
            float4 g1 = *(const float4*)(src + k0 + 260);
            float4 g2 = *(const float4*)(src + k0 + 264);
            float4 g3 = *(const float4*)(src + k0 + 268);
            v0.x *= silu_f(g0.x); v0.y *= silu_f(g0.y); v0.z *= silu_f(g0.z); v0.w *= silu_f(g0.w);
            v1.x *= silu_f(g1.x); v1.y *= silu_f(g1.y); v1.z *= silu_f(g1.z); v1.w *= silu_f(g1.w);
            v2.x *= silu_f(g2.x); v2.y *= silu_f(g2.y); v2.z *= silu_f(g2.z); v2.w *= silu_f(g2.w);
            v3.x *= silu_f(g3.x); v3.y *= silu_f(g3.y); v3.z *= silu_f(g3.z); v3.w *= silu_f(g3.w);
        }
        if (wok) wv = *(const us8*)(Wrow + kt * 32 + gS * 8);
        else     wv = us8{0, 0, 0, 0, 0, 0, 0, 0};
    };
    auto writelds = [&](int buf) {
        us8 lo, hi;
        lo[0] = f2b(v0.x); lo[1] = f2b(v0.y); lo[2] = f2b(v0.z); lo[3] = f2b(v0.w);
        lo[4] = f2b(v1.x); lo[5] = f2b(v1.y); lo[6] = f2b(v1.z); lo[7] = f2b(v1.w);
        hi[0] = f2b(v2.x); hi[1] = f2b(v2.y); hi[2] = f2b(v2.z); hi[3] = f2b(v2.w);
        hi[4] = f2b(v3.x); hi[5] = f2b(v3.y); hi[6] = f2b(v3.z); hi[7] = f2b(v3.w);
        *(us8*)&Ab[buf][2 * hA][rA][0] = lo;
        *(us8*)&Ab[buf][2 * hA + 1][rA][0] = hi;
        *(us8*)&Wl[buf][gS][nS][0] = wv;
    };

    loadregs(0);
    writelds(0);
    __syncthreads();

    const int li = lane & 15, kg = lane >> 4;
    for (int t = 0; t < nk; ++t) {
        if (t + 1 < nk) loadregs(t + 1);
        const int cb = t & 1;
        bf16x8 af0 = *(const bf16x8*)&Ab[cb][kg][wave * 32 + li][0];
        bf16x8 af1 = *(const bf16x8*)&Ab[cb][kg][wave * 32 + 16 + li][0];
        bf16x8 wf0 = *(const bf16x8*)&Wl[cb][kg][li][0];
        bf16x8 wf1 = *(const bf16x8*)&Wl[cb][kg][16 + li][0];
        bf16x8 wf2 = *(const bf16x8*)&Wl[cb][kg][32 + li][0];
        bf16x8 wf3 = *(const bf16x8*)&Wl[cb][kg][48 + li][0];
        acc[0][0] = __builtin_amdgcn_mfma_f32_16x16x32_bf16(af0, wf0, acc[0][0], 0, 0, 0);
        acc[0][1] = __builtin_amdgcn_mfma_f32_16x16x32_bf16(af0, wf1, acc[0][1], 0, 0, 0);
        acc[0][2] = __builtin_amdgcn_mfma_f32_16x16x32_bf16(af0, wf2, acc[0][2], 0, 0, 0);
        acc[0][3] = __builtin_amdgcn_mfma_f32_16x16x32_bf16(af0, wf3, acc[0][3], 0, 0, 0);
        acc[1][0] = __builtin_amdgcn_mfma_f32_16x16x32_bf16(af1, wf0, acc[1][0], 0, 0, 0);
        acc[1][1] = __builtin_amdgcn_mfma_f32_16x16x32_bf16(af1, wf1, acc[1][1], 0, 0, 0);
        acc[1][2] = __builtin_amdgcn_mfma_f32_16x16x32_bf16(af1, wf2, acc[1][2], 0, 0, 0);
        acc[1][3] = __builtin_amdgcn_mfma_f32_16x16x32_bf16(af1, wf3, acc[1][3], 0, 0, 0);
        if (t + 1 < nk) writelds((t + 1) & 1);
        __syncthreads();
    }

#pragma unroll
    for (int mf = 0; mf < 2; ++mf) {
#pragma unroll
        for (int nf = 0; nf < 4; ++nf) {
#pragma unroll
            for (int rr = 0; rr < 4; ++rr) {
                int m = m0 + wave * 32 + mf * 16 + (lane >> 4) * 4 + rr;
                int n = n0 + nf * 16 + (lane & 15);
                if (n >= N) continue;
                float v = acc[mf][nf][rr];
                int bb = m >> 10, l = m & 1023;
                if (epi == 0) {
                    int mm = cflip ? (m ^ 1023) : m;
                    C[(size_t)mm * ldc + n] = v;
                } else if (epi == 1) {
                    v += bias[n];
                    v = v * (gg[n] * BNS) + bet[n];
                    C[((size_t)(bb * N + n) << 10) + l] = fmaxf(v, 0.f);
                } else if (epi == 2) {
                    C[(size_t)m * ldc + n] = v + bias[n] + xm[((size_t)(bb * 128 + n) << 10) + l];
                } else if (epi == 3) {
                    float xin = (n < 128) ? xm[((size_t)(bb * 128 + n) << 10) + l]
                                          : xa[((size_t)(bb * 64 + (n - 128)) << 10) + l];
                    C[(size_t)m * ldc + n] = xin + (v + bias[n]) * (gg[n] * BNS) + bet[n];
                } else if (epi == 4) {
                    int o = n >> 2, kq = (n >> 1) & 1, l2 = n & 1;
                    int ii = l >> 4, jj = l & 15;
                    v += bias[o];
                    v = fmaxf(v * (gg[o] * BNS) + bet[o], 0.f);
                    size_t oidx = ((size_t)((b0g + bb) * 64 + o) * 128 + (2 * ii + kq)) * 32 + (2 * jj + l2);
                    outf[oidx] = v + xres[oidx];
                } else { // epi 5: xproj + composed dt
                    if (n < 32) {
                        C[(size_t)m * 32 + n] = v;
                    } else {
                        float a = v + bias[n - 32];
                        float sp = (a > 15.f) ? a : __logf(1.f + __expf(a));
                        outf[(size_t)m * 256 + (n - 32)] = sp;
                    }
                }
            }
        }
    }
}

// ---------------- LayerNorm via LDS transpose ----------------
__global__ __launch_bounds__(256) void ln_sE(const float* mainin, const float* g,
                                             const float* bt, float* xn) {
    __shared__ float tile[128][65];
    __shared__ float red0[4][64];
    __shared__ float red1[4][64];
    __shared__ float mu_s[64];
    __shared__ float rs_s[64];
    const int bb = blockIdx.y;
    const int l0 = blockIdx.x * 64;
    const int tid = threadIdx.x;
    for (int idx = tid; idx < 128 * 64; idx += 256) {
        int c = idx >> 6, l = idx & 63;
        tile[c][l] = mainin[((size_t)(bb * 128 + c) << 10) + l0 + l];
    }
    __syncthreads();
    {
        int l = tid & 63, q = tid >> 6;
        float s = 0.f, s2 = 0.f;
#pragma unroll
        for (int c0 = 0; c0 < 32; ++c0) {
            float v = tile[q * 32 + c0][l];
            s += v; s2 = fmaf(v, v, s2);
        }
        red0[q][l] = s; red1[q][l] = s2;
    }
    __syncthreads();
    if (tid < 64) {
        float S = red0[0][tid] + red0[1][tid] + red0[2][tid] + red0[3][tid];
        float S2 = red1[0][tid] + red1[1][tid] + red1[2][tid] + red1[3][tid];
        float mu = S * (1.f / 128.f);
        float var = S2 * (1.f / 128.f) - mu * mu;
        mu_s[tid] = mu;
        rs_s[tid] = rsqrtf(var + 1e-5f);
    }
    __syncthreads();
    for (int idx = tid; idx < 128 * 64; idx += 256) {
        int l = idx >> 7, c = idx & 127;
        float v = (tile[c][l] - mu_s[l]) * rs_s[l] * g[c] + bt[c];
        xn[((size_t)(bb << 10) + l0 + l) * 128 + c] = v;
    }
}

// ---------------- causal conv (k=4) + SiLU, both dirs via grid.y ----------------
__global__ __launch_bounds__(256) void conv_sE(const float* xzf, const float* xzb,
                                               const float* cw0, const float* cb0,
                                               const float* cw1, const float* cb1,
                                               float* xcf, float* xcb2) {
    int m = blockIdx.x, d = threadIdx.x, dir = blockIdx.y;
    const float* xz = dir ? xzb : xzf;
    const float* cw = dir ? cw1 : cw0;
    const float* cb = dir ? cb1 : cb0;
    float* xc = dir ? xcb2 : xcf;
    int l = m & 1023;
    float acc = cb[d];
    const float* w = cw + d * 4;
    for (int k = 0; k < 4; ++k) {
        int ls = l - 3 + k;
        if (ls >= 0) acc = fmaf(xz[(size_t)(m - 3 + k) * 512 + d], w[k], acc);
    }
    xc[(size_t)m * 256 + d] = silu_f(acc);
}

// ---------------- segmented scan: stage = pure copies (xc, dtl, xdbl32) -----------------
#define STAGE_SE(L0V, SBV)                                                                  \
    {                                                                                       \
        const int l0_ = (L0V), sb_ = (SBV);                                                 \
        _Pragma("unroll")                                                                   \
        for (int f = t2; f < TS * 4; f += 64) {                                             \
            int l = f >> 2, sg = (f & 3) * 4;                                               \
            *(float4*)&xvs[sb_][l][sg] = *(const float4*)(xcb + base256 + (size_t)(l0_ + l) * 256 + sg); \
            *(float4*)&dts[sb_][l][sg] = *(const float4*)(dlb + base256 + (size_t)(l0_ + l) * 256 + sg); \
        }                                                                                   \
        _Pragma("unroll")                                                                   \
        for (int f = t2; f < TS * 8; f += 64) {                                             \
            int l = f >> 3, sg = (f & 7) * 4;                                               \
            *(float4*)&bcs[sb_][l][sg] = *(const float4*)(xdb + base32 + (size_t)(l0_ + l) * 32 + sg);   \
        }                                                                                   \
    }

__global__ __launch_bounds__(128) void scan_sE(
    const float* xc0, const float* xc1, const float* dtl0, const float* dtl1,
    const float* xd0, const float* xd1,
    const float* al0, const float* al1, const float* D0, const float* D1,
    float* y0, float* y1) {
    __shared__ float dts[2][TS][16];
    __shared__ float xvs[2][TS][16];
    __shared__ float bcs[2][TS][32];

    const int b = blockIdx.x;
    const int dir = blockIdx.y;
    const int seg = blockIdx.z >> 4;
    const int d0 = (blockIdx.z & 15) * 16;
    const int tid = threadIdx.x;

    const float* xcb = dir ? xc1 : xc0;
    const float* dlb = dir ? dtl1 : dtl0;
    const float* xdb = dir ? xd1 : xd0;
    float* ygb = dir ? y1 : y0;

    const size_t base256 = (size_t)b * L_ * 256 + d0;
    const size_t base32  = (size_t)b * L_ * 32;

    const int lstart = seg * SEGL - (seg ? WARM : 0);
    const int ntiles = (seg ? (SEGL + WARM) : SEGL) / TS;
    const int wtiles = seg ? (WARM / TS) : 0;

    const int isStage = tid >> 6;
    const int t2 = tid & 63;
    const int dg = t2 >> 2, q = t2 & 3;

    const float LOG2E = 1.44269504088896340736f;
    float al2[4];
    float Dd = 0.f;
    float h0 = 0.f, h1 = 0.f, h2 = 0.f, h3 = 0.f;
    if (!isStage) {
        const float* alog = (dir ? al1 : al0) + (d0 + dg) * 16 + q * 4;
#pragma unroll
        for (int n = 0; n < 4; ++n) al2[n] = -__expf(alog[n]) * LOG2E;
        Dd = (dir ? D1 : D0)[d0 + dg];
    }
    float* yp = ygb + (size_t)b * L_ * 512 + d0 + dg;   // ld = 512 (overlay)

    if (isStage) STAGE_SE(lstart, 0);
    __syncthreads();

    for (int t = 0; t < ntiles; ++t) {
        if (isStage) {
            if (t + 1 < ntiles) STAGE_SE(lstart + (t + 1) * TS, (t + 1) & 1);
        } else {
            const int cb = t & 1;
            const bool dostore = (t >= wtiles);
#pragma unroll 4
            for (int l = 0; l < TS; ++l) {
                float dt = dts[cb][l][dg];
                float xv = xvs[cb][l][dg];
                float4 Bv = *(const float4*)&bcs[cb][l][q * 4];
                float4 Cv = *(const float4*)&bcs[cb][l][16 + q * 4];
                float dtx = dt * xv;
                float e0 = exp2f(dt * al2[0]);
                float e1 = exp2f(dt * al2[1]);
                float e2 = exp2f(dt * al2[2]);
                float e3 = exp2f(dt * al2[3]);
                h0 = fmaf(e0, h0, dtx * Bv.x);
                h1 = fmaf(e1, h1, dtx * Bv.y);
                h2 = fmaf(e2, h2, dtx * Bv.z);
                h3 = fmaf(e3, h3, dtx * Bv.w);
                float acc = fmaf(h3, Cv.w, fmaf(h2, Cv.z, fmaf(h1, Cv.y, h0 * Cv.x)));
                acc += __shfl_xor(acc, 1);
                acc += __shfl_xor(acc, 2);
                if (dostore && q == 0) {
                    yp[(size_t)(lstart + t * TS + l) * 512] = fmaf(Dd, xv, acc);
                }
            }
        }
        __syncthreads();
    }
}

// ---------------- depthwise conv 3x3 / 5x5 + BN + SiLU ----------------
__global__ __launch_bounds__(256) void dwconv_sE(const float* auxin,
                                                 const float* mk3w, const float* mk3b,
                                                 const float* mk5w, const float* mk5b,
                                                 const float* mkg, const float* mkbeta,
                                                 float* xout) {
    int idx = blockIdx.x * 256 + threadIdx.x;
    int j = idx & 15, i = (idx >> 4) & 63, c = (idx >> 10) & 63, b = idx >> 16;
    const float* src = auxin + ((size_t)(b * 64 + c) << 10);
    float acc;
    if (c < 32) {
        acc = mk3b[c];
        for (int di = -1; di <= 1; ++di)
            for (int dj = -1; dj <= 1; ++dj) {
                int ii = i + di, jj = j + dj;
                if (ii >= 0 && ii < 64 && jj >= 0 && jj < 16)
                    acc = fmaf(src[ii * 16 + jj], mk3w[(c * 3 + di + 1) * 3 + dj + 1], acc);
            }
    } else {
        int cc = c - 32;
        acc = mk5b[cc];
        for (int di = -2; di <= 2; ++di)
            for (int dj = -2; dj <= 2; ++dj) {
                int ii = i + di, jj = j + dj;
                if (ii >= 0 && ii < 64 && jj >= 0 && jj < 16)
                    acc = fmaf(src[ii * 16 + jj], mk5w[(cc * 5 + di + 2) * 5 + dj + 2], acc);
            }
    }
    float v = acc * (mkg[c] * BNS) + mkbeta[c];
    v = silu_f(v);
    xout[(size_t)((b << 10) + i * 16 + j) * 192 + 128 + c] = v;
}

// ---------------- host ----------------
extern "C" void kernel_launch(void* const* d_in, const int* in_sizes, int n_in,
                              void* d_out, int out_size, void* d_ws, size_t ws_size,
                              hipStream_t stream) {
    (void)in_sizes; (void)n_in;
    const float* X         = (const float*)d_in[0];
    const float* main_w    = (const float*)d_in[1];
    const float* main_b    = (const float*)d_in[2];
    const float* main_g    = (const float*)d_in[3];
    const float* main_beta = (const float*)d_in[4];
    const float* aux_w     = (const float*)d_in[5];
    const float* aux_b     = (const float*)d_in[6];
    const float* aux_g     = (const float*)d_in[7];
    const float* aux_beta  = (const float*)d_in[8];
    const float* ln_g      = (const float*)d_in[9];
    const float* ln_b      = (const float*)d_in[10];
    const float* vim_w     = (const float*)d_in[11];
    const float* vim_b     = (const float*)d_in[12];
    const float* mk3_w     = (const float*)d_in[13];
    const float* mk3_b     = (const float*)d_in[14];
    const float* mk5_w     = (const float*)d_in[15];
    const float* mk5_b     = (const float*)d_in[16];
    const float* mk_g      = (const float*)d_in[17];
    const float* mk_beta   = (const float*)d_in[18];
    const float* fus_w     = (const float*)d_in[19];
    const float* fus_b     = (const float*)d_in[20];
    const float* fus_g     = (const float*)d_in[21];
    const float* fus_beta  = (const float*)d_in[22];
    const float* rec_w     = (const float*)d_in[23];
    const float* rec_b     = (const float*)d_in[24];
    const float* rec_g     = (const float*)d_in[25];
    const float* rec_beta  = (const float*)d_in[26];
    const float* in_w0    = (const float*)d_in[27];
    const float* conv_w0  = (const float*)d_in[28];
    const float* conv_b0  = (const float*)d_in[29];
    const float* xproj_w0 = (const float*)d_in[30];
    const float* dt_w0    = (const float*)d_in[31];
    const float* dt_b0    = (const float*)d_in[32];
    const float* Alog0    = (const float*)d_in[33];
    const float* Dvec0    = (const float*)d_in[34];
    const float* out_w0   = (const float*)d_in[35];
    const float* in_w1    = (const float*)d_in[36];
    const float* conv_w1  = (const float*)d_in[37];
    const float* conv_b1  = (const float*)d_in[38];
    const float* xproj_w1 = (const float*)d_in[39];
    const float* dt_w1    = (const float*)d_in[40];
    const float* dt_b1    = (const float*)d_in[41];
    const float* Alog1    = (const float*)d_in[42];
    const float* Dvec1    = (const float*)d_in[43];
    const float* out_w1   = (const float*)d_in[44];

    const size_t wf = ws_size / sizeof(float);
    const size_t FIX = AR_END / 2;              // 235520 floats
    int nb = 0;
    if      (FIX + (size_t)8 * 1024 * 2432 <= wf) nb = 8;
    else if (FIX + (size_t)4 * 1024 * 2432 <= wf) nb = 4;
    else if (FIX + (size_t)2 * 1024 * 2432 <= wf) nb = 2;
    else if (FIX + (size_t)1 * 1024 * 2432 <= wf) nb = 1;
    if (nb == 0) {
        sentinel_sE<<<(out_size + 255) / 256, 256, 0, stream>>>((float*)d_out, out_size);
        return;
    }

    float* ws = (float*)d_ws;
    unsigned short* warena = (unsigned short*)ws;
    const unsigned short* bmain = warena;
    const unsigned short* baux  = warena + 16384;
    const unsigned short* bin0  = warena + 24576;
    const unsigned short* bin1  = warena + 90112;
    const unsigned short* bxpc0 = warena + AR_XPC0;
    const unsigned short* bxpc1 = warena + AR_XPC1;
    const unsigned short* bvim  = warena + 303104;
    const unsigned short* bfus  = warena + 319488;
    const unsigned short* bwcat = warena + 356352;
    const unsigned short* brec  = warena + 421888;

    const size_t R = (size_t)nb * 1024;
    float* xzf    = ws + FIX;
    float* xzb    = xzf + R * 512;
    float* mainin = xzb + R * 512;
    float* auxin  = mainin + R * 128;
    float* xn     = auxin + R * 64;
    float* vimin  = xn;                      // overlay (xn dead after in_proj)
    float* lowb   = xn + R * 128;
    float* highb  = lowb + R * 128;
    float* dtlf   = lowb;                    // overlay (low+high dead after patch): R*256
    float* xcf    = highb + R * 128;
    float* xcb    = xcf + R * 256;
    float* xoutc  = xcf;                     // overlay (xc_f dead after scan)
    float* xfused = xcb;                     // overlay (xc_b dead after scan)
    float* xdblf  = xcb + R * 256;           // R*32
    float* xdblb  = xdblf + R * 32;          // R*32
    float* dtlb   = xdblb + R * 32;          // R*256

    wcvt_sE<<<1840, 256, 0, stream>>>(main_w, aux_w, in_w0, in_w1, xproj_w0, xproj_w1,
                                      vim_w, fus_w, out_w0, out_w1, rec_w, warena);
    wcomp_sE<<<dim3(256, 2), 256, 0, stream>>>(xproj_w0, xproj_w1, dt_w0, dt_w1, warena);
    const unsigned GM = (unsigned)(R / 128);

    for (int b0 = 0; b0 < 8; b0 += nb) {
        wavelet_sE<<<nb * 512, 256, 0, stream>>>(X, lowb, highb, b0);

        // patch_proj main (z=0) + aux (z=1)                            [epi 1]
        mgemm_sE<<<dim3(GM, 2, 2), 256, 0, stream>>>(
            lowb, nullptr, bmain, mainin, 128, 128, 128, 128, 0, 0, 0, 0, 1, 0, 0,
            main_b, main_g, main_beta, nullptr, nullptr, nullptr, nullptr,
            highb, baux, auxin, 64, 0, aux_b, aux_g, aux_beta, nullptr);
        ln_sE<<<dim3(16, nb), 256, 0, stream>>>(mainin, ln_g, ln_b, xn);

        // in_proj fwd (z=0) + bwd flipped (z=1)                        [epi 0]
        mgemm_sE<<<dim3(GM, 8, 2), 256, 0, stream>>>(
            xn, nullptr, bin0, xzf, 512, 128, 128, 128, 512, 0, 0, 0, 0, 0, 0,
            nullptr, nullptr, nullptr, nullptr, nullptr, nullptr, nullptr,
            xn, bin1, xzb, 512, 1, nullptr, nullptr, nullptr, nullptr);

        // conv f+b
        conv_sE<<<dim3((unsigned)R, 2), 256, 0, stream>>>(
            xzf, xzb, conv_w0, conv_b0, conv_w1, conv_b1, xcf, xcb);

        // xproj + composed dt: N=288, writes xdbl32 + dtl              [epi 5]
        mgemm_sE<<<dim3(GM, 5, 2), 256, 0, stream>>>(
            xcf, nullptr, bxpc0, xdblf, 288, 256, 256, 256, 32, 0, 0, 0, 5, 0, 0,
            dt_b0, nullptr, nullptr, nullptr, nullptr, nullptr, dtlf,
            xcb, bxpc1, xdblb, 288, 0, dt_b1, nullptr, nullptr, dtlb);

        // segmented scan; writes RAW y into xz cols 0..255
        scan_sE<<<dim3(nb, 2, 128), 128, 0, stream>>>(
            xcf, xcb, dtlf, dtlb, xdblf, xdblb,
            Alog0, Alog1, Dvec0, Dvec1, xzf, xzb);

        // fused out_proj f+b with silu(z) gating in staging            [adual+agate]
        mgemm_sE<<<dim3(GM, 2, 1), 256, 0, stream>>>(
            xzf, xzb, bwcat, vimin, 128, 512, 512, 512, 128, 0, 0, 1, 0, 0, 1,
            nullptr, nullptr, nullptr, nullptr, nullptr, nullptr, nullptr,
            nullptr, nullptr, nullptr, 0, 0, nullptr, nullptr, nullptr, nullptr);

        // vim: vimin @ vim_w + vim_b + x_seq -> xout cols 0..127       [epi 2]
        mgemm_sE<<<dim3(GM, 2, 1), 256, 0, stream>>>(
            vimin, nullptr, bvim, xoutc, 128, 128, 128, 128, 192, 0, 0, 0, 2, 0, 0,
            vim_b, nullptr, nullptr, mainin, nullptr, nullptr, nullptr,
            nullptr, nullptr, nullptr, 0, 0, nullptr, nullptr, nullptr, nullptr);

        dwconv_sE<<<nb * 256, 256, 0, stream>>>(
            auxin, mk3_w, mk3_b, mk5_w, mk5_b, mk_g, mk_beta, xoutc);

        // fusion: xout @ fus_w + x_in + BN -> x_fused                  [epi 3]
        mgemm_sE<<<dim3(GM, 3, 1), 256, 0, stream>>>(
            xoutc, nullptr, bfus, xfused, 192, 192, 192, 192, 192, 0, 0, 0, 3, 0, 0,
            fus_b, fus_g, fus_beta, mainin, auxin, nullptr, nullptr,
            nullptr, nullptr, nullptr, 0, 0, nullptr, nullptr, nullptr, nullptr);

        // reconstruction: x_fused @ recT + BN + ReLU + x -> d_out      [epi 4]
        mgemm_sE<<<dim3(GM, 4, 1), 256, 0, stream>>>(
            xfused, nullptr, brec, nullptr, 256, 192, 192, 192, 0, 0, 0, 0, 4, b0, 0,
            rec_b, rec_g, rec_beta, nullptr, nullptr, X, (float*)d_out,
            nullptr, nullptr, nullptr, 0, 0, nullptr, nullptr, nullptr, nullptr);
    }
}